// Round 1
// baseline (1167.753 us; speedup 1.0000x reference)
//
#include <hip/hip_runtime.h>
#include <hip/hip_bf16.h>

static constexpr int IN_CH  = 32;
static constexpr int HID    = 64;
static constexpr int LAT    = 16;
static constexpr int NGRAPH = 64;

// ---------------- CSR build ----------------

__global__ void deg_kernel(const int* __restrict__ ei, int* __restrict__ cnt, int E) {
    int e = blockIdx.x * blockDim.x + threadIdx.x;
    if (e < E) atomicAdd(&cnt[ei[E + e]], 1);
}

__global__ void dinv_kernel(const int* __restrict__ cnt, float* __restrict__ dinv, int N) {
    int n = blockIdx.x * blockDim.x + threadIdx.x;
    if (n < N) dinv[n] = rsqrtf((float)cnt[n] + 1.0f);
}

// exclusive scan of cnt -> rowptr (per-block), block totals -> bsum
__global__ void scan1_kernel(const int* __restrict__ cnt, int* __restrict__ rowptr,
                             int* __restrict__ bsum, int N) {
    __shared__ int s[256];
    int i = blockIdx.x * 256 + threadIdx.x;
    int v = (i < N) ? cnt[i] : 0;
    s[threadIdx.x] = v;
    for (int off = 1; off < 256; off <<= 1) {
        __syncthreads();
        int t = (threadIdx.x >= off) ? s[threadIdx.x - off] : 0;
        __syncthreads();
        s[threadIdx.x] += t;
    }
    if (i < N) rowptr[i] = s[threadIdx.x] - v;
    if (threadIdx.x == 255) bsum[blockIdx.x] = s[255];
}

__global__ void scan2_kernel(int* bsum, int nb) {
    if (threadIdx.x == 0 && blockIdx.x == 0) {
        int run = 0;
        for (int j = 0; j < nb; j++) { int t = bsum[j]; bsum[j] = run; run += t; }
    }
}

__global__ void scan3_kernel(int* __restrict__ rowptr, const int* __restrict__ bsum, int N) {
    int i = blockIdx.x * 256 + threadIdx.x;
    if (i < N) rowptr[i] += bsum[blockIdx.x];
}

__global__ void fill_kernel(const int* __restrict__ ei, const int* __restrict__ rowptr,
                            int* __restrict__ cursor, int* __restrict__ col,
                            float* __restrict__ coef, const float* __restrict__ dinv, int E) {
    int e = blockIdx.x * blockDim.x + threadIdx.x;
    if (e >= E) return;
    int s = ei[e], d = ei[E + e];
    int pos = rowptr[d] + atomicAdd(&cursor[d], 1);
    col[pos]  = s;
    coef[pos] = dinv[s] * dinv[d];
}

// ---------------- aggregation: out[n] = sum_e coef*in[src] + dinv[n]^2*in[n] (+bias) ----------------

template <int C, bool ADD_BIAS>
__global__ __launch_bounds__(256) void agg_kernel(
        const float* __restrict__ in, float* __restrict__ out,
        const int* __restrict__ rowptr, const int* __restrict__ cnt,
        const int* __restrict__ col, const float* __restrict__ coef,
        const float* __restrict__ dinv, const float* __restrict__ bias, int N) {
    constexpr int NPB = 256 / C;
    int t = threadIdx.x;
    int node = blockIdx.x * NPB + t / C;
    int c = t % C;
    if (node >= N) return;
    int start = rowptr[node];
    int m = cnt[node];
    float dn = dinv[node];
    float acc = dn * dn * in[(size_t)node * C + c];
    for (int i = 0; i < m; i++) {
        int e = start + i;
        int s = col[e];
        float w = coef[e];
        acc += w * in[(size_t)s * C + c];
    }
    if (ADD_BIAS) acc += bias[c];
    out[(size_t)node * C + c] = acc;
}

// ---------------- tiny dense transform: out = [relu](in @ W [+ b]) ----------------

template <int CIN, int COUT, bool RELU, bool BIAS>
__global__ __launch_bounds__(256) void gemm_kernel(
        const float* __restrict__ in, const float* __restrict__ W,
        const float* __restrict__ b, float* __restrict__ out, int N) {
    constexpr int NPB = 256 / COUT;
    __shared__ float Ws[CIN * COUT];
    __shared__ float bs[COUT];
    __shared__ float xs[NPB * CIN];
    for (int i = threadIdx.x; i < CIN * COUT; i += 256) Ws[i] = W[i];
    if constexpr (BIAS) {
        for (int i = threadIdx.x; i < COUT; i += 256) bs[i] = b[i];
    }
    int ngroups = (N + NPB - 1) / NPB;
    for (int grp = blockIdx.x; grp < ngroups; grp += gridDim.x) {
        int base = grp * NPB;
        __syncthreads();   // Ws ready (first iter) / prev compute done
        for (int i = threadIdx.x; i < NPB * CIN; i += 256) {
            int n = base + i / CIN;
            xs[i] = (n < N) ? in[(size_t)base * CIN + i] : 0.f;
        }
        __syncthreads();
        int r  = threadIdx.x / COUT;
        int co = threadIdx.x % COUT;
        int n = base + r;
        if (n < N) {
            float acc = BIAS ? bs[co] : 0.f;
            #pragma unroll
            for (int k = 0; k < CIN; k++) acc += xs[r * CIN + k] * Ws[k * COUT + co];
            if constexpr (RELU) acc = fmaxf(acc, 0.f);
            out[(size_t)n * COUT + co] = acc;
        }
    }
}

// ---------------- pooling over sorted batch ids ----------------

__global__ __launch_bounds__(256) void pool_kernel(
        const float* __restrict__ h, const int* __restrict__ batch,
        float* __restrict__ sums, int* __restrict__ cntb, int N) {
    const int CHUNK = 512;
    int chunkStart = blockIdx.x * CHUNK;
    int c = threadIdx.x & 63;
    int r = threadIdx.x >> 6;   // 0..3
    int curg = -1;
    float acc = 0.f;
    int cnt = 0;
    int end = chunkStart + CHUNK;
    if (end > N) end = N;
    for (int n = chunkStart + r; n < end; n += 4) {
        int g = batch[n];
        if (g != curg) {
            if (curg >= 0) {
                atomicAdd(&sums[curg * 64 + c], acc);
                if (c == 0) atomicAdd(&cntb[curg], cnt);
            }
            curg = g; acc = 0.f; cnt = 0;
        }
        acc += h[(size_t)n * 64 + c];
        cnt++;
    }
    if (curg >= 0) {
        atomicAdd(&sums[curg * 64 + c], acc);
        if (c == 0) atomicAdd(&cntb[curg], cnt);
    }
}

// ---------------- latent: z = mean @ Wp + bp ; dg = relu(z @ Wd + bd) ----------------

__global__ __launch_bounds__(1024) void latent_kernel(
        const float* __restrict__ sums, const int* __restrict__ cntb,
        const float* __restrict__ Wp, const float* __restrict__ bp,
        const float* __restrict__ Wd, const float* __restrict__ bd,
        float* __restrict__ z_out, float* __restrict__ dg) {
    __shared__ float zl[NGRAPH * LAT];   // 1024
    int t = threadIdx.x;
    {
        int g = t / LAT, l = t % LAT;
        float cf = (float)cntb[g];
        float inv = 1.0f / fmaxf(cf, 1.0f);
        float acc = bp[l];
        #pragma unroll
        for (int k = 0; k < HID; k++) acc += sums[g * HID + k] * inv * Wp[k * LAT + l];
        zl[t] = acc;
        z_out[t] = acc;
    }
    __syncthreads();
    #pragma unroll
    for (int i = 0; i < 4; i++) {
        int idx = t + i * 1024;
        int g = idx >> 6, c = idx & 63;
        float acc = bd[c];
        #pragma unroll
        for (int l = 0; l < LAT; l++) acc += zl[g * LAT + l] * Wd[l * HID + c];
        dg[idx] = fmaxf(acc, 0.f);
    }
}

__global__ void bcast_kernel(const float* __restrict__ dg, const int* __restrict__ batch,
                             float* __restrict__ d, int N) {
    int idx = blockIdx.x * blockDim.x + threadIdx.x;
    if (idx >= N * HID) return;
    int n = idx >> 6, c = idx & 63;
    d[idx] = dg[batch[n] * HID + c];
}

// ---------------- launch ----------------

extern "C" void kernel_launch(void* const* d_in, const int* in_sizes, int n_in,
                              void* d_out, int out_size, void* d_ws, size_t ws_size,
                              hipStream_t stream) {
    const float* x          = (const float*)d_in[0];
    const int*   ei         = (const int*)d_in[1];
    const int*   batch      = (const int*)d_in[2];
    const float* W_enc0     = (const float*)d_in[3];
    const float* b_enc0     = (const float*)d_in[4];
    const float* W_enc1     = (const float*)d_in[5];
    const float* b_enc1     = (const float*)d_in[6];
    const float* W_enc2     = (const float*)d_in[7];
    const float* b_enc2     = (const float*)d_in[8];
    const float* W_proj     = (const float*)d_in[9];
    const float* b_proj     = (const float*)d_in[10];
    const float* W_dec_proj = (const float*)d_in[11];
    const float* b_dec_proj = (const float*)d_in[12];
    const float* W_dec0     = (const float*)d_in[13];
    const float* b_dec0     = (const float*)d_in[14];
    const float* W_dec1     = (const float*)d_in[15];
    const float* b_dec1     = (const float*)d_in[16];

    const int N = in_sizes[0] / IN_CH;
    const int E = in_sizes[1] / 2;

    char* ws = (char*)d_ws;
    size_t off = 0;
    auto alloc = [&](size_t bytes) {
        void* p = ws + off;
        off += (bytes + 255) & ~(size_t)255;
        return p;
    };
    float* A      = (float*)alloc((size_t)N * HID * 4);
    float* B      = (float*)alloc((size_t)N * HID * 4);
    int*   col    = (int*)  alloc((size_t)E * 4);
    float* coef   = (float*)alloc((size_t)E * 4);
    int*   cntn   = (int*)  alloc((size_t)N * 4);
    int*   rowptr = (int*)  alloc((size_t)(N + 1) * 4);
    int*   cursor = (int*)  alloc((size_t)N * 4);
    float* dinv   = (float*)alloc((size_t)N * 4);
    int nb = (N + 255) / 256;
    int*   bsum   = (int*)  alloc((size_t)nb * 4);
    float* sums   = (float*)alloc((size_t)NGRAPH * HID * 4);
    int*   cntb   = (int*)  alloc((size_t)NGRAPH * 4);
    float* dg     = (float*)alloc((size_t)NGRAPH * HID * 4);

    float* x_recon = (float*)d_out;
    float* z_out   = (float*)d_out + (size_t)N * IN_CH;

    hipMemsetAsync(cntn,   0, (size_t)N * 4, stream);
    hipMemsetAsync(cursor, 0, (size_t)N * 4, stream);
    hipMemsetAsync(sums,   0, (size_t)NGRAPH * HID * 4, stream);
    hipMemsetAsync(cntb,   0, (size_t)NGRAPH * 4, stream);

    int eb = (E + 255) / 256;

    // CSR build
    deg_kernel<<<eb, 256, 0, stream>>>(ei, cntn, E);
    dinv_kernel<<<nb, 256, 0, stream>>>(cntn, dinv, N);
    scan1_kernel<<<nb, 256, 0, stream>>>(cntn, rowptr, bsum, N);
    scan2_kernel<<<1, 1, 0, stream>>>(bsum, nb);
    scan3_kernel<<<nb, 256, 0, stream>>>(rowptr, bsum, N);
    fill_kernel<<<eb, 256, 0, stream>>>(ei, rowptr, cursor, col, coef, dinv, E);

    // encoder
    agg_kernel<IN_CH, false><<<(N + 7) / 8, 256, 0, stream>>>(x, A, rowptr, cntn, col, coef, dinv, nullptr, N);
    gemm_kernel<IN_CH, HID, true, true><<<1024, 256, 0, stream>>>(A, W_enc0, b_enc0, B, N);
    agg_kernel<HID, false><<<(N + 3) / 4, 256, 0, stream>>>(B, A, rowptr, cntn, col, coef, dinv, nullptr, N);
    gemm_kernel<HID, HID, true, true><<<1024, 256, 0, stream>>>(A, W_enc1, b_enc1, B, N);
    agg_kernel<HID, false><<<(N + 3) / 4, 256, 0, stream>>>(B, A, rowptr, cntn, col, coef, dinv, nullptr, N);
    gemm_kernel<HID, HID, true, true><<<1024, 256, 0, stream>>>(A, W_enc2, b_enc2, B, N);

    // pool + latent
    pool_kernel<<<(N + 511) / 512, 256, 0, stream>>>(B, batch, sums, cntb, N);
    latent_kernel<<<1, 1024, 0, stream>>>(sums, cntb, W_proj, b_proj, W_dec_proj, b_dec_proj, z_out, dg);

    // decoder
    bcast_kernel<<<((size_t)N * HID + 255) / 256, 256, 0, stream>>>(dg, batch, A, N);
    agg_kernel<HID, false><<<(N + 3) / 4, 256, 0, stream>>>(A, B, rowptr, cntn, col, coef, dinv, nullptr, N);
    gemm_kernel<HID, HID, true, true><<<1024, 256, 0, stream>>>(B, W_dec0, b_dec0, A, N);
    gemm_kernel<HID, IN_CH, false, false><<<1024, 256, 0, stream>>>(A, W_dec1, nullptr, B, N);
    agg_kernel<IN_CH, true><<<(N + 7) / 8, 256, 0, stream>>>(B, x_recon, rowptr, cntn, col, coef, dinv, b_dec1, N);
}

// Round 2
// 1080.476 us; speedup vs baseline: 1.0808x; 1.0808x over previous
//
#include <hip/hip_runtime.h>
#include <hip/hip_bf16.h>

static constexpr int IN_CH  = 32;
static constexpr int HID    = 64;
static constexpr int LAT    = 16;
static constexpr int NGRAPH = 64;

// Sliced feature layout: [C/8][N][8]  -- slice s holds channels s*8..s*8+7 for all
// nodes, contiguous (N*32B per slice). One slice fits a 4MB XCD L2 (N*8*4B = 3.2MB).
// blockIdx % NSL pins a slice to an XCD (round-robin heuristic; correctness-safe).

// ---------------- CSR build ----------------

__global__ void deg_kernel(const int* __restrict__ ei, int* __restrict__ cnt, int E) {
    int e = blockIdx.x * blockDim.x + threadIdx.x;
    if (e < E) atomicAdd(&cnt[ei[E + e]], 1);
}

__global__ void dinv_kernel(const int* __restrict__ cnt, float* __restrict__ dinv, int N) {
    int n = blockIdx.x * blockDim.x + threadIdx.x;
    if (n < N) dinv[n] = rsqrtf((float)cnt[n] + 1.0f);
}

__global__ void scan1_kernel(const int* __restrict__ cnt, int* __restrict__ rowptr,
                             int* __restrict__ bsum, int N) {
    __shared__ int s[256];
    int i = blockIdx.x * 256 + threadIdx.x;
    int v = (i < N) ? cnt[i] : 0;
    s[threadIdx.x] = v;
    for (int off = 1; off < 256; off <<= 1) {
        __syncthreads();
        int t = (threadIdx.x >= off) ? s[threadIdx.x - off] : 0;
        __syncthreads();
        s[threadIdx.x] += t;
    }
    if (i < N) rowptr[i] = s[threadIdx.x] - v;
    if (threadIdx.x == 255) bsum[blockIdx.x] = s[255];
}

// block-scan over the <=512 per-block sums (old 1-thread walk was ~390 serial
// global round-trips ~ 80us)
__global__ __launch_bounds__(512) void scan2_kernel(int* bsum, int nb) {
    __shared__ int s[512];
    int t = threadIdx.x;
    int v = (t < nb) ? bsum[t] : 0;
    s[t] = v;
    for (int off = 1; off < 512; off <<= 1) {
        __syncthreads();
        int x = (t >= off) ? s[t - off] : 0;
        __syncthreads();
        s[t] += x;
    }
    if (t < nb) bsum[t] = s[t] - v;   // exclusive
}

__global__ void scan3_kernel(int* __restrict__ rowptr, const int* __restrict__ bsum, int N) {
    int i = blockIdx.x * 256 + threadIdx.x;
    if (i < N) rowptr[i] += bsum[blockIdx.x];
}

// col only (coef recomputed from dinv at use; halves the scattered fill writes)
__global__ void fill_kernel(const int* __restrict__ ei, const int* __restrict__ rowptr,
                            int* __restrict__ cursor, int* __restrict__ col, int E) {
    int e = blockIdx.x * blockDim.x + threadIdx.x;
    if (e >= E) return;
    int s = ei[e], d = ei[E + e];
    int pos = rowptr[d] + atomicAdd(&cursor[d], 1);
    col[pos] = s;
}

// ---------------- x -> sliced layout ----------------

__global__ void slice_x_kernel(const float* __restrict__ x, float* __restrict__ xs, int N) {
    int idx = blockIdx.x * 256 + threadIdx.x;
    if (idx >= N * IN_CH) return;
    int n = idx >> 5, c = idx & 31;
    xs[(size_t)(c >> 3) * N * 8 + (size_t)n * 8 + (c & 7)] = x[idx];
}

// ---------------- sliced aggregation ----------------
// out[n,ch] = dinv[n]^2*in[n,ch] + sum_edges dinv[s]*dinv[n]*in[s,ch]  (+bias)

template <int C, bool ADD_BIAS, bool OUT_ROWMAJOR>
__global__ __launch_bounds__(256) void agg_sliced_kernel(
        const float* __restrict__ in,       // sliced [C/8][N][8]
        float* __restrict__ out,
        const int* __restrict__ rowptr, const int* __restrict__ cnt,
        const int* __restrict__ col, const float* __restrict__ dinv,
        const float* __restrict__ bias, int N) {
    constexpr int NSL = C / 8;
    int sl    = blockIdx.x & (NSL - 1);
    int chunk = blockIdx.x / NSL;
    int g  = threadIdx.x >> 3;          // node group 0..31
    int c8 = threadIdx.x & 7;
    int node = chunk * 32 + g;
    if (node >= N) return;
    const float* inS = in + (size_t)sl * N * 8;
    int start = rowptr[node];
    int m = cnt[node];
    float dn = dinv[node];
    float acc = dn * dn * inS[(size_t)node * 8 + c8];
    int i = 0;
    for (; i + 4 <= m; i += 4) {        // 4 independent gathers in flight
        int s0 = col[start + i], s1 = col[start + i + 1];
        int s2 = col[start + i + 2], s3 = col[start + i + 3];
        float v0 = inS[(size_t)s0 * 8 + c8];
        float v1 = inS[(size_t)s1 * 8 + c8];
        float v2 = inS[(size_t)s2 * 8 + c8];
        float v3 = inS[(size_t)s3 * 8 + c8];
        float w0 = dinv[s0], w1 = dinv[s1], w2 = dinv[s2], w3 = dinv[s3];
        acc += dn * w0 * v0;
        acc += dn * w1 * v1;
        acc += dn * w2 * v2;
        acc += dn * w3 * v3;
    }
    for (; i < m; ++i) {
        int s = col[start + i];
        acc += dn * dinv[s] * inS[(size_t)s * 8 + c8];
    }
    int ch = sl * 8 + c8;
    if (ADD_BIAS) acc += bias[ch];
    if (OUT_ROWMAJOR) out[(size_t)node * C + ch] = acc;
    else              out[(size_t)sl * N * 8 + (size_t)node * 8 + c8] = acc;
}

// ---------------- tiny dense transform (sliced in/out): out = [relu](in @ W [+ b]) ----------------

template <int CIN, int COUT, bool RELU, bool BIAS>
__global__ __launch_bounds__(256) void gemm_kernel(
        const float* __restrict__ in,       // sliced [CIN/8][N][8]
        const float* __restrict__ W, const float* __restrict__ b,
        float* __restrict__ out,            // sliced [COUT/8][N][8]
        int N) {
    constexpr int NPB = 256 / COUT;
    __shared__ float Ws[CIN * COUT];
    __shared__ float bs[COUT];
    __shared__ float xs[NPB * CIN];
    for (int i = threadIdx.x; i < CIN * COUT; i += 256) Ws[i] = W[i];
    if constexpr (BIAS) {
        for (int i = threadIdx.x; i < COUT; i += 256) bs[i] = b[i];
    }
    int ngroups = (N + NPB - 1) / NPB;
    for (int grp = blockIdx.x; grp < ngroups; grp += gridDim.x) {
        int base = grp * NPB;
        __syncthreads();
        for (int i = threadIdx.x; i < NPB * CIN; i += 256) {
            int r = i / CIN, k = i % CIN;
            int n = base + r;
            xs[i] = (n < N) ? in[(size_t)(k >> 3) * N * 8 + (size_t)n * 8 + (k & 7)] : 0.f;
        }
        __syncthreads();
        int r  = threadIdx.x / COUT;
        int co = threadIdx.x % COUT;
        int n = base + r;
        if (n < N) {
            float acc = BIAS ? bs[co] : 0.f;
            #pragma unroll
            for (int k = 0; k < CIN; k++) acc += xs[r * CIN + k] * Ws[k * COUT + co];
            if constexpr (RELU) acc = fmaxf(acc, 0.f);
            out[(size_t)(co >> 3) * N * 8 + (size_t)n * 8 + (co & 7)] = acc;
        }
    }
}

// ---------------- pooling over sorted batch ids (input sliced [8][N][8]) ----------------

__global__ __launch_bounds__(256) void pool_kernel(
        const float* __restrict__ h, const int* __restrict__ batch,
        float* __restrict__ sums, int* __restrict__ cntb, int N) {
    const int CHUNK = 512;
    int chunkStart = blockIdx.x * CHUNK;
    int c = threadIdx.x & 63;
    int r = threadIdx.x >> 6;
    size_t sbase = (size_t)(c >> 3) * N * 8 + (c & 7);
    int curg = -1;
    float acc = 0.f;
    int cnt = 0;
    int end = chunkStart + CHUNK;
    if (end > N) end = N;
    for (int n = chunkStart + r; n < end; n += 4) {
        int g = batch[n];
        if (g != curg) {
            if (curg >= 0) {
                atomicAdd(&sums[curg * 64 + c], acc);
                if (c == 0) atomicAdd(&cntb[curg], cnt);
            }
            curg = g; acc = 0.f; cnt = 0;
        }
        acc += h[sbase + (size_t)n * 8];
        cnt++;
    }
    if (curg >= 0) {
        atomicAdd(&sums[curg * 64 + c], acc);
        if (c == 0) atomicAdd(&cntb[curg], cnt);
    }
}

// ---------------- latent: z = mean @ Wp + bp ; dg = relu(z @ Wd + bd) ----------------

__global__ __launch_bounds__(1024) void latent_kernel(
        const float* __restrict__ sums, const int* __restrict__ cntb,
        const float* __restrict__ Wp, const float* __restrict__ bp,
        const float* __restrict__ Wd, const float* __restrict__ bd,
        float* __restrict__ z_out, float* __restrict__ dg) {
    __shared__ float zl[NGRAPH * LAT];
    int t = threadIdx.x;
    {
        int g = t / LAT, l = t % LAT;
        float cf = (float)cntb[g];
        float inv = 1.0f / fmaxf(cf, 1.0f);
        float acc = bp[l];
        #pragma unroll
        for (int k = 0; k < HID; k++) acc += sums[g * HID + k] * inv * Wp[k * LAT + l];
        zl[t] = acc;
        z_out[t] = acc;
    }
    __syncthreads();
    #pragma unroll
    for (int i = 0; i < 4; i++) {
        int idx = t + i * 1024;
        int g = idx >> 6, c = idx & 63;
        float acc = bd[c];
        #pragma unroll
        for (int l = 0; l < LAT; l++) acc += zl[g * LAT + l] * Wd[l * HID + c];
        dg[idx] = fmaxf(acc, 0.f);
    }
}

// broadcast per-graph decoder input to nodes, writing sliced layout
__global__ void bcast_kernel(const float* __restrict__ dg, const int* __restrict__ batch,
                             float* __restrict__ d, int N) {
    int idx = blockIdx.x * blockDim.x + threadIdx.x;
    if (idx >= N * HID) return;
    int n = idx >> 6, c = idx & 63;
    d[(size_t)(c >> 3) * N * 8 + (size_t)n * 8 + (c & 7)] = dg[batch[n] * HID + c];
}

// ---------------- launch ----------------

extern "C" void kernel_launch(void* const* d_in, const int* in_sizes, int n_in,
                              void* d_out, int out_size, void* d_ws, size_t ws_size,
                              hipStream_t stream) {
    const float* x          = (const float*)d_in[0];
    const int*   ei         = (const int*)d_in[1];
    const int*   batch      = (const int*)d_in[2];
    const float* W_enc0     = (const float*)d_in[3];
    const float* b_enc0     = (const float*)d_in[4];
    const float* W_enc1     = (const float*)d_in[5];
    const float* b_enc1     = (const float*)d_in[6];
    const float* W_enc2     = (const float*)d_in[7];
    const float* b_enc2     = (const float*)d_in[8];
    const float* W_proj     = (const float*)d_in[9];
    const float* b_proj     = (const float*)d_in[10];
    const float* W_dec_proj = (const float*)d_in[11];
    const float* b_dec_proj = (const float*)d_in[12];
    const float* W_dec0     = (const float*)d_in[13];
    const float* b_dec0     = (const float*)d_in[14];
    const float* W_dec1     = (const float*)d_in[15];
    const float* b_dec1     = (const float*)d_in[16];

    const int N = in_sizes[0] / IN_CH;
    const int E = in_sizes[1] / 2;

    char* ws = (char*)d_ws;
    size_t off = 0;
    auto alloc = [&](size_t bytes) {
        void* p = ws + off;
        off += (bytes + 255) & ~(size_t)255;
        return p;
    };
    float* A      = (float*)alloc((size_t)N * HID * 4);
    float* B      = (float*)alloc((size_t)N * HID * 4);
    float* XS     = (float*)alloc((size_t)N * IN_CH * 4);
    int*   col    = (int*)  alloc((size_t)E * 4);
    int*   cntn   = (int*)  alloc((size_t)N * 4);
    int*   rowptr = (int*)  alloc((size_t)(N + 1) * 4);
    int*   cursor = (int*)  alloc((size_t)N * 4);
    float* dinv   = (float*)alloc((size_t)N * 4);
    int nb = (N + 255) / 256;
    int*   bsum   = (int*)  alloc((size_t)nb * 4);
    float* sums   = (float*)alloc((size_t)NGRAPH * HID * 4);
    int*   cntb   = (int*)  alloc((size_t)NGRAPH * 4);
    float* dg     = (float*)alloc((size_t)NGRAPH * HID * 4);

    float* x_recon = (float*)d_out;
    float* z_out   = (float*)d_out + (size_t)N * IN_CH;

    hipMemsetAsync(cntn,   0, (size_t)N * 4, stream);
    hipMemsetAsync(cursor, 0, (size_t)N * 4, stream);
    hipMemsetAsync(sums,   0, (size_t)NGRAPH * HID * 4, stream);
    hipMemsetAsync(cntb,   0, (size_t)NGRAPH * 4, stream);

    int eb = (E + 255) / 256;
    int nodeChunks = (N + 31) / 32;

    // CSR build
    deg_kernel<<<eb, 256, 0, stream>>>(ei, cntn, E);
    dinv_kernel<<<nb, 256, 0, stream>>>(cntn, dinv, N);
    scan1_kernel<<<nb, 256, 0, stream>>>(cntn, rowptr, bsum, N);
    scan2_kernel<<<1, 512, 0, stream>>>(bsum, nb);
    scan3_kernel<<<nb, 256, 0, stream>>>(rowptr, bsum, N);
    fill_kernel<<<eb, 256, 0, stream>>>(ei, rowptr, cursor, col, E);
    slice_x_kernel<<<(N * IN_CH + 255) / 256, 256, 0, stream>>>(x, XS, N);

    // encoder
    agg_sliced_kernel<IN_CH, false, false><<<nodeChunks * 4, 256, 0, stream>>>(
        XS, A, rowptr, cntn, col, dinv, nullptr, N);
    gemm_kernel<IN_CH, HID, true, true><<<1024, 256, 0, stream>>>(A, W_enc0, b_enc0, B, N);
    agg_sliced_kernel<HID, false, false><<<nodeChunks * 8, 256, 0, stream>>>(
        B, A, rowptr, cntn, col, dinv, nullptr, N);
    gemm_kernel<HID, HID, true, true><<<1024, 256, 0, stream>>>(A, W_enc1, b_enc1, B, N);
    agg_sliced_kernel<HID, false, false><<<nodeChunks * 8, 256, 0, stream>>>(
        B, A, rowptr, cntn, col, dinv, nullptr, N);
    gemm_kernel<HID, HID, true, true><<<1024, 256, 0, stream>>>(A, W_enc2, b_enc2, B, N);

    // pool + latent
    pool_kernel<<<(N + 511) / 512, 256, 0, stream>>>(B, batch, sums, cntb, N);
    latent_kernel<<<1, 1024, 0, stream>>>(sums, cntb, W_proj, b_proj, W_dec_proj, b_dec_proj, z_out, dg);

    // decoder
    bcast_kernel<<<((size_t)N * HID + 255) / 256, 256, 0, stream>>>(dg, batch, A, N);
    agg_sliced_kernel<HID, false, false><<<nodeChunks * 8, 256, 0, stream>>>(
        A, B, rowptr, cntn, col, dinv, nullptr, N);
    gemm_kernel<HID, HID, true, true><<<1024, 256, 0, stream>>>(B, W_dec0, b_dec0, A, N);
    gemm_kernel<HID, IN_CH, false, false><<<1024, 256, 0, stream>>>(A, W_dec1, nullptr, B, N);
    agg_sliced_kernel<IN_CH, true, true><<<nodeChunks * 4, 256, 0, stream>>>(
        B, x_recon, rowptr, cntn, col, dinv, b_dec1, N);
}

// Round 3
// 841.944 us; speedup vs baseline: 1.3870x; 1.2833x over previous
//
#include <hip/hip_runtime.h>
#include <hip/hip_bf16.h>

static constexpr int IN_CH  = 32;
static constexpr int HID    = 64;
static constexpr int LAT    = 16;
static constexpr int NGRAPH = 64;
static constexpr int NBUCKET = 1024;   // degree buckets for counting sort

// Feature layout: sliced [C/8][N][8] floats. One 8-ch slice = N*32B = 3.2MB,
// fits a 4MB XCD L2. blockIdx % NSL pins slice->XCD (perf heuristic only).
// All agg INPUTS are pre-scaled by dinv[n]; agg computes dn * (self + sum gathers).

// ---------------- degree / dinv ----------------

__global__ void deg_kernel(const int* __restrict__ ei, int* __restrict__ cnt, int E) {
    int e = blockIdx.x * blockDim.x + threadIdx.x;
    if (e < E) atomicAdd(&cnt[ei[E + e]], 1);
}

__global__ void dinv_kernel(const int* __restrict__ cnt, float* __restrict__ dinv, int N) {
    int n = blockIdx.x * blockDim.x + threadIdx.x;
    if (n < N) dinv[n] = rsqrtf((float)cnt[n] + 1.0f);
}

// ---------------- counting sort by degree ----------------

__global__ __launch_bounds__(256) void hist_kernel(const int* __restrict__ cnt,
                                                   int* __restrict__ hist, int N) {
    __shared__ int lh[NBUCKET];
    for (int i = threadIdx.x; i < NBUCKET; i += 256) lh[i] = 0;
    __syncthreads();
    int n = blockIdx.x * 256 + threadIdx.x;
    if (n < N) atomicAdd(&lh[min(cnt[n], NBUCKET - 1)], 1);
    __syncthreads();
    for (int i = threadIdx.x; i < NBUCKET; i += 256)
        if (lh[i]) atomicAdd(&hist[i], lh[i]);
}

__global__ __launch_bounds__(1024) void hscan_kernel(int* hist) {
    __shared__ int s[NBUCKET];
    int t = threadIdx.x;
    int v = hist[t];
    s[t] = v;
    for (int off = 1; off < NBUCKET; off <<= 1) {
        __syncthreads();
        int x = (t >= off) ? s[t - off] : 0;
        __syncthreads();
        s[t] += x;
    }
    hist[t] = s[t] - v;   // exclusive
}

__global__ __launch_bounds__(256) void scatter_kernel(
        const int* __restrict__ cnt, const int* __restrict__ hoff, int* __restrict__ hcur,
        int* __restrict__ perm, int* __restrict__ rank, int* __restrict__ cnt2, int N) {
    __shared__ int lh[NBUCKET];    // local count
    __shared__ int gb[NBUCKET];    // global base for this block
    for (int i = threadIdx.x; i < NBUCKET; i += 256) lh[i] = 0;
    __syncthreads();
    int n = blockIdx.x * 256 + threadIdx.x;
    int b = -1, lpos = 0, d = 0;
    if (n < N) {
        d = cnt[n];
        b = min(d, NBUCKET - 1);
        lpos = atomicAdd(&lh[b], 1);
    }
    __syncthreads();
    for (int i = threadIdx.x; i < NBUCKET; i += 256)
        gb[i] = lh[i] ? atomicAdd(&hcur[i], lh[i]) : 0;
    __syncthreads();
    if (n < N) {
        int r = hoff[b] + gb[b] + lpos;
        perm[r] = n;
        rank[n] = r;
        cnt2[r] = d;
    }
}

// ---------------- exclusive scan of cnt2 -> rowptr2 ----------------

__global__ void scan1_kernel(const int* __restrict__ cnt, int* __restrict__ rowptr,
                             int* __restrict__ bsum, int N) {
    __shared__ int s[256];
    int i = blockIdx.x * 256 + threadIdx.x;
    int v = (i < N) ? cnt[i] : 0;
    s[threadIdx.x] = v;
    for (int off = 1; off < 256; off <<= 1) {
        __syncthreads();
        int t = (threadIdx.x >= off) ? s[threadIdx.x - off] : 0;
        __syncthreads();
        s[threadIdx.x] += t;
    }
    if (i < N) rowptr[i] = s[threadIdx.x] - v;
    if (threadIdx.x == 255) bsum[blockIdx.x] = s[255];
}

__global__ __launch_bounds__(512) void scan2_kernel(int* bsum, int nb) {
    __shared__ int s[512];
    int t = threadIdx.x;
    int v = (t < nb) ? bsum[t] : 0;
    s[t] = v;
    for (int off = 1; off < 512; off <<= 1) {
        __syncthreads();
        int x = (t >= off) ? s[t - off] : 0;
        __syncthreads();
        s[t] += x;
    }
    if (t < nb) bsum[t] = s[t] - v;
}

__global__ void scan3_kernel(int* __restrict__ rowptr, const int* __restrict__ bsum, int N) {
    int i = blockIdx.x * 256 + threadIdx.x;
    if (i < N) rowptr[i] += bsum[blockIdx.x];
}

// fill CSR in degree-sorted row order; col stores ORIGINAL src id
__global__ void fill_kernel(const int* __restrict__ ei, const int* __restrict__ rank,
                            const int* __restrict__ rowptr2, int* __restrict__ cursor,
                            int* __restrict__ col, int E) {
    int e = blockIdx.x * blockDim.x + threadIdx.x;
    if (e >= E) return;
    int s = ei[e], d = ei[E + e];
    int rd = rank[d];
    int pos = rowptr2[rd] + atomicAdd(&cursor[rd], 1);
    col[pos] = s;
}

// ---------------- x -> sliced layout, pre-scaled by dinv ----------------

__global__ void slice_x_kernel(const float* __restrict__ x, const float* __restrict__ dinv,
                               float* __restrict__ xs, int N) {
    int idx = blockIdx.x * 256 + threadIdx.x;   // over N*2
    if (idx >= N * 2) return;
    int n = idx >> 1, h = idx & 1;
    int sl = blockIdx.y;
    float4 v = ((const float4*)x)[(size_t)n * 8 + sl * 2 + h];
    float dn = dinv[n];
    v.x *= dn; v.y *= dn; v.z *= dn; v.w *= dn;
    ((float4*)(xs + (size_t)sl * N * 8))[idx] = v;
}

// ---------------- aggregation (streaming CSR, degree-uniform waves) ----------------
// out[node] = dinv[node] * (in[node] + sum_{src in row} in[src])   [+bias]

template <int C, bool ADD_BIAS, bool OUT_ROWMAJOR>
__global__ __launch_bounds__(256) void agg_kernel(
        const float* __restrict__ in, float* __restrict__ out,
        const int* __restrict__ rowptr2, const int* __restrict__ cnt2,
        const int* __restrict__ col, const float* __restrict__ dinv,
        const int* __restrict__ perm, const float* __restrict__ bias, int N) {
    constexpr int NSL = C / 8;
    int sl = blockIdx.x % NSL;
    int chunk = blockIdx.x / NSL;
    int slot = threadIdx.x >> 1;
    int h = threadIdx.x & 1;
    int r = chunk * 128 + slot;
    if (r >= N) return;
    int node = perm[r];
    const float4* inS = (const float4*)(in + (size_t)sl * N * 8);
    int start = rowptr2[r];
    int m = cnt2[r];
    const int* cp = col + start;
    float4 a = inS[(size_t)node * 2 + h];
    float ax = a.x, ay = a.y, az = a.z, aw = a.w;
    int i = 0;
    for (; i + 8 <= m; i += 8) {
        int s0 = cp[i], s1 = cp[i+1], s2 = cp[i+2], s3 = cp[i+3];
        int s4 = cp[i+4], s5 = cp[i+5], s6 = cp[i+6], s7 = cp[i+7];
        float4 v0 = inS[(size_t)s0*2+h], v1 = inS[(size_t)s1*2+h];
        float4 v2 = inS[(size_t)s2*2+h], v3 = inS[(size_t)s3*2+h];
        float4 v4 = inS[(size_t)s4*2+h], v5 = inS[(size_t)s5*2+h];
        float4 v6 = inS[(size_t)s6*2+h], v7 = inS[(size_t)s7*2+h];
        ax += ((v0.x+v1.x)+(v2.x+v3.x)) + ((v4.x+v5.x)+(v6.x+v7.x));
        ay += ((v0.y+v1.y)+(v2.y+v3.y)) + ((v4.y+v5.y)+(v6.y+v7.y));
        az += ((v0.z+v1.z)+(v2.z+v3.z)) + ((v4.z+v5.z)+(v6.z+v7.z));
        aw += ((v0.w+v1.w)+(v2.w+v3.w)) + ((v4.w+v5.w)+(v6.w+v7.w));
    }
    if (i + 4 <= m) {
        int s0 = cp[i], s1 = cp[i+1], s2 = cp[i+2], s3 = cp[i+3];
        float4 v0 = inS[(size_t)s0*2+h], v1 = inS[(size_t)s1*2+h];
        float4 v2 = inS[(size_t)s2*2+h], v3 = inS[(size_t)s3*2+h];
        ax += (v0.x+v1.x)+(v2.x+v3.x);
        ay += (v0.y+v1.y)+(v2.y+v3.y);
        az += (v0.z+v1.z)+(v2.z+v3.z);
        aw += (v0.w+v1.w)+(v2.w+v3.w);
        i += 4;
    }
    for (; i < m; ++i) {
        int s = cp[i];
        float4 v = inS[(size_t)s*2+h];
        ax += v.x; ay += v.y; az += v.z; aw += v.w;
    }
    float dn = dinv[node];
    ax *= dn; ay *= dn; az *= dn; aw *= dn;
    if (ADD_BIAS) {
        float4 b4 = ((const float4*)bias)[sl * 2 + h];
        ax += b4.x; ay += b4.y; az += b4.z; aw += b4.w;
    }
    float4 res = make_float4(ax, ay, az, aw);
    if (OUT_ROWMAJOR) ((float4*)out)[(size_t)node * (C/4) + sl*2 + h] = res;
    else ((float4*)(out + (size_t)sl * N * 8))[(size_t)node * 2 + h] = res;
}

// ---------------- dense transform: out = [relu](in @ W [+b]) [*dinv] ----------------

template <int CIN, int COUT, bool RELU, bool BIAS, bool SCALE, bool OUT_ROWMAJOR>
__global__ __launch_bounds__(256) void gemm_kernel(
        const float* __restrict__ in, const float* __restrict__ W,
        const float* __restrict__ b, const float* __restrict__ dinv,
        float* __restrict__ out, int N) {
    constexpr int NPB = 256 / COUT;
    constexpr int PAD = CIN + 4;
    constexpr int K4 = CIN / 4;
    __shared__ float4 wt4[K4 * COUT];   // [k4][COUT]
    __shared__ float xs[NPB * PAD];
    __shared__ float bs[COUT];
    for (int i = threadIdx.x; i < K4 * COUT; i += 256) {
        int k4 = i / COUT, co = i % COUT;
        float4 w;
        w.x = W[(4*k4+0)*COUT + co];
        w.y = W[(4*k4+1)*COUT + co];
        w.z = W[(4*k4+2)*COUT + co];
        w.w = W[(4*k4+3)*COUT + co];
        wt4[i] = w;
    }
    if constexpr (BIAS) {
        for (int i = threadIdx.x; i < COUT; i += 256) bs[i] = b[i];
    }
    int r  = threadIdx.x / COUT;
    int co = threadIdx.x % COUT;
    int ngroups = (N + NPB - 1) / NPB;
    for (int grp = blockIdx.x; grp < ngroups; grp += gridDim.x) {
        int base = grp * NPB;
        __syncthreads();
        for (int i = threadIdx.x; i < NPB * CIN; i += 256) {
            int rr = i / CIN, k = i % CIN;
            int n = base + rr;
            xs[rr * PAD + k] = (n < N) ? in[(size_t)(k >> 3) * N * 8 + (size_t)n * 8 + (k & 7)] : 0.f;
        }
        __syncthreads();
        int n = base + r;
        if (n < N) {
            float acc0 = BIAS ? bs[co] : 0.f;
            float acc1 = 0.f;
            const float4* xv = (const float4*)(xs + r * PAD);
            #pragma unroll
            for (int k4 = 0; k4 < K4; k4 += 2) {
                float4 xk0 = xv[k4],     wk0 = wt4[k4 * COUT + co];
                float4 xk1 = xv[k4 + 1], wk1 = wt4[(k4 + 1) * COUT + co];
                acc0 += xk0.x*wk0.x + xk0.y*wk0.y + xk0.z*wk0.z + xk0.w*wk0.w;
                acc1 += xk1.x*wk1.x + xk1.y*wk1.y + xk1.z*wk1.z + xk1.w*wk1.w;
            }
            float acc = acc0 + acc1;
            if constexpr (RELU) acc = fmaxf(acc, 0.f);
            if constexpr (SCALE) acc *= dinv[n];
            if constexpr (OUT_ROWMAJOR) out[(size_t)n * COUT + co] = acc;
            else out[(size_t)(co >> 3) * N * 8 + (size_t)n * 8 + (co & 7)] = acc;
        }
    }
}

// ---------------- pooling over sorted batch ids (row-major input) ----------------

__global__ __launch_bounds__(256) void pool_kernel(
        const float* __restrict__ h, const int* __restrict__ batch,
        float* __restrict__ sums, int* __restrict__ cntb, int N) {
    const int CHUNK = 512;
    int chunkStart = blockIdx.x * CHUNK;
    int c = threadIdx.x & 63;
    int r = threadIdx.x >> 6;
    int curg = -1;
    float acc = 0.f;
    int cnt = 0;
    int end = chunkStart + CHUNK;
    if (end > N) end = N;
    for (int n = chunkStart + r; n < end; n += 4) {
        int g = batch[n];
        if (g != curg) {
            if (curg >= 0) {
                atomicAdd(&sums[curg * 64 + c], acc);
                if (c == 0) atomicAdd(&cntb[curg], cnt);
            }
            curg = g; acc = 0.f; cnt = 0;
        }
        acc += h[(size_t)n * 64 + c];
        cnt++;
    }
    if (curg >= 0) {
        atomicAdd(&sums[curg * 64 + c], acc);
        if (c == 0) atomicAdd(&cntb[curg], cnt);
    }
}

// ---------------- latent ----------------

__global__ __launch_bounds__(1024) void latent_kernel(
        const float* __restrict__ sums, const int* __restrict__ cntb,
        const float* __restrict__ Wp, const float* __restrict__ bp,
        const float* __restrict__ Wd, const float* __restrict__ bd,
        float* __restrict__ z_out, float* __restrict__ dg) {
    __shared__ float zl[NGRAPH * LAT];
    int t = threadIdx.x;
    {
        int g = t / LAT, l = t % LAT;
        float cf = (float)cntb[g];
        float inv = 1.0f / fmaxf(cf, 1.0f);
        float acc = bp[l];
        #pragma unroll
        for (int k = 0; k < HID; k++) acc += sums[g * HID + k] * inv * Wp[k * LAT + l];
        zl[t] = acc;
        z_out[t] = acc;
    }
    __syncthreads();
    #pragma unroll
    for (int i = 0; i < 4; i++) {
        int idx = t + i * 1024;
        int g = idx >> 6, c = idx & 63;
        float acc = bd[c];
        #pragma unroll
        for (int l = 0; l < LAT; l++) acc += zl[g * LAT + l] * Wd[l * HID + c];
        dg[idx] = fmaxf(acc, 0.f);
    }
}

// broadcast per-graph decoder input to nodes, sliced + dinv-prescaled
__global__ void bcast_kernel(const float* __restrict__ dg, const int* __restrict__ batch,
                             const float* __restrict__ dinv, float* __restrict__ d, int N) {
    int idx = blockIdx.x * 256 + threadIdx.x;   // over N*2
    if (idx >= N * 2) return;
    int n = idx >> 1, h = idx & 1;
    int sl = blockIdx.y;
    float4 v = ((const float4*)dg)[(size_t)batch[n] * 16 + sl * 2 + h];
    float dn = dinv[n];
    v.x *= dn; v.y *= dn; v.z *= dn; v.w *= dn;
    ((float4*)(d + (size_t)sl * N * 8))[idx] = v;
}

// ---------------- launch ----------------

extern "C" void kernel_launch(void* const* d_in, const int* in_sizes, int n_in,
                              void* d_out, int out_size, void* d_ws, size_t ws_size,
                              hipStream_t stream) {
    const float* x          = (const float*)d_in[0];
    const int*   ei         = (const int*)d_in[1];
    const int*   batch      = (const int*)d_in[2];
    const float* W_enc0     = (const float*)d_in[3];
    const float* b_enc0     = (const float*)d_in[4];
    const float* W_enc1     = (const float*)d_in[5];
    const float* b_enc1     = (const float*)d_in[6];
    const float* W_enc2     = (const float*)d_in[7];
    const float* b_enc2     = (const float*)d_in[8];
    const float* W_proj     = (const float*)d_in[9];
    const float* b_proj     = (const float*)d_in[10];
    const float* W_dec_proj = (const float*)d_in[11];
    const float* b_dec_proj = (const float*)d_in[12];
    const float* W_dec0     = (const float*)d_in[13];
    const float* b_dec0     = (const float*)d_in[14];
    const float* W_dec1     = (const float*)d_in[15];
    const float* b_dec1     = (const float*)d_in[16];

    const int N = in_sizes[0] / IN_CH;
    const int E = in_sizes[1] / 2;

    char* ws = (char*)d_ws;
    size_t off = 0;
    auto alloc = [&](size_t bytes) {
        void* p = ws + off;
        off += (bytes + 255) & ~(size_t)255;
        return p;
    };
    float* A       = (float*)alloc((size_t)N * HID * 4);
    float* B       = (float*)alloc((size_t)N * HID * 4);
    float* XS      = (float*)alloc((size_t)N * IN_CH * 4);
    int*   col     = (int*)  alloc((size_t)E * 4);
    int*   cntn    = (int*)  alloc((size_t)N * 4);
    int*   cnt2    = (int*)  alloc((size_t)N * 4);
    int*   rowptr2 = (int*)  alloc((size_t)(N + 1) * 4);
    int*   cursor  = (int*)  alloc((size_t)N * 4);
    int*   perm    = (int*)  alloc((size_t)N * 4);
    int*   rank    = (int*)  alloc((size_t)N * 4);
    float* dinv    = (float*)alloc((size_t)N * 4);
    int nb = (N + 255) / 256;
    int*   bsum    = (int*)  alloc((size_t)nb * 4);
    int*   hist    = (int*)  alloc((size_t)NBUCKET * 4);
    int*   hcur    = (int*)  alloc((size_t)NBUCKET * 4);
    float* sums    = (float*)alloc((size_t)NGRAPH * HID * 4);
    int*   cntb    = (int*)  alloc((size_t)NGRAPH * 4);
    float* dg      = (float*)alloc((size_t)NGRAPH * HID * 4);

    float* x_recon = (float*)d_out;
    float* z_out   = (float*)d_out + (size_t)N * IN_CH;

    hipMemsetAsync(cntn,   0, (size_t)N * 4, stream);
    hipMemsetAsync(cursor, 0, (size_t)N * 4, stream);
    hipMemsetAsync(hist,   0, (size_t)NBUCKET * 4, stream);
    hipMemsetAsync(hcur,   0, (size_t)NBUCKET * 4, stream);
    hipMemsetAsync(sums,   0, (size_t)NGRAPH * HID * 4, stream);
    hipMemsetAsync(cntb,   0, (size_t)NGRAPH * 4, stream);

    int eb = (E + 255) / 256;
    int chunks = (N + 127) / 128;

    // CSR build + degree sort
    deg_kernel<<<eb, 256, 0, stream>>>(ei, cntn, E);
    dinv_kernel<<<nb, 256, 0, stream>>>(cntn, dinv, N);
    hist_kernel<<<nb, 256, 0, stream>>>(cntn, hist, N);
    hscan_kernel<<<1, NBUCKET, 0, stream>>>(hist);
    scatter_kernel<<<nb, 256, 0, stream>>>(cntn, hist, hcur, perm, rank, cnt2, N);
    scan1_kernel<<<nb, 256, 0, stream>>>(cnt2, rowptr2, bsum, N);
    scan2_kernel<<<1, 512, 0, stream>>>(bsum, nb);
    scan3_kernel<<<nb, 256, 0, stream>>>(rowptr2, bsum, N);
    fill_kernel<<<eb, 256, 0, stream>>>(ei, rank, rowptr2, cursor, col, E);
    {
        dim3 g((N * 2 + 255) / 256, IN_CH / 8);
        slice_x_kernel<<<g, 256, 0, stream>>>(x, dinv, XS, N);
    }

    // encoder
    agg_kernel<IN_CH, false, false><<<chunks * 4, 256, 0, stream>>>(
        XS, A, rowptr2, cnt2, col, dinv, perm, nullptr, N);
    gemm_kernel<IN_CH, HID, true, true, true, false><<<2048, 256, 0, stream>>>(
        A, W_enc0, b_enc0, dinv, B, N);
    agg_kernel<HID, false, false><<<chunks * 8, 256, 0, stream>>>(
        B, A, rowptr2, cnt2, col, dinv, perm, nullptr, N);
    gemm_kernel<HID, HID, true, true, true, false><<<2048, 256, 0, stream>>>(
        A, W_enc1, b_enc1, dinv, B, N);
    agg_kernel<HID, false, false><<<chunks * 8, 256, 0, stream>>>(
        B, A, rowptr2, cnt2, col, dinv, perm, nullptr, N);
    gemm_kernel<HID, HID, true, true, false, true><<<2048, 256, 0, stream>>>(
        A, W_enc2, b_enc2, dinv, B, N);   // row-major out for pool, no dinv scale

    // pool + latent
    pool_kernel<<<(N + 511) / 512, 256, 0, stream>>>(B, batch, sums, cntb, N);
    latent_kernel<<<1, 1024, 0, stream>>>(sums, cntb, W_proj, b_proj, W_dec_proj, b_dec_proj, z_out, dg);

    // decoder
    {
        dim3 g((N * 2 + 255) / 256, HID / 8);
        bcast_kernel<<<g, 256, 0, stream>>>(dg, batch, dinv, A, N);
    }
    agg_kernel<HID, false, false><<<chunks * 8, 256, 0, stream>>>(
        A, B, rowptr2, cnt2, col, dinv, perm, nullptr, N);
    gemm_kernel<HID, HID, true, true, false, false><<<2048, 256, 0, stream>>>(
        B, W_dec0, b_dec0, dinv, A, N);
    gemm_kernel<HID, IN_CH, false, false, true, false><<<2048, 256, 0, stream>>>(
        A, W_dec1, nullptr, dinv, B, N);
    agg_kernel<IN_CH, true, true><<<chunks * 4, 256, 0, stream>>>(
        B, x_recon, rowptr2, cnt2, col, dinv, perm, b_dec1, N);
}

// Round 4
// 833.860 us; speedup vs baseline: 1.4004x; 1.0097x over previous
//
#include <hip/hip_runtime.h>
#include <hip/hip_bf16.h>

typedef unsigned long long u64;

static constexpr int IN_CH  = 32;
static constexpr int HID    = 64;
static constexpr int LAT    = 16;
static constexpr int NGRAPH = 64;
static constexpr int NBUCKET = 1024;   // degree buckets for counting sort
static constexpr int KB_CSR  = 24;     // blocks per bucket in csr_kernel

// Feature layout: sliced [C/8][N][8] floats. One 8-ch slice = N*32B = 3.2MB,
// fits a 4MB XCD L2. blockIdx % NSL pins slice->XCD (perf heuristic only).
// All agg INPUTS are pre-scaled by dinv[n]; agg computes dn * (self + sum gathers).
//
// CSR build pipeline (no random global atomics, no scattered 4B writes):
//   bhist/bscan: exact histogram of dst>>9 -> bucket bases
//   bin<0>:      LDS counting-sort edges by dst-bucket -> staged1 (coalesced runs)
//   degb:        per-bucket LDS histogram -> degree + dinv (no atomics)
//   hist/hscan/scatter: degree-sort -> rank/perm/cnt2
//   bin<1>:      rebin staged1 by rank[dst] (rank gather is bucket-local)
//   csr:         bucket-local scatter into col (XCD-pinned, line-filling)

// ---------------- bucket histogram of dst ----------------

__global__ __launch_bounds__(256) void bhist_kernel(const int* __restrict__ ei,
                                                    int* __restrict__ bh, int E) {
    __shared__ int lh[256];
    lh[threadIdx.x] = 0;
    __syncthreads();
    int base = blockIdx.x * 2048;
    #pragma unroll
    for (int j = 0; j < 8; j++) {
        int idx = base + j * 256 + threadIdx.x;
        if (idx < E) atomicAdd(&lh[ei[E + idx] >> 9], 1);
    }
    __syncthreads();
    if (lh[threadIdx.x]) atomicAdd(&bh[threadIdx.x], lh[threadIdx.x]);
}

__global__ __launch_bounds__(256) void bscan_kernel(const int* __restrict__ bh,
                                                    int* __restrict__ bbase, int E) {
    __shared__ int s[256];
    int t = threadIdx.x;
    int v = bh[t];
    s[t] = v;
    for (int off = 1; off < 256; off <<= 1) {
        __syncthreads();
        int x = (t >= off) ? s[t - off] : 0;
        __syncthreads();
        s[t] += x;
    }
    __syncthreads();
    bbase[t] = s[t] - v;
    if (t == 255) bbase[256] = E;
}

// ---------------- LDS counting-sort binning ----------------
// MODE 0: in = edge_index, key = dst, val = src, bin by dst>>9
// MODE 1: in = staged1 (dst,src), key = rank[dst] (bucket-local gather), bin by rank>>9

template <int MODE>
__global__ __launch_bounds__(256) void bin_kernel(
        const int* __restrict__ ei, const u64* __restrict__ sin,
        const int* __restrict__ rank,
        const int* __restrict__ bbase, int* __restrict__ gcur,
        u64* __restrict__ sout, int E) {
    __shared__ int lhist[256], lscan[256], lcur[256], gbase[256];
    __shared__ u64 sbuf[2048];
    int tid = threadIdx.x;
    lhist[tid] = 0;
    __syncthreads();
    int base = blockIdx.x * 2048;
    int cnt = min(2048, E - base);
    int myb[8]; u64 myp[8];
    #pragma unroll
    for (int j = 0; j < 8; j++) {
        int idx = base + j * 256 + tid;
        myb[j] = -1;
        if (idx < E) {
            int key, val;
            if constexpr (MODE == 0) { key = ei[E + idx]; val = ei[idx]; }
            else {
                u64 p = sin[idx];
                key = rank[(int)(p >> 32)];
                val = (int)(p & 0xffffffffu);
            }
            int b = key >> 9;
            myb[j] = b;
            myp[j] = ((u64)(unsigned)key << 32) | (unsigned)val;
            atomicAdd(&lhist[b], 1);
        }
    }
    __syncthreads();
    int v = lhist[tid];
    lscan[tid] = v;
    for (int off = 1; off < 256; off <<= 1) {
        __syncthreads();
        int x = (tid >= off) ? lscan[tid - off] : 0;
        __syncthreads();
        lscan[tid] += x;
    }
    __syncthreads();
    int excl = lscan[tid] - v;
    __syncthreads();
    lscan[tid] = excl;
    lcur[tid] = excl;
    __syncthreads();
    #pragma unroll
    for (int j = 0; j < 8; j++) {
        if (myb[j] >= 0) {
            int pos = atomicAdd(&lcur[myb[j]], 1);
            sbuf[pos] = myp[j];
        }
    }
    gbase[tid] = v ? atomicAdd(&gcur[tid], v) : 0;
    __syncthreads();
    for (int i = tid; i < cnt; i += 256) {
        u64 p = sbuf[i];
        int b = (int)(p >> 41);   // key>>9
        sout[bbase[b] + gbase[b] + (i - lscan[b])] = p;
    }
}

// ---------------- per-bucket degree + dinv (no atomics to global) ----------------

__global__ __launch_bounds__(256) void degb_kernel(
        const u64* __restrict__ staged, const int* __restrict__ bbase,
        int* __restrict__ cnt, float* __restrict__ dinv, int N) {
    __shared__ int ldeg[512];
    int b = blockIdx.x;
    ldeg[threadIdx.x] = 0;
    ldeg[threadIdx.x + 256] = 0;
    __syncthreads();
    int s0 = bbase[b], s1 = bbase[b + 1];
    for (int i = s0 + threadIdx.x; i < s1; i += 256)
        atomicAdd(&ldeg[(int)(staged[i] >> 32) - (b << 9)], 1);
    __syncthreads();
    #pragma unroll
    for (int j = 0; j < 2; j++) {
        int t = threadIdx.x + j * 256;
        int n = (b << 9) + t;
        if (n < N) {
            int d = ldeg[t];
            cnt[n] = d;
            dinv[n] = rsqrtf((float)d + 1.0f);
        }
    }
}

// ---------------- counting sort by degree ----------------

__global__ __launch_bounds__(256) void hist_kernel(const int* __restrict__ cnt,
                                                   int* __restrict__ hist, int N) {
    __shared__ int lh[NBUCKET];
    for (int i = threadIdx.x; i < NBUCKET; i += 256) lh[i] = 0;
    __syncthreads();
    int n = blockIdx.x * 256 + threadIdx.x;
    if (n < N) atomicAdd(&lh[min(cnt[n], NBUCKET - 1)], 1);
    __syncthreads();
    for (int i = threadIdx.x; i < NBUCKET; i += 256)
        if (lh[i]) atomicAdd(&hist[i], lh[i]);
}

__global__ __launch_bounds__(1024) void hscan_kernel(int* hist) {
    __shared__ int s[NBUCKET];
    int t = threadIdx.x;
    int v = hist[t];
    s[t] = v;
    for (int off = 1; off < NBUCKET; off <<= 1) {
        __syncthreads();
        int x = (t >= off) ? s[t - off] : 0;
        __syncthreads();
        s[t] += x;
    }
    hist[t] = s[t] - v;   // exclusive
}

__global__ __launch_bounds__(256) void scatter_kernel(
        const int* __restrict__ cnt, const int* __restrict__ hoff, int* __restrict__ hcur,
        int* __restrict__ perm, int* __restrict__ rank, int* __restrict__ cnt2, int N) {
    __shared__ int lh[NBUCKET];
    __shared__ int gb[NBUCKET];
    for (int i = threadIdx.x; i < NBUCKET; i += 256) lh[i] = 0;
    __syncthreads();
    int n = blockIdx.x * 256 + threadIdx.x;
    int b = -1, lpos = 0, d = 0;
    if (n < N) {
        d = cnt[n];
        b = min(d, NBUCKET - 1);
        lpos = atomicAdd(&lh[b], 1);
    }
    __syncthreads();
    for (int i = threadIdx.x; i < NBUCKET; i += 256)
        gb[i] = lh[i] ? atomicAdd(&hcur[i], lh[i]) : 0;
    __syncthreads();
    if (n < N) {
        int r = hoff[b] + gb[b] + lpos;
        perm[r] = n;
        rank[n] = r;
        cnt2[r] = d;
    }
}

// ---------------- exclusive scan of cnt2 -> rowptr2 ----------------

__global__ void scan1_kernel(const int* __restrict__ cnt, int* __restrict__ rowptr,
                             int* __restrict__ bsum, int N) {
    __shared__ int s[256];
    int i = blockIdx.x * 256 + threadIdx.x;
    int v = (i < N) ? cnt[i] : 0;
    s[threadIdx.x] = v;
    for (int off = 1; off < 256; off <<= 1) {
        __syncthreads();
        int t = (threadIdx.x >= off) ? s[threadIdx.x - off] : 0;
        __syncthreads();
        s[threadIdx.x] += t;
    }
    if (i < N) rowptr[i] = s[threadIdx.x] - v;
    if (threadIdx.x == 255) bsum[blockIdx.x] = s[255];
}

__global__ __launch_bounds__(512) void scan2_kernel(int* bsum, int nb) {
    __shared__ int s[512];
    int t = threadIdx.x;
    int v = (t < nb) ? bsum[t] : 0;
    s[t] = v;
    for (int off = 1; off < 512; off <<= 1) {
        __syncthreads();
        int x = (t >= off) ? s[t - off] : 0;
        __syncthreads();
        s[t] += x;
    }
    if (t < nb) bsum[t] = s[t] - v;
}

__global__ void scan3_kernel(int* __restrict__ rowptr, const int* __restrict__ bsum, int N) {
    int i = blockIdx.x * 256 + threadIdx.x;
    if (i < N) rowptr[i] += bsum[blockIdx.x];
}

__global__ void bbaser_kernel(const int* __restrict__ rowptr2, int* __restrict__ bbase,
                              int N, int E) {
    int t = blockIdx.x * blockDim.x + threadIdx.x;
    if (t <= 256) bbase[t] = ((t << 9) >= N) ? E : rowptr2[t << 9];
}

// ---------------- bucket-local CSR fill ----------------
// All blocks of a bucket share blockIdx%8 -> same XCD; rowptr2/cur/col accesses
// confined to the bucket's ~32KB window -> lines fill before writeback.

__global__ __launch_bounds__(256) void csr_kernel(
        const u64* __restrict__ staged, const int* __restrict__ bbase,
        const int* __restrict__ rowptr2, int* __restrict__ cur,
        int* __restrict__ col) {
    int bucket = blockIdx.x & 255;
    int k = blockIdx.x >> 8;
    int s0 = bbase[bucket], s1 = bbase[bucket + 1];
    for (int i = s0 + k * 256 + threadIdx.x; i < s1; i += 256 * KB_CSR) {
        u64 p = staged[i];
        int r = (int)(p >> 32);
        int pos = rowptr2[r] + atomicAdd(&cur[r], 1);
        col[pos] = (int)(p & 0xffffffffu);
    }
}

// ---------------- x -> sliced layout, pre-scaled by dinv ----------------

__global__ void slice_x_kernel(const float* __restrict__ x, const float* __restrict__ dinv,
                               float* __restrict__ xs, int N) {
    int idx = blockIdx.x * 256 + threadIdx.x;   // over N*2
    if (idx >= N * 2) return;
    int n = idx >> 1, h = idx & 1;
    int sl = blockIdx.y;
    float4 v = ((const float4*)x)[(size_t)n * 8 + sl * 2 + h];
    float dn = dinv[n];
    v.x *= dn; v.y *= dn; v.z *= dn; v.w *= dn;
    ((float4*)(xs + (size_t)sl * N * 8))[idx] = v;
}

// ---------------- aggregation (streaming CSR, degree-uniform waves) ----------------
// out[node] = dinv[node] * (in[node] + sum_{src in row} in[src])   [+bias]

template <int C, bool ADD_BIAS, bool OUT_ROWMAJOR>
__global__ __launch_bounds__(256) void agg_kernel(
        const float* __restrict__ in, float* __restrict__ out,
        const int* __restrict__ rowptr2, const int* __restrict__ cnt2,
        const int* __restrict__ col, const float* __restrict__ dinv,
        const int* __restrict__ perm, const float* __restrict__ bias, int N) {
    constexpr int NSL = C / 8;
    int sl = blockIdx.x % NSL;
    int chunk = blockIdx.x / NSL;
    int slot = threadIdx.x >> 1;
    int h = threadIdx.x & 1;
    int r = chunk * 128 + slot;
    if (r >= N) return;
    int node = perm[r];
    const float4* inS = (const float4*)(in + (size_t)sl * N * 8);
    int start = rowptr2[r];
    int m = cnt2[r];
    const int* cp = col + start;
    float4 a = inS[(size_t)node * 2 + h];
    float ax = a.x, ay = a.y, az = a.z, aw = a.w;
    int i = 0;
    for (; i + 8 <= m; i += 8) {
        int s0 = cp[i], s1 = cp[i+1], s2 = cp[i+2], s3 = cp[i+3];
        int s4 = cp[i+4], s5 = cp[i+5], s6 = cp[i+6], s7 = cp[i+7];
        float4 v0 = inS[(size_t)s0*2+h], v1 = inS[(size_t)s1*2+h];
        float4 v2 = inS[(size_t)s2*2+h], v3 = inS[(size_t)s3*2+h];
        float4 v4 = inS[(size_t)s4*2+h], v5 = inS[(size_t)s5*2+h];
        float4 v6 = inS[(size_t)s6*2+h], v7 = inS[(size_t)s7*2+h];
        ax += ((v0.x+v1.x)+(v2.x+v3.x)) + ((v4.x+v5.x)+(v6.x+v7.x));
        ay += ((v0.y+v1.y)+(v2.y+v3.y)) + ((v4.y+v5.y)+(v6.y+v7.y));
        az += ((v0.z+v1.z)+(v2.z+v3.z)) + ((v4.z+v5.z)+(v6.z+v7.z));
        aw += ((v0.w+v1.w)+(v2.w+v3.w)) + ((v4.w+v5.w)+(v6.w+v7.w));
    }
    if (i + 4 <= m) {
        int s0 = cp[i], s1 = cp[i+1], s2 = cp[i+2], s3 = cp[i+3];
        float4 v0 = inS[(size_t)s0*2+h], v1 = inS[(size_t)s1*2+h];
        float4 v2 = inS[(size_t)s2*2+h], v3 = inS[(size_t)s3*2+h];
        ax += (v0.x+v1.x)+(v2.x+v3.x);
        ay += (v0.y+v1.y)+(v2.y+v3.y);
        az += (v0.z+v1.z)+(v2.z+v3.z);
        aw += (v0.w+v1.w)+(v2.w+v3.w);
        i += 4;
    }
    for (; i < m; ++i) {
        int s = cp[i];
        float4 v = inS[(size_t)s*2+h];
        ax += v.x; ay += v.y; az += v.z; aw += v.w;
    }
    float dn = dinv[node];
    ax *= dn; ay *= dn; az *= dn; aw *= dn;
    if (ADD_BIAS) {
        float4 b4 = ((const float4*)bias)[sl * 2 + h];
        ax += b4.x; ay += b4.y; az += b4.z; aw += b4.w;
    }
    float4 res = make_float4(ax, ay, az, aw);
    if (OUT_ROWMAJOR) ((float4*)out)[(size_t)node * (C/4) + sl*2 + h] = res;
    else ((float4*)(out + (size_t)sl * N * 8))[(size_t)node * 2 + h] = res;
}

// ---------------- dense transform: out = [relu](in @ W [+b]) [*dinv] ----------------

template <int CIN, int COUT, bool RELU, bool BIAS, bool SCALE, bool OUT_ROWMAJOR>
__global__ __launch_bounds__(256) void gemm_kernel(
        const float* __restrict__ in, const float* __restrict__ W,
        const float* __restrict__ b, const float* __restrict__ dinv,
        float* __restrict__ out, int N) {
    constexpr int NPB = 256 / COUT;
    constexpr int PAD = CIN + 4;
    constexpr int K4 = CIN / 4;
    __shared__ float4 wt4[K4 * COUT];
    __shared__ float xs[NPB * PAD];
    __shared__ float bs[COUT];
    for (int i = threadIdx.x; i < K4 * COUT; i += 256) {
        int k4 = i / COUT, co = i % COUT;
        float4 w;
        w.x = W[(4*k4+0)*COUT + co];
        w.y = W[(4*k4+1)*COUT + co];
        w.z = W[(4*k4+2)*COUT + co];
        w.w = W[(4*k4+3)*COUT + co];
        wt4[i] = w;
    }
    if constexpr (BIAS) {
        for (int i = threadIdx.x; i < COUT; i += 256) bs[i] = b[i];
    }
    int r  = threadIdx.x / COUT;
    int co = threadIdx.x % COUT;
    int ngroups = (N + NPB - 1) / NPB;
    for (int grp = blockIdx.x; grp < ngroups; grp += gridDim.x) {
        int base = grp * NPB;
        __syncthreads();
        for (int i = threadIdx.x; i < NPB * CIN; i += 256) {
            int rr = i / CIN, k = i % CIN;
            int n = base + rr;
            xs[rr * PAD + k] = (n < N) ? in[(size_t)(k >> 3) * N * 8 + (size_t)n * 8 + (k & 7)] : 0.f;
        }
        __syncthreads();
        int n = base + r;
        if (n < N) {
            float acc0 = BIAS ? bs[co] : 0.f;
            float acc1 = 0.f;
            const float4* xv = (const float4*)(xs + r * PAD);
            #pragma unroll
            for (int k4 = 0; k4 < K4; k4 += 2) {
                float4 xk0 = xv[k4],     wk0 = wt4[k4 * COUT + co];
                float4 xk1 = xv[k4 + 1], wk1 = wt4[(k4 + 1) * COUT + co];
                acc0 += xk0.x*wk0.x + xk0.y*wk0.y + xk0.z*wk0.z + xk0.w*wk0.w;
                acc1 += xk1.x*wk1.x + xk1.y*wk1.y + xk1.z*wk1.z + xk1.w*wk1.w;
            }
            float acc = acc0 + acc1;
            if constexpr (RELU) acc = fmaxf(acc, 0.f);
            if constexpr (SCALE) acc *= dinv[n];
            if constexpr (OUT_ROWMAJOR) out[(size_t)n * COUT + co] = acc;
            else out[(size_t)(co >> 3) * N * 8 + (size_t)n * 8 + (co & 7)] = acc;
        }
    }
}

// ---------------- pooling over sorted batch ids (row-major input) ----------------

__global__ __launch_bounds__(256) void pool_kernel(
        const float* __restrict__ h, const int* __restrict__ batch,
        float* __restrict__ sums, int* __restrict__ cntb, int N) {
    const int CHUNK = 512;
    int chunkStart = blockIdx.x * CHUNK;
    int c = threadIdx.x & 63;
    int r = threadIdx.x >> 6;
    int curg = -1;
    float acc = 0.f;
    int cnt = 0;
    int end = chunkStart + CHUNK;
    if (end > N) end = N;
    for (int n = chunkStart + r; n < end; n += 4) {
        int g = batch[n];
        if (g != curg) {
            if (curg >= 0) {
                atomicAdd(&sums[curg * 64 + c], acc);
                if (c == 0) atomicAdd(&cntb[curg], cnt);
            }
            curg = g; acc = 0.f; cnt = 0;
        }
        acc += h[(size_t)n * 64 + c];
        cnt++;
    }
    if (curg >= 0) {
        atomicAdd(&sums[curg * 64 + c], acc);
        if (c == 0) atomicAdd(&cntb[curg], cnt);
    }
}

// ---------------- latent ----------------

__global__ __launch_bounds__(1024) void latent_kernel(
        const float* __restrict__ sums, const int* __restrict__ cntb,
        const float* __restrict__ Wp, const float* __restrict__ bp,
        const float* __restrict__ Wd, const float* __restrict__ bd,
        float* __restrict__ z_out, float* __restrict__ dg) {
    __shared__ float zl[NGRAPH * LAT];
    int t = threadIdx.x;
    {
        int g = t / LAT, l = t % LAT;
        float cf = (float)cntb[g];
        float inv = 1.0f / fmaxf(cf, 1.0f);
        float acc = bp[l];
        #pragma unroll
        for (int k = 0; k < HID; k++) acc += sums[g * HID + k] * inv * Wp[k * LAT + l];
        zl[t] = acc;
        z_out[t] = acc;
    }
    __syncthreads();
    #pragma unroll
    for (int i = 0; i < 4; i++) {
        int idx = t + i * 1024;
        int g = idx >> 6, c = idx & 63;
        float acc = bd[c];
        #pragma unroll
        for (int l = 0; l < LAT; l++) acc += zl[g * LAT + l] * Wd[l * HID + c];
        dg[idx] = fmaxf(acc, 0.f);
    }
}

// broadcast per-graph decoder input to nodes, sliced + dinv-prescaled
__global__ void bcast_kernel(const float* __restrict__ dg, const int* __restrict__ batch,
                             const float* __restrict__ dinv, float* __restrict__ d, int N) {
    int idx = blockIdx.x * 256 + threadIdx.x;   // over N*2
    if (idx >= N * 2) return;
    int n = idx >> 1, h = idx & 1;
    int sl = blockIdx.y;
    float4 v = ((const float4*)dg)[(size_t)batch[n] * 16 + sl * 2 + h];
    float dn = dinv[n];
    v.x *= dn; v.y *= dn; v.z *= dn; v.w *= dn;
    ((float4*)(d + (size_t)sl * N * 8))[idx] = v;
}

// ---------------- launch ----------------

extern "C" void kernel_launch(void* const* d_in, const int* in_sizes, int n_in,
                              void* d_out, int out_size, void* d_ws, size_t ws_size,
                              hipStream_t stream) {
    const float* x          = (const float*)d_in[0];
    const int*   ei         = (const int*)d_in[1];
    const int*   batch      = (const int*)d_in[2];
    const float* W_enc0     = (const float*)d_in[3];
    const float* b_enc0     = (const float*)d_in[4];
    const float* W_enc1     = (const float*)d_in[5];
    const float* b_enc1     = (const float*)d_in[6];
    const float* W_enc2     = (const float*)d_in[7];
    const float* b_enc2     = (const float*)d_in[8];
    const float* W_proj     = (const float*)d_in[9];
    const float* b_proj     = (const float*)d_in[10];
    const float* W_dec_proj = (const float*)d_in[11];
    const float* b_dec_proj = (const float*)d_in[12];
    const float* W_dec0     = (const float*)d_in[13];
    const float* b_dec0     = (const float*)d_in[14];
    const float* W_dec1     = (const float*)d_in[15];
    const float* b_dec1     = (const float*)d_in[16];

    const int N = in_sizes[0] / IN_CH;
    const int E = in_sizes[1] / 2;

    char* ws = (char*)d_ws;
    size_t off = 0;
    auto alloc = [&](size_t bytes) {
        void* p = ws + off;
        off += (bytes + 255) & ~(size_t)255;
        return p;
    };
    float* A       = (float*)alloc((size_t)N * HID * 4);   // aliases staged2
    float* B       = (float*)alloc((size_t)N * HID * 4);
    float* XS      = (float*)alloc((size_t)N * IN_CH * 4); // aliases staged1
    int*   col     = (int*)  alloc((size_t)E * 4);
    int*   cntn    = (int*)  alloc((size_t)N * 4);
    int*   cnt2    = (int*)  alloc((size_t)N * 4);
    int*   rowptr2 = (int*)  alloc((size_t)(N + 1) * 4);
    int*   cursor  = (int*)  alloc((size_t)N * 4);
    int*   perm    = (int*)  alloc((size_t)N * 4);
    int*   rank    = (int*)  alloc((size_t)N * 4);
    float* dinv    = (float*)alloc((size_t)N * 4);
    int nb = (N + 255) / 256;
    int*   bsum    = (int*)  alloc((size_t)nb * 4);
    int*   hist    = (int*)  alloc((size_t)NBUCKET * 4);
    int*   hcur    = (int*)  alloc((size_t)NBUCKET * 4);
    int*   bh      = (int*)  alloc(256 * 4);
    int*   bbaseD  = (int*)  alloc(257 * 4);
    int*   bbaseR  = (int*)  alloc(257 * 4);
    int*   gcurD   = (int*)  alloc(256 * 4);
    int*   gcurR   = (int*)  alloc(256 * 4);
    float* sums    = (float*)alloc((size_t)NGRAPH * HID * 4);
    int*   cntb    = (int*)  alloc((size_t)NGRAPH * 4);
    float* dg      = (float*)alloc((size_t)NGRAPH * HID * 4);

    u64* staged1 = (u64*)XS;   // 12.8MB, dead before slice_x writes XS
    u64* staged2 = (u64*)A;    // 12.8MB, dead before first agg writes A

    float* x_recon = (float*)d_out;
    float* z_out   = (float*)d_out + (size_t)N * IN_CH;

    hipMemsetAsync(cursor, 0, (size_t)N * 4, stream);
    hipMemsetAsync(hist,   0, (size_t)NBUCKET * 4, stream);
    hipMemsetAsync(hcur,   0, (size_t)NBUCKET * 4, stream);
    hipMemsetAsync(bh,     0, 256 * 4, stream);
    hipMemsetAsync(gcurD,  0, 256 * 4, stream);
    hipMemsetAsync(gcurR,  0, 256 * 4, stream);
    hipMemsetAsync(sums,   0, (size_t)NGRAPH * HID * 4, stream);
    hipMemsetAsync(cntb,   0, (size_t)NGRAPH * 4, stream);

    int ebins = (E + 2047) / 2048;
    int chunks = (N + 127) / 128;

    // CSR build + degree sort (binned, no random scatter)
    bhist_kernel<<<ebins, 256, 0, stream>>>(ei, bh, E);
    bscan_kernel<<<1, 256, 0, stream>>>(bh, bbaseD, E);
    bin_kernel<0><<<ebins, 256, 0, stream>>>(ei, nullptr, nullptr, bbaseD, gcurD, staged1, E);
    degb_kernel<<<256, 256, 0, stream>>>(staged1, bbaseD, cntn, dinv, N);
    hist_kernel<<<nb, 256, 0, stream>>>(cntn, hist, N);
    hscan_kernel<<<1, NBUCKET, 0, stream>>>(hist);
    scatter_kernel<<<nb, 256, 0, stream>>>(cntn, hist, hcur, perm, rank, cnt2, N);
    scan1_kernel<<<nb, 256, 0, stream>>>(cnt2, rowptr2, bsum, N);
    scan2_kernel<<<1, 512, 0, stream>>>(bsum, nb);
    scan3_kernel<<<nb, 256, 0, stream>>>(rowptr2, bsum, N);
    bbaser_kernel<<<2, 256, 0, stream>>>(rowptr2, bbaseR, N, E);
    bin_kernel<1><<<ebins, 256, 0, stream>>>(nullptr, staged1, rank, bbaseR, gcurR, staged2, E);
    csr_kernel<<<256 * KB_CSR, 256, 0, stream>>>(staged2, bbaseR, rowptr2, cursor, col);

    {
        dim3 g((N * 2 + 255) / 256, IN_CH / 8);
        slice_x_kernel<<<g, 256, 0, stream>>>(x, dinv, XS, N);
    }

    // encoder
    agg_kernel<IN_CH, false, false><<<chunks * 4, 256, 0, stream>>>(
        XS, A, rowptr2, cnt2, col, dinv, perm, nullptr, N);
    gemm_kernel<IN_CH, HID, true, true, true, false><<<2048, 256, 0, stream>>>(
        A, W_enc0, b_enc0, dinv, B, N);
    agg_kernel<HID, false, false><<<chunks * 8, 256, 0, stream>>>(
        B, A, rowptr2, cnt2, col, dinv, perm, nullptr, N);
    gemm_kernel<HID, HID, true, true, true, false><<<2048, 256, 0, stream>>>(
        A, W_enc1, b_enc1, dinv, B, N);
    agg_kernel<HID, false, false><<<chunks * 8, 256, 0, stream>>>(
        B, A, rowptr2, cnt2, col, dinv, perm, nullptr, N);
    gemm_kernel<HID, HID, true, true, false, true><<<2048, 256, 0, stream>>>(
        A, W_enc2, b_enc2, dinv, B, N);   // row-major out for pool, no dinv scale

    // pool + latent
    pool_kernel<<<(N + 511) / 512, 256, 0, stream>>>(B, batch, sums, cntb, N);
    latent_kernel<<<1, 1024, 0, stream>>>(sums, cntb, W_proj, b_proj, W_dec_proj, b_dec_proj, z_out, dg);

    // decoder
    {
        dim3 g((N * 2 + 255) / 256, HID / 8);
        bcast_kernel<<<g, 256, 0, stream>>>(dg, batch, dinv, A, N);
    }
    agg_kernel<HID, false, false><<<chunks * 8, 256, 0, stream>>>(
        A, B, rowptr2, cnt2, col, dinv, perm, nullptr, N);
    gemm_kernel<HID, HID, true, true, false, false><<<2048, 256, 0, stream>>>(
        B, W_dec0, b_dec0, dinv, A, N);
    gemm_kernel<HID, IN_CH, false, false, true, false><<<2048, 256, 0, stream>>>(
        A, W_dec1, nullptr, dinv, B, N);
    agg_kernel<IN_CH, true, true><<<chunks * 4, 256, 0, stream>>>(
        B, x_recon, rowptr2, cnt2, col, dinv, perm, b_dec1, N);
}

// Round 5
// 781.725 us; speedup vs baseline: 1.4938x; 1.0667x over previous
//
#include <hip/hip_runtime.h>
#include <hip/hip_bf16.h>

typedef unsigned long long u64;

static constexpr int IN_CH  = 32;
static constexpr int HID    = 64;
static constexpr int LAT    = 16;
static constexpr int NGRAPH = 64;
static constexpr int NBUCKET = 1024;   // degree buckets for counting sort
static constexpr int KB_CSR  = 24;     // blocks per bucket in csr_kernel

// RANK-SPACE pipeline: nodes are permuted by degree (rank r); ALL intermediate
// feature tensors, dinvR, batchR, and CSR (rowptr2/cnt2/col with col=rank[src])
// live in rank space. agg is fully sequential in r except the feature gather,
// which is confined to one L2-resident 3.2MB slice ([C/8][N][8] layout,
// blockIdx%NSL pins slice->XCD). Original order is restored only at the two
// row-major outputs (pool input, x_recon) via perm[] row scatter.
// All agg INPUTS pre-scaled by dinv; agg computes dn * (self + sum gathers).

// ---------------- bucket histogram of dst ----------------

__global__ __launch_bounds__(256) void bhist_kernel(const int* __restrict__ ei,
                                                    int* __restrict__ bh, int E) {
    __shared__ int lh[256];
    lh[threadIdx.x] = 0;
    __syncthreads();
    int base = blockIdx.x * 2048;
    #pragma unroll
    for (int j = 0; j < 8; j++) {
        int idx = base + j * 256 + threadIdx.x;
        if (idx < E) atomicAdd(&lh[ei[E + idx] >> 9], 1);
    }
    __syncthreads();
    if (lh[threadIdx.x]) atomicAdd(&bh[threadIdx.x], lh[threadIdx.x]);
}

__global__ __launch_bounds__(256) void bscan_kernel(const int* __restrict__ bh,
                                                    int* __restrict__ bbase, int E) {
    __shared__ int s[256];
    int t = threadIdx.x;
    int v = bh[t];
    s[t] = v;
    for (int off = 1; off < 256; off <<= 1) {
        __syncthreads();
        int x = (t >= off) ? s[t - off] : 0;
        __syncthreads();
        s[t] += x;
    }
    __syncthreads();
    bbase[t] = s[t] - v;
    if (t == 255) bbase[256] = E;
}

// ---------------- LDS counting-sort binning ----------------
// MODE 0: in = edge_index, key = dst, val = src, bin by dst>>9
// MODE 1: in = staged1 (dst,src), key = rank[dst], val = rank[src], bin by key>>9

template <int MODE>
__global__ __launch_bounds__(256) void bin_kernel(
        const int* __restrict__ ei, const u64* __restrict__ sin,
        const int* __restrict__ rank,
        const int* __restrict__ bbase, int* __restrict__ gcur,
        u64* __restrict__ sout, int E) {
    __shared__ int lhist[256], lscan[256], lcur[256], gbase[256];
    __shared__ u64 sbuf[2048];
    int tid = threadIdx.x;
    lhist[tid] = 0;
    __syncthreads();
    int base = blockIdx.x * 2048;
    int cnt = min(2048, E - base);
    int myb[8]; u64 myp[8];
    #pragma unroll
    for (int j = 0; j < 8; j++) {
        int idx = base + j * 256 + tid;
        myb[j] = -1;
        if (idx < E) {
            int key, val;
            if constexpr (MODE == 0) { key = ei[E + idx]; val = ei[idx]; }
            else {
                u64 p = sin[idx];
                key = rank[(int)(p >> 32)];
                val = rank[(int)(p & 0xffffffffu)];
            }
            int b = key >> 9;
            myb[j] = b;
            myp[j] = ((u64)(unsigned)key << 32) | (unsigned)val;
            atomicAdd(&lhist[b], 1);
        }
    }
    __syncthreads();
    int v = lhist[tid];
    lscan[tid] = v;
    for (int off = 1; off < 256; off <<= 1) {
        __syncthreads();
        int x = (tid >= off) ? lscan[tid - off] : 0;
        __syncthreads();
        lscan[tid] += x;
    }
    __syncthreads();
    int excl = lscan[tid] - v;
    __syncthreads();
    lscan[tid] = excl;
    lcur[tid] = excl;
    __syncthreads();
    #pragma unroll
    for (int j = 0; j < 8; j++) {
        if (myb[j] >= 0) {
            int pos = atomicAdd(&lcur[myb[j]], 1);
            sbuf[pos] = myp[j];
        }
    }
    gbase[tid] = v ? atomicAdd(&gcur[tid], v) : 0;
    __syncthreads();
    for (int i = tid; i < cnt; i += 256) {
        u64 p = sbuf[i];
        int b = (int)(p >> 41);   // key>>9
        sout[bbase[b] + gbase[b] + (i - lscan[b])] = p;
    }
}

// ---------------- per-bucket degree (no atomics to global) ----------------

__global__ __launch_bounds__(256) void degb_kernel(
        const u64* __restrict__ staged, const int* __restrict__ bbase,
        int* __restrict__ cnt, int N) {
    __shared__ int ldeg[512];
    int b = blockIdx.x;
    ldeg[threadIdx.x] = 0;
    ldeg[threadIdx.x + 256] = 0;
    __syncthreads();
    int s0 = bbase[b], s1 = bbase[b + 1];
    for (int i = s0 + threadIdx.x; i < s1; i += 256)
        atomicAdd(&ldeg[(int)(staged[i] >> 32) - (b << 9)], 1);
    __syncthreads();
    #pragma unroll
    for (int j = 0; j < 2; j++) {
        int t = threadIdx.x + j * 256;
        int n = (b << 9) + t;
        if (n < N) cnt[n] = ldeg[t];
    }
}

// ---------------- counting sort by degree ----------------

__global__ __launch_bounds__(256) void hist_kernel(const int* __restrict__ cnt,
                                                   int* __restrict__ hist, int N) {
    __shared__ int lh[NBUCKET];
    for (int i = threadIdx.x; i < NBUCKET; i += 256) lh[i] = 0;
    __syncthreads();
    int n = blockIdx.x * 256 + threadIdx.x;
    if (n < N) atomicAdd(&lh[min(cnt[n], NBUCKET - 1)], 1);
    __syncthreads();
    for (int i = threadIdx.x; i < NBUCKET; i += 256)
        if (lh[i]) atomicAdd(&hist[i], lh[i]);
}

__global__ __launch_bounds__(1024) void hscan_kernel(int* hist) {
    __shared__ int s[NBUCKET];
    int t = threadIdx.x;
    int v = hist[t];
    s[t] = v;
    for (int off = 1; off < NBUCKET; off <<= 1) {
        __syncthreads();
        int x = (t >= off) ? s[t - off] : 0;
        __syncthreads();
        s[t] += x;
    }
    hist[t] = s[t] - v;   // exclusive
}

__global__ __launch_bounds__(256) void scatter_kernel(
        const int* __restrict__ cnt, const int* __restrict__ batch,
        const int* __restrict__ hoff, int* __restrict__ hcur,
        int* __restrict__ perm, int* __restrict__ rank, int* __restrict__ cnt2,
        float* __restrict__ dinvR, int* __restrict__ batchR, int N) {
    __shared__ int lh[NBUCKET];
    __shared__ int gb[NBUCKET];
    for (int i = threadIdx.x; i < NBUCKET; i += 256) lh[i] = 0;
    __syncthreads();
    int n = blockIdx.x * 256 + threadIdx.x;
    int b = -1, lpos = 0, d = 0;
    if (n < N) {
        d = cnt[n];
        b = min(d, NBUCKET - 1);
        lpos = atomicAdd(&lh[b], 1);
    }
    __syncthreads();
    for (int i = threadIdx.x; i < NBUCKET; i += 256)
        gb[i] = lh[i] ? atomicAdd(&hcur[i], lh[i]) : 0;
    __syncthreads();
    if (n < N) {
        int r = hoff[b] + gb[b] + lpos;
        perm[r] = n;
        rank[n] = r;
        cnt2[r] = d;
        dinvR[r] = rsqrtf((float)d + 1.0f);
        batchR[r] = batch[n];
    }
}

// ---------------- exclusive scan of cnt2 -> rowptr2 ----------------

__global__ void scan1_kernel(const int* __restrict__ cnt, int* __restrict__ rowptr,
                             int* __restrict__ bsum, int N) {
    __shared__ int s[256];
    int i = blockIdx.x * 256 + threadIdx.x;
    int v = (i < N) ? cnt[i] : 0;
    s[threadIdx.x] = v;
    for (int off = 1; off < 256; off <<= 1) {
        __syncthreads();
        int t = (threadIdx.x >= off) ? s[threadIdx.x - off] : 0;
        __syncthreads();
        s[threadIdx.x] += t;
    }
    if (i < N) rowptr[i] = s[threadIdx.x] - v;
    if (threadIdx.x == 255) bsum[blockIdx.x] = s[255];
}

__global__ __launch_bounds__(512) void scan2_kernel(int* bsum, int nb) {
    __shared__ int s[512];
    int t = threadIdx.x;
    int v = (t < nb) ? bsum[t] : 0;
    s[t] = v;
    for (int off = 1; off < 512; off <<= 1) {
        __syncthreads();
        int x = (t >= off) ? s[t - off] : 0;
        __syncthreads();
        s[t] += x;
    }
    if (t < nb) bsum[t] = s[t] - v;
}

__global__ void scan3_kernel(int* __restrict__ rowptr, const int* __restrict__ bsum, int N) {
    int i = blockIdx.x * 256 + threadIdx.x;
    if (i < N) rowptr[i] += bsum[blockIdx.x];
}

__global__ void bbaser_kernel(const int* __restrict__ rowptr2, int* __restrict__ bbase,
                              int N, int E) {
    int t = blockIdx.x * blockDim.x + threadIdx.x;
    if (t <= 256) bbase[t] = ((t << 9) >= N) ? E : rowptr2[t << 9];
}

// ---------------- bucket-local CSR fill ----------------

__global__ __launch_bounds__(256) void csr_kernel(
        const u64* __restrict__ staged, const int* __restrict__ bbase,
        const int* __restrict__ rowptr2, int* __restrict__ cur,
        int* __restrict__ col) {
    int bucket = blockIdx.x & 255;
    int k = blockIdx.x >> 8;
    int s0 = bbase[bucket], s1 = bbase[bucket + 1];
    for (int i = s0 + k * 256 + threadIdx.x; i < s1; i += 256 * KB_CSR) {
        u64 p = staged[i];
        int r = (int)(p >> 32);
        int pos = rowptr2[r] + atomicAdd(&cur[r], 1);
        col[pos] = (int)(p & 0xffffffffu);
    }
}

// ---------------- x -> rank-space sliced layout, pre-scaled ----------------

__global__ void slice_x_kernel(const float* __restrict__ x, const int* __restrict__ perm,
                               const float* __restrict__ dinvR,
                               float* __restrict__ xs, int N) {
    int idx = blockIdx.x * 256 + threadIdx.x;   // over N*2
    if (idx >= N * 2) return;
    int r = idx >> 1, h = idx & 1;
    int sl = blockIdx.y;
    int n = perm[r];
    float4 v = ((const float4*)x)[(size_t)n * 8 + sl * 2 + h];
    float dn = dinvR[r];
    v.x *= dn; v.y *= dn; v.z *= dn; v.w *= dn;
    ((float4*)(xs + (size_t)sl * N * 8))[idx] = v;
}

// ---------------- aggregation (rank space; all-sequential except gather) ----------------
// out[r] = dinvR[r] * (in[r] + sum_{sr in row r} in[sr])   [+bias]

template <int C, bool ADD_BIAS, bool OUT_ROWMAJOR>
__global__ __launch_bounds__(256) void agg_kernel(
        const float* __restrict__ in, float* __restrict__ out,
        const int* __restrict__ rowptr2, const int* __restrict__ cnt2,
        const int* __restrict__ col, const float* __restrict__ dinvR,
        const int* __restrict__ perm, const float* __restrict__ bias, int N) {
    constexpr int NSL = C / 8;
    int sl = blockIdx.x % NSL;
    int chunk = blockIdx.x / NSL;
    int slot = threadIdx.x >> 1;
    int h = threadIdx.x & 1;
    int r = chunk * 128 + slot;
    if (r >= N) return;
    const float4* inS = (const float4*)(in + (size_t)sl * N * 8);
    int start = rowptr2[r];
    int m = cnt2[r];
    const int* cp = col + start;
    float4 a = inS[(size_t)r * 2 + h];
    float ax = a.x, ay = a.y, az = a.z, aw = a.w;
    int i = 0;
    for (; i + 8 <= m; i += 8) {
        int s0 = cp[i], s1 = cp[i+1], s2 = cp[i+2], s3 = cp[i+3];
        int s4 = cp[i+4], s5 = cp[i+5], s6 = cp[i+6], s7 = cp[i+7];
        float4 v0 = inS[(size_t)s0*2+h], v1 = inS[(size_t)s1*2+h];
        float4 v2 = inS[(size_t)s2*2+h], v3 = inS[(size_t)s3*2+h];
        float4 v4 = inS[(size_t)s4*2+h], v5 = inS[(size_t)s5*2+h];
        float4 v6 = inS[(size_t)s6*2+h], v7 = inS[(size_t)s7*2+h];
        ax += ((v0.x+v1.x)+(v2.x+v3.x)) + ((v4.x+v5.x)+(v6.x+v7.x));
        ay += ((v0.y+v1.y)+(v2.y+v3.y)) + ((v4.y+v5.y)+(v6.y+v7.y));
        az += ((v0.z+v1.z)+(v2.z+v3.z)) + ((v4.z+v5.z)+(v6.z+v7.z));
        aw += ((v0.w+v1.w)+(v2.w+v3.w)) + ((v4.w+v5.w)+(v6.w+v7.w));
    }
    if (i + 4 <= m) {
        int s0 = cp[i], s1 = cp[i+1], s2 = cp[i+2], s3 = cp[i+3];
        float4 v0 = inS[(size_t)s0*2+h], v1 = inS[(size_t)s1*2+h];
        float4 v2 = inS[(size_t)s2*2+h], v3 = inS[(size_t)s3*2+h];
        ax += (v0.x+v1.x)+(v2.x+v3.x);
        ay += (v0.y+v1.y)+(v2.y+v3.y);
        az += (v0.z+v1.z)+(v2.z+v3.z);
        aw += (v0.w+v1.w)+(v2.w+v3.w);
        i += 4;
    }
    for (; i < m; ++i) {
        int s = cp[i];
        float4 v = inS[(size_t)s*2+h];
        ax += v.x; ay += v.y; az += v.z; aw += v.w;
    }
    float dn = dinvR[r];
    ax *= dn; ay *= dn; az *= dn; aw *= dn;
    if (ADD_BIAS) {
        float4 b4 = ((const float4*)bias)[sl * 2 + h];
        ax += b4.x; ay += b4.y; az += b4.z; aw += b4.w;
    }
    float4 res = make_float4(ax, ay, az, aw);
    if (OUT_ROWMAJOR) {
        int node = perm[r];
        ((float4*)out)[(size_t)node * (C/4) + sl*2 + h] = res;
    } else {
        ((float4*)(out + (size_t)sl * N * 8))[(size_t)r * 2 + h] = res;
    }
}

// ---------------- dense transform (rank space): out = [relu](in @ W [+b]) [*dinvR] ----------------

template <int CIN, int COUT, bool RELU, bool BIAS, bool SCALE, bool OUT_ROWMAJOR>
__global__ __launch_bounds__(256) void gemm_kernel(
        const float* __restrict__ in, const float* __restrict__ W,
        const float* __restrict__ b, const float* __restrict__ dinvR,
        const int* __restrict__ perm, float* __restrict__ out, int N) {
    constexpr int NPB = 256 / COUT;
    constexpr int PAD = CIN + 4;
    constexpr int K4 = CIN / 4;
    __shared__ float4 wt4[K4 * COUT];
    __shared__ float xs[NPB * PAD];
    __shared__ float bs[COUT];
    for (int i = threadIdx.x; i < K4 * COUT; i += 256) {
        int k4 = i / COUT, co = i % COUT;
        float4 w;
        w.x = W[(4*k4+0)*COUT + co];
        w.y = W[(4*k4+1)*COUT + co];
        w.z = W[(4*k4+2)*COUT + co];
        w.w = W[(4*k4+3)*COUT + co];
        wt4[i] = w;
    }
    if constexpr (BIAS) {
        for (int i = threadIdx.x; i < COUT; i += 256) bs[i] = b[i];
    }
    int r  = threadIdx.x / COUT;
    int co = threadIdx.x % COUT;
    int ngroups = (N + NPB - 1) / NPB;
    for (int grp = blockIdx.x; grp < ngroups; grp += gridDim.x) {
        int base = grp * NPB;
        __syncthreads();
        for (int i = threadIdx.x; i < NPB * CIN; i += 256) {
            int rr = i / CIN, k = i % CIN;
            int n = base + rr;
            xs[rr * PAD + k] = (n < N) ? in[(size_t)(k >> 3) * N * 8 + (size_t)n * 8 + (k & 7)] : 0.f;
        }
        __syncthreads();
        int n = base + r;
        if (n < N) {
            float acc0 = BIAS ? bs[co] : 0.f;
            float acc1 = 0.f;
            const float4* xv = (const float4*)(xs + r * PAD);
            #pragma unroll
            for (int k4 = 0; k4 < K4; k4 += 2) {
                float4 xk0 = xv[k4],     wk0 = wt4[k4 * COUT + co];
                float4 xk1 = xv[k4 + 1], wk1 = wt4[(k4 + 1) * COUT + co];
                acc0 += xk0.x*wk0.x + xk0.y*wk0.y + xk0.z*wk0.z + xk0.w*wk0.w;
                acc1 += xk1.x*wk1.x + xk1.y*wk1.y + xk1.z*wk1.z + xk1.w*wk1.w;
            }
            float acc = acc0 + acc1;
            if constexpr (RELU) acc = fmaxf(acc, 0.f);
            if constexpr (SCALE) acc *= dinvR[n];
            if constexpr (OUT_ROWMAJOR) out[(size_t)perm[n] * COUT + co] = acc;
            else out[(size_t)(co >> 3) * N * 8 + (size_t)n * 8 + (co & 7)] = acc;
        }
    }
}

// ---------------- pooling over sorted batch ids (row-major, original order) ----------------

__global__ __launch_bounds__(256) void pool_kernel(
        const float* __restrict__ h, const int* __restrict__ batch,
        float* __restrict__ sums, int* __restrict__ cntb, int N) {
    const int CHUNK = 512;
    int chunkStart = blockIdx.x * CHUNK;
    int c = threadIdx.x & 63;
    int r = threadIdx.x >> 6;
    int curg = -1;
    float acc = 0.f;
    int cnt = 0;
    int end = chunkStart + CHUNK;
    if (end > N) end = N;
    for (int n = chunkStart + r; n < end; n += 4) {
        int g = batch[n];
        if (g != curg) {
            if (curg >= 0) {
                atomicAdd(&sums[curg * 64 + c], acc);
                if (c == 0) atomicAdd(&cntb[curg], cnt);
            }
            curg = g; acc = 0.f; cnt = 0;
        }
        acc += h[(size_t)n * 64 + c];
        cnt++;
    }
    if (curg >= 0) {
        atomicAdd(&sums[curg * 64 + c], acc);
        if (c == 0) atomicAdd(&cntb[curg], cnt);
    }
}

// ---------------- latent ----------------

__global__ __launch_bounds__(1024) void latent_kernel(
        const float* __restrict__ sums, const int* __restrict__ cntb,
        const float* __restrict__ Wp, const float* __restrict__ bp,
        const float* __restrict__ Wd, const float* __restrict__ bd,
        float* __restrict__ z_out, float* __restrict__ dg) {
    __shared__ float zl[NGRAPH * LAT];
    int t = threadIdx.x;
    {
        int g = t / LAT, l = t % LAT;
        float cf = (float)cntb[g];
        float inv = 1.0f / fmaxf(cf, 1.0f);
        float acc = bp[l];
        #pragma unroll
        for (int k = 0; k < HID; k++) acc += sums[g * HID + k] * inv * Wp[k * LAT + l];
        zl[t] = acc;
        z_out[t] = acc;
    }
    __syncthreads();
    #pragma unroll
    for (int i = 0; i < 4; i++) {
        int idx = t + i * 1024;
        int g = idx >> 6, c = idx & 63;
        float acc = bd[c];
        #pragma unroll
        for (int l = 0; l < LAT; l++) acc += zl[g * LAT + l] * Wd[l * HID + c];
        dg[idx] = fmaxf(acc, 0.f);
    }
}

// broadcast per-graph decoder input to rank space, sliced + dinv-prescaled
__global__ void bcast_kernel(const float* __restrict__ dg, const int* __restrict__ batchR,
                             const float* __restrict__ dinvR, float* __restrict__ d, int N) {
    int idx = blockIdx.x * 256 + threadIdx.x;   // over N*2
    if (idx >= N * 2) return;
    int r = idx >> 1, h = idx & 1;
    int sl = blockIdx.y;
    float4 v = ((const float4*)dg)[(size_t)batchR[r] * 16 + sl * 2 + h];
    float dn = dinvR[r];
    v.x *= dn; v.y *= dn; v.z *= dn; v.w *= dn;
    ((float4*)(d + (size_t)sl * N * 8))[idx] = v;
}

// ---------------- launch ----------------

extern "C" void kernel_launch(void* const* d_in, const int* in_sizes, int n_in,
                              void* d_out, int out_size, void* d_ws, size_t ws_size,
                              hipStream_t stream) {
    const float* x          = (const float*)d_in[0];
    const int*   ei         = (const int*)d_in[1];
    const int*   batch      = (const int*)d_in[2];
    const float* W_enc0     = (const float*)d_in[3];
    const float* b_enc0     = (const float*)d_in[4];
    const float* W_enc1     = (const float*)d_in[5];
    const float* b_enc1     = (const float*)d_in[6];
    const float* W_enc2     = (const float*)d_in[7];
    const float* b_enc2     = (const float*)d_in[8];
    const float* W_proj     = (const float*)d_in[9];
    const float* b_proj     = (const float*)d_in[10];
    const float* W_dec_proj = (const float*)d_in[11];
    const float* b_dec_proj = (const float*)d_in[12];
    const float* W_dec0     = (const float*)d_in[13];
    const float* b_dec0     = (const float*)d_in[14];
    const float* W_dec1     = (const float*)d_in[15];
    const float* b_dec1     = (const float*)d_in[16];

    const int N = in_sizes[0] / IN_CH;
    const int E = in_sizes[1] / 2;

    char* ws = (char*)d_ws;
    size_t off = 0;
    auto alloc = [&](size_t bytes) {
        void* p = ws + off;
        off += (bytes + 255) & ~(size_t)255;
        return p;
    };
    float* A       = (float*)alloc((size_t)N * HID * 4);   // aliases staged2
    float* B       = (float*)alloc((size_t)N * HID * 4);
    float* XS      = (float*)alloc((size_t)N * IN_CH * 4); // aliases staged1
    int*   col     = (int*)  alloc((size_t)E * 4);
    int*   cntn    = (int*)  alloc((size_t)N * 4);
    int*   cnt2    = (int*)  alloc((size_t)N * 4);
    int*   rowptr2 = (int*)  alloc((size_t)(N + 1) * 4);
    int*   cursor  = (int*)  alloc((size_t)N * 4);
    int*   perm    = (int*)  alloc((size_t)N * 4);
    int*   rank    = (int*)  alloc((size_t)N * 4);
    float* dinvR   = (float*)alloc((size_t)N * 4);
    int*   batchR  = (int*)  alloc((size_t)N * 4);
    int nb = (N + 255) / 256;
    int*   bsum    = (int*)  alloc((size_t)nb * 4);
    int*   hist    = (int*)  alloc((size_t)NBUCKET * 4);
    int*   hcur    = (int*)  alloc((size_t)NBUCKET * 4);
    int*   bh      = (int*)  alloc(256 * 4);
    int*   bbaseD  = (int*)  alloc(257 * 4);
    int*   bbaseR  = (int*)  alloc(257 * 4);
    int*   gcurD   = (int*)  alloc(256 * 4);
    int*   gcurR   = (int*)  alloc(256 * 4);
    float* sums    = (float*)alloc((size_t)NGRAPH * HID * 4);
    int*   cntb    = (int*)  alloc((size_t)NGRAPH * 4);
    float* dg      = (float*)alloc((size_t)NGRAPH * HID * 4);

    u64* staged1 = (u64*)XS;   // 12.8MB, dead before slice_x writes XS
    u64* staged2 = (u64*)A;    // 12.8MB, dead before first agg writes A

    float* x_recon = (float*)d_out;
    float* z_out   = (float*)d_out + (size_t)N * IN_CH;

    hipMemsetAsync(cursor, 0, (size_t)N * 4, stream);
    hipMemsetAsync(hist,   0, (size_t)NBUCKET * 4, stream);
    hipMemsetAsync(hcur,   0, (size_t)NBUCKET * 4, stream);
    hipMemsetAsync(bh,     0, 256 * 4, stream);
    hipMemsetAsync(gcurD,  0, 256 * 4, stream);
    hipMemsetAsync(gcurR,  0, 256 * 4, stream);
    hipMemsetAsync(sums,   0, (size_t)NGRAPH * HID * 4, stream);
    hipMemsetAsync(cntb,   0, (size_t)NGRAPH * 4, stream);

    int ebins = (E + 2047) / 2048;
    int chunks = (N + 127) / 128;

    // CSR build + degree sort (binned, no random scatter)
    bhist_kernel<<<ebins, 256, 0, stream>>>(ei, bh, E);
    bscan_kernel<<<1, 256, 0, stream>>>(bh, bbaseD, E);
    bin_kernel<0><<<ebins, 256, 0, stream>>>(ei, nullptr, nullptr, bbaseD, gcurD, staged1, E);
    degb_kernel<<<256, 256, 0, stream>>>(staged1, bbaseD, cntn, N);
    hist_kernel<<<nb, 256, 0, stream>>>(cntn, hist, N);
    hscan_kernel<<<1, NBUCKET, 0, stream>>>(hist);
    scatter_kernel<<<nb, 256, 0, stream>>>(cntn, batch, hist, hcur, perm, rank, cnt2,
                                           dinvR, batchR, N);
    scan1_kernel<<<nb, 256, 0, stream>>>(cnt2, rowptr2, bsum, N);
    scan2_kernel<<<1, 512, 0, stream>>>(bsum, nb);
    scan3_kernel<<<nb, 256, 0, stream>>>(rowptr2, bsum, N);
    bbaser_kernel<<<2, 256, 0, stream>>>(rowptr2, bbaseR, N, E);
    bin_kernel<1><<<ebins, 256, 0, stream>>>(nullptr, staged1, rank, bbaseR, gcurR, staged2, E);
    csr_kernel<<<256 * KB_CSR, 256, 0, stream>>>(staged2, bbaseR, rowptr2, cursor, col);

    {
        dim3 g((N * 2 + 255) / 256, IN_CH / 8);
        slice_x_kernel<<<g, 256, 0, stream>>>(x, perm, dinvR, XS, N);
    }

    // encoder (all rank space)
    agg_kernel<IN_CH, false, false><<<chunks * 4, 256, 0, stream>>>(
        XS, A, rowptr2, cnt2, col, dinvR, perm, nullptr, N);
    gemm_kernel<IN_CH, HID, true, true, true, false><<<2048, 256, 0, stream>>>(
        A, W_enc0, b_enc0, dinvR, perm, B, N);
    agg_kernel<HID, false, false><<<chunks * 8, 256, 0, stream>>>(
        B, A, rowptr2, cnt2, col, dinvR, perm, nullptr, N);
    gemm_kernel<HID, HID, true, true, true, false><<<2048, 256, 0, stream>>>(
        A, W_enc1, b_enc1, dinvR, perm, B, N);
    agg_kernel<HID, false, false><<<chunks * 8, 256, 0, stream>>>(
        B, A, rowptr2, cnt2, col, dinvR, perm, nullptr, N);
    gemm_kernel<HID, HID, true, true, false, true><<<2048, 256, 0, stream>>>(
        A, W_enc2, b_enc2, dinvR, perm, B, N);   // scatter to ORIGINAL order for pool

    // pool + latent
    pool_kernel<<<(N + 511) / 512, 256, 0, stream>>>(B, batch, sums, cntb, N);
    latent_kernel<<<1, 1024, 0, stream>>>(sums, cntb, W_proj, b_proj, W_dec_proj, b_dec_proj, z_out, dg);

    // decoder (rank space)
    {
        dim3 g((N * 2 + 255) / 256, HID / 8);
        bcast_kernel<<<g, 256, 0, stream>>>(dg, batchR, dinvR, A, N);
    }
    agg_kernel<HID, false, false><<<chunks * 8, 256, 0, stream>>>(
        A, B, rowptr2, cnt2, col, dinvR, perm, nullptr, N);
    gemm_kernel<HID, HID, true, true, false, false><<<2048, 256, 0, stream>>>(
        B, W_dec0, b_dec0, dinvR, perm, A, N);
    gemm_kernel<HID, IN_CH, false, false, true, false><<<2048, 256, 0, stream>>>(
        A, W_dec1, nullptr, dinvR, perm, B, N);
    agg_kernel<IN_CH, true, true><<<chunks * 4, 256, 0, stream>>>(
        B, x_recon, rowptr2, cnt2, col, dinvR, perm, b_dec1, N);
}

// Round 6
// 739.916 us; speedup vs baseline: 1.5782x; 1.0565x over previous
//
#include <hip/hip_runtime.h>
#include <hip/hip_bf16.h>

typedef unsigned long long u64;

static constexpr int IN_CH  = 32;
static constexpr int HID    = 64;
static constexpr int LAT    = 16;
static constexpr int NGRAPH = 64;
static constexpr int NBUCKET = 1024;   // degree buckets for counting sort
static constexpr int KB_CSR  = 24;     // blocks per bucket in csr_kernel

// RANK-SPACE pipeline (see R4/R5): nodes permuted by degree; feature tensors,
// dinvR, pgR, CSR all in rank space. Sliced [C/8][N][8] layout keeps each
// gather slice L2-resident per XCD. All agg inputs pre-scaled by dinv.
// R6: edge-split agg (col bytes halved via pair shfl-combine), dec-conv0 as
// LDS group-agg (input has only 64 distinct rows), W-in-registers gemm,
// fused memsets/hist/bbaser.

__device__ inline void add4(float4& a, const float4& b) {
    a.x += b.x; a.y += b.y; a.z += b.z; a.w += b.w;
}
__device__ inline float4 shfl_xor_f4(float4 v, int mask) {
    float4 r;
    r.x = __shfl_xor(v.x, mask);
    r.y = __shfl_xor(v.y, mask);
    r.z = __shfl_xor(v.z, mask);
    r.w = __shfl_xor(v.w, mask);
    return r;
}

// ---------------- bucket histogram of dst ----------------

__global__ __launch_bounds__(256) void bhist_kernel(const int* __restrict__ ei,
                                                    int* __restrict__ bh, int E) {
    __shared__ int lh[256];
    lh[threadIdx.x] = 0;
    __syncthreads();
    int base = blockIdx.x * 2048;
    #pragma unroll
    for (int j = 0; j < 8; j++) {
        int idx = base + j * 256 + threadIdx.x;
        if (idx < E) atomicAdd(&lh[ei[E + idx] >> 9], 1);
    }
    __syncthreads();
    if (lh[threadIdx.x]) atomicAdd(&bh[threadIdx.x], lh[threadIdx.x]);
}

__global__ __launch_bounds__(256) void bscan_kernel(const int* __restrict__ bh,
                                                    int* __restrict__ bbase, int E) {
    __shared__ int s[256];
    int t = threadIdx.x;
    int v = bh[t];
    s[t] = v;
    for (int off = 1; off < 256; off <<= 1) {
        __syncthreads();
        int x = (t >= off) ? s[t - off] : 0;
        __syncthreads();
        s[t] += x;
    }
    __syncthreads();
    bbase[t] = s[t] - v;
    if (t == 255) bbase[256] = E;
}

// ---------------- LDS counting-sort binning ----------------
// MODE 0: in = edge_index, key = dst, val = src, bin by dst>>9
// MODE 1: in = staged1 (dst,src), key = rank[dst], val = rank[src], bin by key>>9

template <int MODE>
__global__ __launch_bounds__(256) void bin_kernel(
        const int* __restrict__ ei, const u64* __restrict__ sin,
        const int* __restrict__ rank,
        const int* __restrict__ bbase, int* __restrict__ gcur,
        u64* __restrict__ sout, int E) {
    __shared__ int lhist[256], lscan[256], lcur[256], gbase[256];
    __shared__ u64 sbuf[2048];
    int tid = threadIdx.x;
    lhist[tid] = 0;
    __syncthreads();
    int base = blockIdx.x * 2048;
    int cnt = min(2048, E - base);
    int myb[8]; u64 myp[8];
    #pragma unroll
    for (int j = 0; j < 8; j++) {
        int idx = base + j * 256 + tid;
        myb[j] = -1;
        if (idx < E) {
            int key, val;
            if constexpr (MODE == 0) { key = ei[E + idx]; val = ei[idx]; }
            else {
                u64 p = sin[idx];
                key = rank[(int)(p >> 32)];
                val = rank[(int)(p & 0xffffffffu)];
            }
            int b = key >> 9;
            myb[j] = b;
            myp[j] = ((u64)(unsigned)key << 32) | (unsigned)val;
            atomicAdd(&lhist[b], 1);
        }
    }
    __syncthreads();
    int v = lhist[tid];
    lscan[tid] = v;
    for (int off = 1; off < 256; off <<= 1) {
        __syncthreads();
        int x = (tid >= off) ? lscan[tid - off] : 0;
        __syncthreads();
        lscan[tid] += x;
    }
    __syncthreads();
    int excl = lscan[tid] - v;
    __syncthreads();
    lscan[tid] = excl;
    lcur[tid] = excl;
    __syncthreads();
    #pragma unroll
    for (int j = 0; j < 8; j++) {
        if (myb[j] >= 0) {
            int pos = atomicAdd(&lcur[myb[j]], 1);
            sbuf[pos] = myp[j];
        }
    }
    gbase[tid] = v ? atomicAdd(&gcur[tid], v) : 0;
    __syncthreads();
    for (int i = tid; i < cnt; i += 256) {
        u64 p = sbuf[i];
        int b = (int)(p >> 41);   // key>>9
        sout[bbase[b] + gbase[b] + (i - lscan[b])] = p;
    }
}

// ---------------- per-bucket degree + degree-histogram (fused) ----------------

__global__ __launch_bounds__(256) void degb_kernel(
        const u64* __restrict__ staged, const int* __restrict__ bbase,
        int* __restrict__ cnt, int* __restrict__ hist, int N) {
    __shared__ int ldeg[512];
    __shared__ int lhist[NBUCKET];
    int b = blockIdx.x;
    ldeg[threadIdx.x] = 0;
    ldeg[threadIdx.x + 256] = 0;
    for (int i = threadIdx.x; i < NBUCKET; i += 256) lhist[i] = 0;
    __syncthreads();
    int s0 = bbase[b], s1 = bbase[b + 1];
    for (int i = s0 + threadIdx.x; i < s1; i += 256)
        atomicAdd(&ldeg[(int)(staged[i] >> 32) - (b << 9)], 1);
    __syncthreads();
    #pragma unroll
    for (int j = 0; j < 2; j++) {
        int t = threadIdx.x + j * 256;
        int n = (b << 9) + t;
        if (n < N) {
            int d = ldeg[t];
            cnt[n] = d;
            atomicAdd(&lhist[min(d, NBUCKET - 1)], 1);
        }
    }
    __syncthreads();
    for (int i = threadIdx.x; i < NBUCKET; i += 256)
        if (lhist[i]) atomicAdd(&hist[i], lhist[i]);
}

__global__ __launch_bounds__(1024) void hscan_kernel(int* hist) {
    __shared__ int s[NBUCKET];
    int t = threadIdx.x;
    int v = hist[t];
    s[t] = v;
    for (int off = 1; off < NBUCKET; off <<= 1) {
        __syncthreads();
        int x = (t >= off) ? s[t - off] : 0;
        __syncthreads();
        s[t] += x;
    }
    hist[t] = s[t] - v;   // exclusive
}

__global__ __launch_bounds__(256) void scatter_kernel(
        const int* __restrict__ cnt, const int* __restrict__ batch,
        const int* __restrict__ hoff, int* __restrict__ hcur,
        int* __restrict__ perm, int* __restrict__ rank, int* __restrict__ cnt2,
        float* __restrict__ dinvR, float2* __restrict__ pgR, int N) {
    __shared__ int lh[NBUCKET];
    __shared__ int gb[NBUCKET];
    for (int i = threadIdx.x; i < NBUCKET; i += 256) lh[i] = 0;
    __syncthreads();
    int n = blockIdx.x * 256 + threadIdx.x;
    int b = -1, lpos = 0, d = 0;
    if (n < N) {
        d = cnt[n];
        b = min(d, NBUCKET - 1);
        lpos = atomicAdd(&lh[b], 1);
    }
    __syncthreads();
    for (int i = threadIdx.x; i < NBUCKET; i += 256)
        gb[i] = lh[i] ? atomicAdd(&hcur[i], lh[i]) : 0;
    __syncthreads();
    if (n < N) {
        int r = hoff[b] + gb[b] + lpos;
        perm[r] = n;
        rank[n] = r;
        cnt2[r] = d;
        float dv = rsqrtf((float)d + 1.0f);
        dinvR[r] = dv;
        pgR[r] = make_float2(dv, __int_as_float(batch[n]));
    }
}

// ---------------- exclusive scan of cnt2 -> rowptr2 ----------------

__global__ void scan1_kernel(const int* __restrict__ cnt, int* __restrict__ rowptr,
                             int* __restrict__ bsum, int N) {
    __shared__ int s[256];
    int i = blockIdx.x * 256 + threadIdx.x;
    int v = (i < N) ? cnt[i] : 0;
    s[threadIdx.x] = v;
    for (int off = 1; off < 256; off <<= 1) {
        __syncthreads();
        int t = (threadIdx.x >= off) ? s[threadIdx.x - off] : 0;
        __syncthreads();
        s[threadIdx.x] += t;
    }
    if (i < N) rowptr[i] = s[threadIdx.x] - v;
    if (threadIdx.x == 255) bsum[blockIdx.x] = s[255];
}

__global__ __launch_bounds__(512) void scan2_kernel(int* bsum, int nb) {
    __shared__ int s[512];
    int t = threadIdx.x;
    int v = (t < nb) ? bsum[t] : 0;
    s[t] = v;
    for (int off = 1; off < 512; off <<= 1) {
        __syncthreads();
        int x = (t >= off) ? s[t - off] : 0;
        __syncthreads();
        s[t] += x;
    }
    if (t < nb) bsum[t] = s[t] - v;
}

// scan3 + bbaseR emit (fused)
__global__ void scan3_kernel(int* __restrict__ rowptr, const int* __restrict__ bsum,
                             int* __restrict__ bbaseR, int N, int E) {
    int i = blockIdx.x * 256 + threadIdx.x;
    if (i < N) {
        int v = rowptr[i] + bsum[blockIdx.x];
        rowptr[i] = v;
        if ((i & 511) == 0) bbaseR[i >> 9] = v;
    }
    if (i == 0) {
        for (int t = (N + 511) >> 9; t <= 256; ++t) bbaseR[t] = E;
    }
}

// ---------------- bucket-local CSR fill ----------------

__global__ __launch_bounds__(256) void csr_kernel(
        const u64* __restrict__ staged, const int* __restrict__ bbase,
        const int* __restrict__ rowptr2, int* __restrict__ cur,
        int* __restrict__ col) {
    int bucket = blockIdx.x & 255;
    int k = blockIdx.x >> 8;
    int s0 = bbase[bucket], s1 = bbase[bucket + 1];
    for (int i = s0 + k * 256 + threadIdx.x; i < s1; i += 256 * KB_CSR) {
        u64 p = staged[i];
        int r = (int)(p >> 32);
        int pos = rowptr2[r] + atomicAdd(&cur[r], 1);
        col[pos] = (int)(p & 0xffffffffu);
    }
}

// ---------------- x -> rank-space sliced layout, pre-scaled ----------------

__global__ void slice_x_kernel(const float* __restrict__ x, const int* __restrict__ perm,
                               const float* __restrict__ dinvR,
                               float* __restrict__ xs, int N) {
    int idx = blockIdx.x * 256 + threadIdx.x;   // over N*2
    if (idx >= N * 2) return;
    int r = idx >> 1, h = idx & 1;
    int sl = blockIdx.y;
    int n = perm[r];
    float4 v = ((const float4*)x)[(size_t)n * 8 + sl * 2 + h];
    float dn = dinvR[r];
    v.x *= dn; v.y *= dn; v.z *= dn; v.w *= dn;
    ((float4*)(xs + (size_t)sl * N * 8))[idx] = v;
}

// ---------------- aggregation (rank space, EDGE-SPLIT pair) ----------------
// out[r] = dinvR[r] * (in[r] + sum_{sr in row r} in[sr])   [+bias]
// Lane pair (e=0,1) splits EDGES (4 each per 8-edge iter); each lane gathers
// both 16B halves of its edges; halves are exchanged once via shfl_xor.

template <int C, bool ADD_BIAS, bool OUT_ROWMAJOR>
__global__ __launch_bounds__(256) void agg_kernel(
        const float* __restrict__ in, float* __restrict__ out,
        const int* __restrict__ rowptr2, const int* __restrict__ cnt2,
        const int* __restrict__ col, const float* __restrict__ dinvR,
        const int* __restrict__ perm, const float* __restrict__ bias, int N) {
    constexpr int NSL = C / 8;
    int sl = blockIdx.x % NSL;
    int chunk = blockIdx.x / NSL;
    int slot = threadIdx.x >> 1, e = threadIdx.x & 1;
    int r = chunk * 128 + slot;
    if (r >= N) return;
    const float4* inS = (const float4*)(in + (size_t)sl * N * 8);
    int start = rowptr2[r], m = cnt2[r];
    const int* cp = col + start;
    float4 a0 = make_float4(0.f, 0.f, 0.f, 0.f);
    float4 a1 = make_float4(0.f, 0.f, 0.f, 0.f);
    {   // self: lane e holds half e
        float4 s = inS[(size_t)r * 2 + e];
        if (e == 0) a0 = s; else a1 = s;
    }
    int i = 0;
    for (; i + 8 <= m; i += 8) {
        const int* q = cp + i + 4 * e;
        int c0 = q[0], c1 = q[1], c2 = q[2], c3 = q[3];
        float4 u0 = inS[(size_t)c0 * 2],     u1 = inS[(size_t)c1 * 2];
        float4 u2 = inS[(size_t)c2 * 2],     u3 = inS[(size_t)c3 * 2];
        float4 v0 = inS[(size_t)c0 * 2 + 1], v1 = inS[(size_t)c1 * 2 + 1];
        float4 v2 = inS[(size_t)c2 * 2 + 1], v3 = inS[(size_t)c3 * 2 + 1];
        add4(a0, u0); add4(a0, u1); add4(a0, u2); add4(a0, u3);
        add4(a1, v0); add4(a1, v1); add4(a1, v2); add4(a1, v3);
    }
    {   // tail: lane0 -> [i, min(m,i+4)), lane1 -> [i+4, min(m,i+8))
        int j0 = i + 4 * e;
        int j1 = min(m, j0 + 4);
        for (int j = j0; j < j1; ++j) {
            int c = cp[j];
            add4(a0, inS[(size_t)c * 2]);
            add4(a1, inS[(size_t)c * 2 + 1]);
        }
    }
    // combine: lane e's full half-e = own a_e + partner's a_e
    float4 sendv = e ? a0 : a1;
    float4 recv = shfl_xor_f4(sendv, 1);
    float4 tot = e ? a1 : a0;
    add4(tot, recv);
    float dn = dinvR[r];
    tot.x *= dn; tot.y *= dn; tot.z *= dn; tot.w *= dn;
    if (ADD_BIAS) {
        float4 b4 = ((const float4*)bias)[sl * 2 + e];
        add4(tot, b4);
    }
    if (OUT_ROWMAJOR) ((float4*)out)[(size_t)perm[r] * (C / 4) + sl * 2 + e] = tot;
    else ((float4*)(out + (size_t)sl * N * 8))[(size_t)r * 2 + e] = tot;
}

// ---------------- group-agg for decoder conv0 ----------------
// Input d[r] = dinv[r]*dg[group[r]] has only 64 distinct 64ch rows -> LDS.
// out[r,ch] = dinv[r]*( dinv[r]*dg[g_r,ch] + sum_sr dinv[sr]*dg[g_sr,ch] )
// Per-edge VMEM: col (4B x2 lanes) + pgR float2 (8B x2 lanes) = 24B.

__global__ __launch_bounds__(256) void gagg_kernel(
        const float* __restrict__ dg, const float2* __restrict__ pgR,
        const int* __restrict__ rowptr2, const int* __restrict__ cnt2,
        const int* __restrict__ col, float* __restrict__ out, int N) {
    __shared__ float dgL[NGRAPH * 68];   // padded stride 68 floats (17 float4)
    for (int i = threadIdx.x; i < NGRAPH * 64; i += 256)
        dgL[(i >> 6) * 68 + (i & 63)] = dg[i];
    __syncthreads();
    int slot = threadIdx.x >> 1, e = threadIdx.x & 1;   // e: channel half (32ch)
    int r = blockIdx.x * 128 + slot;
    if (r >= N) return;
    const float4* dgL4 = (const float4*)dgL;            // row stride 17
    int start = rowptr2[r], m = cnt2[r];
    const int* cp = col + start;
    float2 ps = pgR[r];
    float dn = ps.x;
    int gs = __float_as_int(ps.y);
    float4 acc[8];
    {
        const float4* rp = dgL4 + gs * 17 + e * 8;
        #pragma unroll
        for (int j = 0; j < 8; ++j) {
            float4 v = rp[j];
            acc[j] = make_float4(dn * v.x, dn * v.y, dn * v.z, dn * v.w);
        }
    }
    int i = 0;
    for (; i + 2 <= m; i += 2) {
        int c0 = cp[i], c1 = cp[i + 1];
        float2 p0 = pgR[c0], p1 = pgR[c1];
        const float4* r0 = dgL4 + __float_as_int(p0.y) * 17 + e * 8;
        const float4* r1 = dgL4 + __float_as_int(p1.y) * 17 + e * 8;
        float w0 = p0.x, w1 = p1.x;
        #pragma unroll
        for (int j = 0; j < 8; ++j) {
            float4 v0 = r0[j], v1 = r1[j];
            acc[j].x += w0 * v0.x + w1 * v1.x;
            acc[j].y += w0 * v0.y + w1 * v1.y;
            acc[j].z += w0 * v0.z + w1 * v1.z;
            acc[j].w += w0 * v0.w + w1 * v1.w;
        }
    }
    if (i < m) {
        int c0 = cp[i];
        float2 p0 = pgR[c0];
        const float4* r0 = dgL4 + __float_as_int(p0.y) * 17 + e * 8;
        float w0 = p0.x;
        #pragma unroll
        for (int j = 0; j < 8; ++j) {
            float4 v0 = r0[j];
            acc[j].x += w0 * v0.x; acc[j].y += w0 * v0.y;
            acc[j].z += w0 * v0.z; acc[j].w += w0 * v0.w;
        }
    }
    #pragma unroll
    for (int k = 0; k < 4; ++k) {
        #pragma unroll
        for (int jj = 0; jj < 2; ++jj) {
            float4 v = acc[k * 2 + jj];
            v.x *= dn; v.y *= dn; v.z *= dn; v.w *= dn;
            ((float4*)(out + (size_t)(4 * e + k) * N * 8))[(size_t)r * 2 + jj] = v;
        }
    }
}

// ---------------- dense transform: W column in registers, x broadcast from LDS ----------------

template <int CIN, int COUT, bool RELU, bool BIAS, bool SCALE, bool OUT_ROWMAJOR>
__global__ __launch_bounds__(256) void gemm_kernel(
        const float* __restrict__ in, const float* __restrict__ W,
        const float* __restrict__ b, const float* __restrict__ dinvR,
        const int* __restrict__ perm, float* __restrict__ out, int N) {
    constexpr int NPB = 256 / COUT;
    constexpr int K4 = CIN / 4;
    __shared__ float4 xsh[NPB * K4];
    int r  = threadIdx.x / COUT;
    int co = threadIdx.x % COUT;
    float w[CIN];
    #pragma unroll
    for (int k = 0; k < CIN; ++k) w[k] = W[k * COUT + co];
    float bsv = BIAS ? b[co] : 0.f;
    int ngroups = (N + NPB - 1) / NPB;
    for (int grp = blockIdx.x; grp < ngroups; grp += gridDim.x) {
        int base = grp * NPB;
        __syncthreads();
        for (int i = threadIdx.x; i < NPB * K4; i += 256) {
            int rr = i / K4, k4 = i % K4;
            int n = base + rr;
            float4 v = make_float4(0.f, 0.f, 0.f, 0.f);
            if (n < N) v = ((const float4*)(in + (size_t)(k4 >> 1) * N * 8))[(size_t)n * 2 + (k4 & 1)];
            xsh[i] = v;
        }
        __syncthreads();
        int n = base + r;
        if (n < N) {
            float acc = bsv;
            #pragma unroll
            for (int k4 = 0; k4 < K4; ++k4) {
                float4 xv = xsh[r * K4 + k4];   // wave-uniform -> LDS broadcast
                acc += xv.x * w[4 * k4] + xv.y * w[4 * k4 + 1]
                     + xv.z * w[4 * k4 + 2] + xv.w * w[4 * k4 + 3];
            }
            if (RELU) acc = fmaxf(acc, 0.f);
            if (SCALE) acc *= dinvR[n];
            if (OUT_ROWMAJOR) out[(size_t)perm[n] * COUT + co] = acc;
            else out[(size_t)(co >> 3) * N * 8 + (size_t)n * 8 + (co & 7)] = acc;
        }
    }
}

// ---------------- pooling over sorted batch ids (row-major, original order) ----------------

__global__ __launch_bounds__(256) void pool_kernel(
        const float* __restrict__ h, const int* __restrict__ batch,
        float* __restrict__ sums, int* __restrict__ cntb, int N) {
    const int CHUNK = 512;
    int chunkStart = blockIdx.x * CHUNK;
    int c = threadIdx.x & 63;
    int r = threadIdx.x >> 6;
    int curg = -1;
    float acc = 0.f;
    int cnt = 0;
    int end = chunkStart + CHUNK;
    if (end > N) end = N;
    for (int n = chunkStart + r; n < end; n += 4) {
        int g = batch[n];
        if (g != curg) {
            if (curg >= 0) {
                atomicAdd(&sums[curg * 64 + c], acc);
                if (c == 0) atomicAdd(&cntb[curg], cnt);
            }
            curg = g; acc = 0.f; cnt = 0;
        }
        acc += h[(size_t)n * 64 + c];
        cnt++;
    }
    if (curg >= 0) {
        atomicAdd(&sums[curg * 64 + c], acc);
        if (c == 0) atomicAdd(&cntb[curg], cnt);
    }
}

// ---------------- latent ----------------

__global__ __launch_bounds__(1024) void latent_kernel(
        const float* __restrict__ sums, const int* __restrict__ cntb,
        const float* __restrict__ Wp, const float* __restrict__ bp,
        const float* __restrict__ Wd, const float* __restrict__ bd,
        float* __restrict__ z_out, float* __restrict__ dg) {
    __shared__ float zl[NGRAPH * LAT];
    int t = threadIdx.x;
    {
        int g = t / LAT, l = t % LAT;
        float cf = (float)cntb[g];
        float inv = 1.0f / fmaxf(cf, 1.0f);
        float acc = bp[l];
        #pragma unroll
        for (int k = 0; k < HID; k++) acc += sums[g * HID + k] * inv * Wp[k * LAT + l];
        zl[t] = acc;
        z_out[t] = acc;
    }
    __syncthreads();
    #pragma unroll
    for (int i = 0; i < 4; i++) {
        int idx = t + i * 1024;
        int g = idx >> 6, c = idx & 63;
        float acc = bd[c];
        #pragma unroll
        for (int l = 0; l < LAT; l++) acc += zl[g * LAT + l] * Wd[l * HID + c];
        dg[idx] = fmaxf(acc, 0.f);
    }
}

// ---------------- launch ----------------

extern "C" void kernel_launch(void* const* d_in, const int* in_sizes, int n_in,
                              void* d_out, int out_size, void* d_ws, size_t ws_size,
                              hipStream_t stream) {
    const float* x          = (const float*)d_in[0];
    const int*   ei         = (const int*)d_in[1];
    const int*   batch      = (const int*)d_in[2];
    const float* W_enc0     = (const float*)d_in[3];
    const float* b_enc0     = (const float*)d_in[4];
    const float* W_enc1     = (const float*)d_in[5];
    const float* b_enc1     = (const float*)d_in[6];
    const float* W_enc2     = (const float*)d_in[7];
    const float* b_enc2     = (const float*)d_in[8];
    const float* W_proj     = (const float*)d_in[9];
    const float* b_proj     = (const float*)d_in[10];
    const float* W_dec_proj = (const float*)d_in[11];
    const float* b_dec_proj = (const float*)d_in[12];
    const float* W_dec0     = (const float*)d_in[13];
    const float* b_dec0     = (const float*)d_in[14];
    const float* W_dec1     = (const float*)d_in[15];
    const float* b_dec1     = (const float*)d_in[16];

    const int N = in_sizes[0] / IN_CH;
    const int E = in_sizes[1] / 2;

    char* ws = (char*)d_ws;
    size_t off = 0;
    auto alloc = [&](size_t bytes) {
        void* p = ws + off;
        off += (bytes + 255) & ~(size_t)255;
        return p;
    };
    float* A       = (float*)alloc((size_t)N * HID * 4);   // aliases staged2
    float* B       = (float*)alloc((size_t)N * HID * 4);
    float* XS      = (float*)alloc((size_t)N * IN_CH * 4); // aliases staged1
    int*   col     = (int*)  alloc((size_t)E * 4);
    int*   cntn    = (int*)  alloc((size_t)N * 4);
    int*   cnt2    = (int*)  alloc((size_t)N * 4);
    int*   rowptr2 = (int*)  alloc((size_t)(N + 1) * 4);
    int*   perm    = (int*)  alloc((size_t)N * 4);
    int*   rank    = (int*)  alloc((size_t)N * 4);
    float* dinvR   = (float*)alloc((size_t)N * 4);
    float2* pgR    = (float2*)alloc((size_t)N * 8);
    int nb = (N + 255) / 256;
    int*   bsum    = (int*)  alloc((size_t)nb * 4);
    int*   bbaseD  = (int*)  alloc(257 * 4);
    int*   bbaseR  = (int*)  alloc(257 * 4);
    // ---- zero-initialized region (single memset) ----
    char* zbase = ws + off;
    int*   cursor  = (int*)  alloc((size_t)N * 4);
    int*   hist    = (int*)  alloc((size_t)NBUCKET * 4);
    int*   hcur    = (int*)  alloc((size_t)NBUCKET * 4);
    int*   bh      = (int*)  alloc(256 * 4);
    int*   gcurD   = (int*)  alloc(256 * 4);
    int*   gcurR   = (int*)  alloc(256 * 4);
    float* sums    = (float*)alloc((size_t)NGRAPH * HID * 4);
    int*   cntb    = (int*)  alloc((size_t)NGRAPH * 4);
    size_t zbytes = (size_t)((ws + off) - zbase);
    float* dg      = (float*)alloc((size_t)NGRAPH * HID * 4);

    u64* staged1 = (u64*)XS;   // dead before slice_x writes XS
    u64* staged2 = (u64*)A;    // dead before first agg writes A

    float* x_recon = (float*)d_out;
    float* z_out   = (float*)d_out + (size_t)N * IN_CH;

    hipMemsetAsync(zbase, 0, zbytes, stream);

    int ebins = (E + 2047) / 2048;
    int chunks = (N + 127) / 128;

    // CSR build + degree sort (binned, no random scatter)
    bhist_kernel<<<ebins, 256, 0, stream>>>(ei, bh, E);
    bscan_kernel<<<1, 256, 0, stream>>>(bh, bbaseD, E);
    bin_kernel<0><<<ebins, 256, 0, stream>>>(ei, nullptr, nullptr, bbaseD, gcurD, staged1, E);
    degb_kernel<<<256, 256, 0, stream>>>(staged1, bbaseD, cntn, hist, N);
    hscan_kernel<<<1, NBUCKET, 0, stream>>>(hist);
    scatter_kernel<<<nb, 256, 0, stream>>>(cntn, batch, hist, hcur, perm, rank, cnt2,
                                           dinvR, pgR, N);
    scan1_kernel<<<nb, 256, 0, stream>>>(cnt2, rowptr2, bsum, N);
    scan2_kernel<<<1, 512, 0, stream>>>(bsum, nb);
    scan3_kernel<<<nb, 256, 0, stream>>>(rowptr2, bsum, bbaseR, N, E);
    bin_kernel<1><<<ebins, 256, 0, stream>>>(nullptr, staged1, rank, bbaseR, gcurR, staged2, E);
    csr_kernel<<<256 * KB_CSR, 256, 0, stream>>>(staged2, bbaseR, rowptr2, cursor, col);

    {
        dim3 g((N * 2 + 255) / 256, IN_CH / 8);
        slice_x_kernel<<<g, 256, 0, stream>>>(x, perm, dinvR, XS, N);
    }

    // encoder (rank space)
    agg_kernel<IN_CH, false, false><<<chunks * 4, 256, 0, stream>>>(
        XS, A, rowptr2, cnt2, col, dinvR, perm, nullptr, N);
    gemm_kernel<IN_CH, HID, true, true, true, false><<<2048, 256, 0, stream>>>(
        A, W_enc0, b_enc0, dinvR, perm, B, N);
    agg_kernel<HID, false, false><<<chunks * 8, 256, 0, stream>>>(
        B, A, rowptr2, cnt2, col, dinvR, perm, nullptr, N);
    gemm_kernel<HID, HID, true, true, true, false><<<2048, 256, 0, stream>>>(
        A, W_enc1, b_enc1, dinvR, perm, B, N);
    agg_kernel<HID, false, false><<<chunks * 8, 256, 0, stream>>>(
        B, A, rowptr2, cnt2, col, dinvR, perm, nullptr, N);
    gemm_kernel<HID, HID, true, true, false, true><<<2048, 256, 0, stream>>>(
        A, W_enc2, b_enc2, dinvR, perm, B, N);   // scatter to ORIGINAL order for pool

    // pool + latent
    pool_kernel<<<(N + 511) / 512, 256, 0, stream>>>(B, batch, sums, cntb, N);
    latent_kernel<<<1, 1024, 0, stream>>>(sums, cntb, W_proj, b_proj, W_dec_proj, b_dec_proj, z_out, dg);

    // decoder (rank space): group-agg replaces bcast + generic agg
    gagg_kernel<<<chunks, 256, 0, stream>>>(dg, pgR, rowptr2, cnt2, col, A, N);
    gemm_kernel<HID, HID, true, true, false, false><<<2048, 256, 0, stream>>>(
        A, W_dec0, b_dec0, dinvR, perm, B, N);
    gemm_kernel<HID, IN_CH, false, false, true, false><<<2048, 256, 0, stream>>>(
        B, W_dec1, nullptr, dinvR, perm, A, N);
    agg_kernel<IN_CH, true, true><<<chunks * 4, 256, 0, stream>>>(
        A, x_recon, rowptr2, cnt2, col, dinvR, perm, b_dec1, N);
}

// Round 7
// 698.987 us; speedup vs baseline: 1.6706x; 1.0586x over previous
//
#include <hip/hip_runtime.h>
#include <hip/hip_bf16.h>

typedef unsigned long long u64;

static constexpr int IN_CH  = 32;
static constexpr int HID    = 64;
static constexpr int LAT    = 16;
static constexpr int NGRAPH = 64;
static constexpr int NBUCKET = 1024;   // degree buckets for counting sort
static constexpr int KB_CSR  = 24;     // blocks per bucket in csr_kernel

// RANK-SPACE pipeline: nodes permuted by degree; feature tensors, dinvR, pgR,
// CSR all in rank space. Sliced [C/8][N][8] layout keeps each gather slice
// L2-resident per XCD (blockIdx%NSL pins slice->XCD). All agg inputs are
// pre-scaled by dinv. Agg: lane PAIR per row; halves pair-coalesced (32B/edge);
// col deduped via int4 + shfl_xor. High-degree chunks first.

__device__ inline void add4(float4& a, const float4& b) {
    a.x += b.x; a.y += b.y; a.z += b.z; a.w += b.w;
}

// ---------------- bucket histogram of dst ----------------

__global__ __launch_bounds__(256) void bhist_kernel(const int* __restrict__ ei,
                                                    int* __restrict__ bh, int E) {
    __shared__ int lh[256];
    lh[threadIdx.x] = 0;
    __syncthreads();
    int base = blockIdx.x * 2048;
    #pragma unroll
    for (int j = 0; j < 8; j++) {
        int idx = base + j * 256 + threadIdx.x;
        if (idx < E) atomicAdd(&lh[ei[E + idx] >> 9], 1);
    }
    __syncthreads();
    if (lh[threadIdx.x]) atomicAdd(&bh[threadIdx.x], lh[threadIdx.x]);
}

// ---------------- LDS counting-sort binning ----------------
// MODE 0: in = edge_index, key = dst, val = src, bin by dst>>9; bbase from bh scan
// MODE 1: in = staged1 (dst,src), key = rank[dst], val = rank[src]; bbase passed

template <int MODE>
__global__ __launch_bounds__(256) void bin_kernel(
        const int* __restrict__ ei, const u64* __restrict__ sin,
        const int* __restrict__ rank,
        const int* __restrict__ bhv,    // MODE0: bh counts; MODE1: bbase offsets
        int* __restrict__ gcur,
        u64* __restrict__ sout, int E) {
    __shared__ int lhist[256], lscan[256], lcur[256], gbase[256], bbaseL[256];
    __shared__ u64 sbuf[2048];
    int tid = threadIdx.x;
    lhist[tid] = 0;
    if constexpr (MODE == 0) {
        int v = bhv[tid];
        lscan[tid] = v;
        for (int off = 1; off < 256; off <<= 1) {
            __syncthreads();
            int x = (tid >= off) ? lscan[tid - off] : 0;
            __syncthreads();
            lscan[tid] += x;
        }
        __syncthreads();
        bbaseL[tid] = lscan[tid] - v;
    } else {
        bbaseL[tid] = bhv[tid];
    }
    __syncthreads();
    int base = blockIdx.x * 2048;
    int cnt = min(2048, E - base);
    int myb[8]; u64 myp[8];
    #pragma unroll
    for (int j = 0; j < 8; j++) {
        int idx = base + j * 256 + tid;
        myb[j] = -1;
        if (idx < E) {
            int key, val;
            if constexpr (MODE == 0) { key = ei[E + idx]; val = ei[idx]; }
            else {
                u64 p = sin[idx];
                key = rank[(int)(p >> 32)];
                val = rank[(int)(p & 0xffffffffu)];
            }
            int b = key >> 9;
            myb[j] = b;
            myp[j] = ((u64)(unsigned)key << 32) | (unsigned)val;
            atomicAdd(&lhist[b], 1);
        }
    }
    __syncthreads();
    int v = lhist[tid];
    lscan[tid] = v;
    for (int off = 1; off < 256; off <<= 1) {
        __syncthreads();
        int x = (tid >= off) ? lscan[tid - off] : 0;
        __syncthreads();
        lscan[tid] += x;
    }
    __syncthreads();
    int excl = lscan[tid] - v;
    __syncthreads();
    lscan[tid] = excl;
    lcur[tid] = excl;
    __syncthreads();
    #pragma unroll
    for (int j = 0; j < 8; j++) {
        if (myb[j] >= 0) {
            int pos = atomicAdd(&lcur[myb[j]], 1);
            sbuf[pos] = myp[j];
        }
    }
    gbase[tid] = v ? atomicAdd(&gcur[tid], v) : 0;
    __syncthreads();
    for (int i = tid; i < cnt; i += 256) {
        u64 p = sbuf[i];
        int b = (int)(p >> 41);   // key>>9
        sout[bbaseL[b] + gbase[b] + (i - lscan[b])] = p;
    }
}

// ---------------- per-bucket degree + degree-histogram (bbase from bh scan) ----------------

__global__ __launch_bounds__(256) void degb_kernel(
        const u64* __restrict__ staged, const int* __restrict__ bh,
        int* __restrict__ cnt, int* __restrict__ hist, int N) {
    __shared__ int ldeg[512];
    __shared__ int lhist[NBUCKET];
    __shared__ int sc[256];
    int b = blockIdx.x;
    int tid = threadIdx.x;
    // scan bh -> this bucket's staged range
    int bv = bh[tid];
    sc[tid] = bv;
    for (int off = 1; off < 256; off <<= 1) {
        __syncthreads();
        int x = (tid >= off) ? sc[tid - off] : 0;
        __syncthreads();
        sc[tid] += x;
    }
    __syncthreads();
    __shared__ int s0s, s1s;
    if (tid == b) { s0s = sc[b] - bv; s1s = sc[b]; }
    ldeg[tid] = 0;
    ldeg[tid + 256] = 0;
    for (int i = tid; i < NBUCKET; i += 256) lhist[i] = 0;
    __syncthreads();
    int s0 = s0s, s1 = s1s;
    for (int i = s0 + tid; i < s1; i += 256)
        atomicAdd(&ldeg[(int)(staged[i] >> 32) - (b << 9)], 1);
    __syncthreads();
    #pragma unroll
    for (int j = 0; j < 2; j++) {
        int t = tid + j * 256;
        int n = (b << 9) + t;
        if (n < N) {
            int d = ldeg[t];
            cnt[n] = d;
            atomicAdd(&lhist[min(d, NBUCKET - 1)], 1);
        }
    }
    __syncthreads();
    for (int i = tid; i < NBUCKET; i += 256)
        if (lhist[i]) atomicAdd(&hist[i], lhist[i]);
}

// ---------------- degree-sort scatter (hscan folded in) ----------------

__global__ __launch_bounds__(256) void scatter_kernel(
        const int* __restrict__ cnt, const int* __restrict__ batch,
        const int* __restrict__ hist, int* __restrict__ hcur,
        int* __restrict__ perm, int* __restrict__ rank, int* __restrict__ cnt2,
        float* __restrict__ dinvR, float2* __restrict__ pgR, int N) {
    __shared__ int lh[NBUCKET];
    __shared__ int gb[NBUCKET];
    __shared__ int hoff[NBUCKET];
    __shared__ int sc[256];
    int tid = threadIdx.x;
    // exclusive scan of hist[1024] (blocked 4/thread)
    int h0 = hist[4 * tid], h1 = hist[4 * tid + 1], h2 = hist[4 * tid + 2], h3 = hist[4 * tid + 3];
    int T = h0 + h1 + h2 + h3;
    sc[tid] = T;
    for (int off = 1; off < 256; off <<= 1) {
        __syncthreads();
        int x = (tid >= off) ? sc[tid - off] : 0;
        __syncthreads();
        sc[tid] += x;
    }
    __syncthreads();
    int ex = sc[tid] - T;
    hoff[4 * tid] = ex;
    hoff[4 * tid + 1] = ex + h0;
    hoff[4 * tid + 2] = ex + h0 + h1;
    hoff[4 * tid + 3] = ex + h0 + h1 + h2;
    for (int i = tid; i < NBUCKET; i += 256) lh[i] = 0;
    __syncthreads();
    int n = blockIdx.x * 256 + tid;
    int b = -1, lpos = 0, d = 0;
    if (n < N) {
        d = cnt[n];
        b = min(d, NBUCKET - 1);
        lpos = atomicAdd(&lh[b], 1);
    }
    __syncthreads();
    for (int i = tid; i < NBUCKET; i += 256)
        gb[i] = lh[i] ? atomicAdd(&hcur[i], lh[i]) : 0;
    __syncthreads();
    if (n < N) {
        int r = hoff[b] + gb[b] + lpos;
        perm[r] = n;
        rank[n] = r;
        cnt2[r] = d;
        float dv = rsqrtf((float)d + 1.0f);
        dinvR[r] = dv;
        pgR[r] = make_float2(dv, __int_as_float(batch[n]));
    }
}

// ---------------- scan of cnt2 -> rowptr2 (scan2 folded into scan3) ----------------

__global__ void scan1_kernel(const int* __restrict__ cnt, int* __restrict__ rowptr,
                             int* __restrict__ bsum, int N) {
    __shared__ int s[256];
    int i = blockIdx.x * 256 + threadIdx.x;
    int v = (i < N) ? cnt[i] : 0;
    s[threadIdx.x] = v;
    for (int off = 1; off < 256; off <<= 1) {
        __syncthreads();
        int t = (threadIdx.x >= off) ? s[threadIdx.x - off] : 0;
        __syncthreads();
        s[threadIdx.x] += t;
    }
    if (i < N) rowptr[i] = s[threadIdx.x] - v;
    if (threadIdx.x == 255) bsum[blockIdx.x] = s[255];
}

// every block re-scans bsum (nb <= 512), applies its prefix, emits bbaseR
__global__ __launch_bounds__(256) void scan3_kernel(
        int* __restrict__ rowptr, const int* __restrict__ bsum,
        int* __restrict__ bbaseR, int nb, int N, int E) {
    __shared__ int sc[256];
    int tid = threadIdx.x;
    int v0 = (2 * tid < nb) ? bsum[2 * tid] : 0;
    int v1 = (2 * tid + 1 < nb) ? bsum[2 * tid + 1] : 0;
    int T = v0 + v1;
    sc[tid] = T;
    for (int off = 1; off < 256; off <<= 1) {
        __syncthreads();
        int x = (tid >= off) ? sc[tid - off] : 0;
        __syncthreads();
        sc[tid] += x;
    }
    __syncthreads();
    __shared__ int myoff;
    int blk = blockIdx.x;
    if (tid == (blk >> 1)) {
        int ex = sc[tid] - T;           // excl at element 2*tid
        myoff = (blk & 1) ? (ex + v0) : ex;
    }
    __syncthreads();
    int i = blk * 256 + tid;
    if (i < N) {
        int v = rowptr[i] + myoff;
        rowptr[i] = v;
        if ((i & 511) == 0) bbaseR[i >> 9] = v;
    }
    if (blk == 0 && tid == 0) {
        for (int t = (N + 511) >> 9; t <= 256; ++t) bbaseR[t] = E;
    }
}

// ---------------- bucket-local CSR fill ----------------

__global__ __launch_bounds__(256) void csr_kernel(
        const u64* __restrict__ staged, const int* __restrict__ bbase,
        const int* __restrict__ rowptr2, int* __restrict__ cur,
        int* __restrict__ col) {
    int bucket = blockIdx.x & 255;
    int k = blockIdx.x >> 8;
    int s0 = bbase[bucket], s1 = bbase[bucket + 1];
    for (int i = s0 + k * 256 + threadIdx.x; i < s1; i += 256 * KB_CSR) {
        u64 p = staged[i];
        int r = (int)(p >> 32);
        int pos = rowptr2[r] + atomicAdd(&cur[r], 1);
        col[pos] = (int)(p & 0xffffffffu);
    }
}

// ---------------- x -> rank-space sliced layout, pre-scaled ----------------

__global__ void slice_x_kernel(const float* __restrict__ x, const int* __restrict__ perm,
                               const float* __restrict__ dinvR,
                               float* __restrict__ xs, int N) {
    int idx = blockIdx.x * 256 + threadIdx.x;   // over N*2
    if (idx >= N * 2) return;
    int r = idx >> 1, h = idx & 1;
    int sl = blockIdx.y;
    int n = perm[r];
    float4 v = ((const float4*)x)[(size_t)n * 8 + sl * 2 + h];
    float dn = dinvR[r];
    v.x *= dn; v.y *= dn; v.z *= dn; v.w *= dn;
    ((float4*)(xs + (size_t)sl * N * 8))[idx] = v;
}

// ---------------- aggregation (pair-half, int4 col + shfl dedup) ----------------
// out[r] = dinvR[r] * (in[r] + sum_{sr in row r} in[sr])   [+bias]
// Lane pair shares a row: lane h owns half h (16B). Col indices read as int4
// (4 edges per lane) and exchanged via shfl_xor so both lanes know all 8;
// every gather is pair-coalesced (two halves of the SAME edge -> one 32B line).

template <int C, bool ADD_BIAS, bool OUT_ROWMAJOR>
__global__ __launch_bounds__(256) void agg_kernel(
        const float* __restrict__ in, float* __restrict__ out,
        const int* __restrict__ rowptr2, const int* __restrict__ cnt2,
        const int* __restrict__ col, const float* __restrict__ dinvR,
        const int* __restrict__ perm, const float* __restrict__ bias, int N) {
    constexpr int NSL = C / 8;
    int sl = blockIdx.x % NSL;
    int nchunks = gridDim.x / NSL;
    int chunk = nchunks - 1 - (blockIdx.x / NSL);   // high-degree chunks first
    int slot = threadIdx.x >> 1, h = threadIdx.x & 1;
    int r = chunk * 128 + slot;
    if (r >= N) return;
    const float4* inS = (const float4*)(in + (size_t)sl * N * 8);
    int start = rowptr2[r], m = cnt2[r];
    const int* cp = col + start;
    float4 acc = inS[(size_t)r * 2 + h];   // self (own half)
    int i = 0;
    for (; i + 8 <= m; i += 8) {
        int4 cv = *(const int4*)(cp + i + 4 * h);
        int4 ov;
        ov.x = __shfl_xor(cv.x, 1);
        ov.y = __shfl_xor(cv.y, 1);
        ov.z = __shfl_xor(cv.z, 1);
        ov.w = __shfl_xor(cv.w, 1);
        int4 lo = h ? ov : cv;   // edges i..i+3
        int4 hi = h ? cv : ov;   // edges i+4..i+7
        float4 v0 = inS[(size_t)lo.x * 2 + h], v1 = inS[(size_t)lo.y * 2 + h];
        float4 v2 = inS[(size_t)lo.z * 2 + h], v3 = inS[(size_t)lo.w * 2 + h];
        float4 v4 = inS[(size_t)hi.x * 2 + h], v5 = inS[(size_t)hi.y * 2 + h];
        float4 v6 = inS[(size_t)hi.z * 2 + h], v7 = inS[(size_t)hi.w * 2 + h];
        add4(v0, v1); add4(v2, v3); add4(v4, v5); add4(v6, v7);
        add4(v0, v2); add4(v4, v6);
        add4(acc, v0); add4(acc, v4);
    }
    for (; i < m; ++i) {
        int c = cp[i];
        add4(acc, inS[(size_t)c * 2 + h]);
    }
    float dn = dinvR[r];
    acc.x *= dn; acc.y *= dn; acc.z *= dn; acc.w *= dn;
    if (ADD_BIAS) {
        float4 b4 = ((const float4*)bias)[sl * 2 + h];
        add4(acc, b4);
    }
    if (OUT_ROWMAJOR) ((float4*)out)[(size_t)perm[r] * (C / 4) + sl * 2 + h] = acc;
    else ((float4*)(out + (size_t)sl * N * 8))[(size_t)r * 2 + h] = acc;
}

// ---------------- group-agg for decoder conv0 ----------------
// Input d[r] = dinv[r]*dg[group[r]] has only 64 distinct 64ch rows -> LDS.

__global__ __launch_bounds__(256) void gagg_kernel(
        const float* __restrict__ dg, const float2* __restrict__ pgR,
        const int* __restrict__ rowptr2, const int* __restrict__ cnt2,
        const int* __restrict__ col, float* __restrict__ out, int N) {
    __shared__ float dgL[NGRAPH * 68];   // padded stride 68 floats (17 float4)
    for (int i = threadIdx.x; i < NGRAPH * 64; i += 256)
        dgL[(i >> 6) * 68 + (i & 63)] = dg[i];
    __syncthreads();
    int slot = threadIdx.x >> 1, e = threadIdx.x & 1;   // e: channel half (32ch)
    int r = (gridDim.x - 1 - blockIdx.x) * 128 + slot;  // high-degree first
    if (r >= N) return;
    const float4* dgL4 = (const float4*)dgL;            // row stride 17
    int start = rowptr2[r], m = cnt2[r];
    const int* cp = col + start;
    float2 ps = pgR[r];
    float dn = ps.x;
    int gs = __float_as_int(ps.y);
    float4 acc[8];
    {
        const float4* rp = dgL4 + gs * 17 + e * 8;
        #pragma unroll
        for (int j = 0; j < 8; ++j) {
            float4 v = rp[j];
            acc[j] = make_float4(dn * v.x, dn * v.y, dn * v.z, dn * v.w);
        }
    }
    int i = 0;
    for (; i + 2 <= m; i += 2) {
        int c0 = cp[i], c1 = cp[i + 1];
        float2 p0 = pgR[c0], p1 = pgR[c1];
        const float4* r0 = dgL4 + __float_as_int(p0.y) * 17 + e * 8;
        const float4* r1 = dgL4 + __float_as_int(p1.y) * 17 + e * 8;
        float w0 = p0.x, w1 = p1.x;
        #pragma unroll
        for (int j = 0; j < 8; ++j) {
            float4 v0 = r0[j], v1 = r1[j];
            acc[j].x += w0 * v0.x + w1 * v1.x;
            acc[j].y += w0 * v0.y + w1 * v1.y;
            acc[j].z += w0 * v0.z + w1 * v1.z;
            acc[j].w += w0 * v0.w + w1 * v1.w;
        }
    }
    if (i < m) {
        int c0 = cp[i];
        float2 p0 = pgR[c0];
        const float4* r0 = dgL4 + __float_as_int(p0.y) * 17 + e * 8;
        float w0 = p0.x;
        #pragma unroll
        for (int j = 0; j < 8; ++j) {
            float4 v0 = r0[j];
            acc[j].x += w0 * v0.x; acc[j].y += w0 * v0.y;
            acc[j].z += w0 * v0.z; acc[j].w += w0 * v0.w;
        }
    }
    #pragma unroll
    for (int k = 0; k < 4; ++k) {
        #pragma unroll
        for (int jj = 0; jj < 2; ++jj) {
            float4 v = acc[k * 2 + jj];
            v.x *= dn; v.y *= dn; v.z *= dn; v.w *= dn;
            ((float4*)(out + (size_t)(4 * e + k) * N * 8))[(size_t)r * 2 + jj] = v;
        }
    }
}

// ---------------- dense transform: W column in registers, x broadcast from LDS ----------------

template <int CIN, int COUT, bool RELU, bool BIAS, bool SCALE, bool OUT_ROWMAJOR>
__global__ __launch_bounds__(256) void gemm_kernel(
        const float* __restrict__ in, const float* __restrict__ W,
        const float* __restrict__ b, const float* __restrict__ dinvR,
        const int* __restrict__ perm, float* __restrict__ out, int N) {
    constexpr int NPB = 256 / COUT;
    constexpr int K4 = CIN / 4;
    __shared__ float4 xsh[NPB * K4];
    int r  = threadIdx.x / COUT;
    int co = threadIdx.x % COUT;
    float w[CIN];
    #pragma unroll
    for (int k = 0; k < CIN; ++k) w[k] = W[k * COUT + co];
    float bsv = BIAS ? b[co] : 0.f;
    int ngroups = (N + NPB - 1) / NPB;
    for (int grp = blockIdx.x; grp < ngroups; grp += gridDim.x) {
        int base = grp * NPB;
        __syncthreads();
        for (int i = threadIdx.x; i < NPB * K4; i += 256) {
            int rr = i / K4, k4 = i % K4;
            int n = base + rr;
            float4 v = make_float4(0.f, 0.f, 0.f, 0.f);
            if (n < N) v = ((const float4*)(in + (size_t)(k4 >> 1) * N * 8))[(size_t)n * 2 + (k4 & 1)];
            xsh[i] = v;
        }
        __syncthreads();
        int n = base + r;
        if (n < N) {
            float acc = bsv;
            #pragma unroll
            for (int k4 = 0; k4 < K4; ++k4) {
                float4 xv = xsh[r * K4 + k4];   // wave-uniform -> LDS broadcast
                acc += xv.x * w[4 * k4] + xv.y * w[4 * k4 + 1]
                     + xv.z * w[4 * k4 + 2] + xv.w * w[4 * k4 + 3];
            }
            if (RELU) acc = fmaxf(acc, 0.f);
            if (SCALE) acc *= dinvR[n];
            if (OUT_ROWMAJOR) out[(size_t)perm[n] * COUT + co] = acc;
            else out[(size_t)(co >> 3) * N * 8 + (size_t)n * 8 + (co & 7)] = acc;
        }
    }
}

// ---------------- pooling over sorted batch ids (row-major, original order) ----------------

__global__ __launch_bounds__(256) void pool_kernel(
        const float* __restrict__ h, const int* __restrict__ batch,
        float* __restrict__ sums, int* __restrict__ cntb, int N) {
    const int CHUNK = 512;
    int chunkStart = blockIdx.x * CHUNK;
    int c = threadIdx.x & 63;
    int r = threadIdx.x >> 6;
    int curg = -1;
    float acc = 0.f;
    int cnt = 0;
    int end = chunkStart + CHUNK;
    if (end > N) end = N;
    for (int n = chunkStart + r; n < end; n += 4) {
        int g = batch[n];
        if (g != curg) {
            if (curg >= 0) {
                atomicAdd(&sums[curg * 64 + c], acc);
                if (c == 0) atomicAdd(&cntb[curg], cnt);
            }
            curg = g; acc = 0.f; cnt = 0;
        }
        acc += h[(size_t)n * 64 + c];
        cnt++;
    }
    if (curg >= 0) {
        atomicAdd(&sums[curg * 64 + c], acc);
        if (c == 0) atomicAdd(&cntb[curg], cnt);
    }
}

// ---------------- latent ----------------

__global__ __launch_bounds__(1024) void latent_kernel(
        const float* __restrict__ sums, const int* __restrict__ cntb,
        const float* __restrict__ Wp, const float* __restrict__ bp,
        const float* __restrict__ Wd, const float* __restrict__ bd,
        float* __restrict__ z_out, float* __restrict__ dg) {
    __shared__ float zl[NGRAPH * LAT];
    int t = threadIdx.x;
    {
        int g = t / LAT, l = t % LAT;
        float cf = (float)cntb[g];
        float inv = 1.0f / fmaxf(cf, 1.0f);
        float acc = bp[l];
        #pragma unroll
        for (int k = 0; k < HID; k++) acc += sums[g * HID + k] * inv * Wp[k * LAT + l];
        zl[t] = acc;
        z_out[t] = acc;
    }
    __syncthreads();
    #pragma unroll
    for (int i = 0; i < 4; i++) {
        int idx = t + i * 1024;
        int g = idx >> 6, c = idx & 63;
        float acc = bd[c];
        #pragma unroll
        for (int l = 0; l < LAT; l++) acc += zl[g * LAT + l] * Wd[l * HID + c];
        dg[idx] = fmaxf(acc, 0.f);
    }
}

// ---------------- launch ----------------

extern "C" void kernel_launch(void* const* d_in, const int* in_sizes, int n_in,
                              void* d_out, int out_size, void* d_ws, size_t ws_size,
                              hipStream_t stream) {
    const float* x          = (const float*)d_in[0];
    const int*   ei         = (const int*)d_in[1];
    const int*   batch      = (const int*)d_in[2];
    const float* W_enc0     = (const float*)d_in[3];
    const float* b_enc0     = (const float*)d_in[4];
    const float* W_enc1     = (const float*)d_in[5];
    const float* b_enc1     = (const float*)d_in[6];
    const float* W_enc2     = (const float*)d_in[7];
    const float* b_enc2     = (const float*)d_in[8];
    const float* W_proj     = (const float*)d_in[9];
    const float* b_proj     = (const float*)d_in[10];
    const float* W_dec_proj = (const float*)d_in[11];
    const float* b_dec_proj = (const float*)d_in[12];
    const float* W_dec0     = (const float*)d_in[13];
    const float* b_dec0     = (const float*)d_in[14];
    const float* W_dec1     = (const float*)d_in[15];
    const float* b_dec1     = (const float*)d_in[16];

    const int N = in_sizes[0] / IN_CH;
    const int E = in_sizes[1] / 2;

    char* ws = (char*)d_ws;
    size_t off = 0;
    auto alloc = [&](size_t bytes) {
        void* p = ws + off;
        off += (bytes + 255) & ~(size_t)255;
        return p;
    };
    float* A       = (float*)alloc((size_t)N * HID * 4);   // aliases staged2
    float* B       = (float*)alloc((size_t)N * HID * 4);
    float* XS      = (float*)alloc((size_t)N * IN_CH * 4); // aliases staged1
    int*   col     = (int*)  alloc((size_t)E * 4);
    int*   cntn    = (int*)  alloc((size_t)N * 4);
    int*   cnt2    = (int*)  alloc((size_t)N * 4);
    int*   rowptr2 = (int*)  alloc((size_t)(N + 1) * 4);
    int*   perm    = (int*)  alloc((size_t)N * 4);
    int*   rank    = (int*)  alloc((size_t)N * 4);
    float* dinvR   = (float*)alloc((size_t)N * 4);
    float2* pgR    = (float2*)alloc((size_t)N * 8);
    int nb = (N + 255) / 256;
    int*   bsum    = (int*)  alloc((size_t)nb * 4);
    int*   bbaseR  = (int*)  alloc(257 * 4);
    // ---- zero-initialized region (single memset) ----
    char* zbase = ws + off;
    int*   cursor  = (int*)  alloc((size_t)N * 4);
    int*   hist    = (int*)  alloc((size_t)NBUCKET * 4);
    int*   hcur    = (int*)  alloc((size_t)NBUCKET * 4);
    int*   bh      = (int*)  alloc(256 * 4);
    int*   gcurD   = (int*)  alloc(256 * 4);
    int*   gcurR   = (int*)  alloc(256 * 4);
    float* sums    = (float*)alloc((size_t)NGRAPH * HID * 4);
    int*   cntb    = (int*)  alloc((size_t)NGRAPH * 4);
    size_t zbytes = (size_t)((ws + off) - zbase);
    float* dg      = (float*)alloc((size_t)NGRAPH * HID * 4);

    u64* staged1 = (u64*)XS;   // dead before slice_x writes XS
    u64* staged2 = (u64*)A;    // dead before first agg writes A

    float* x_recon = (float*)d_out;
    float* z_out   = (float*)d_out + (size_t)N * IN_CH;

    hipMemsetAsync(zbase, 0, zbytes, stream);

    int ebins = (E + 2047) / 2048;
    int chunks = (N + 127) / 128;

    // CSR build + degree sort (binned, no random scatter)
    bhist_kernel<<<ebins, 256, 0, stream>>>(ei, bh, E);
    bin_kernel<0><<<ebins, 256, 0, stream>>>(ei, nullptr, nullptr, bh, gcurD, staged1, E);
    degb_kernel<<<256, 256, 0, stream>>>(staged1, bh, cntn, hist, N);
    scatter_kernel<<<nb, 256, 0, stream>>>(cntn, batch, hist, hcur, perm, rank, cnt2,
                                           dinvR, pgR, N);
    scan1_kernel<<<nb, 256, 0, stream>>>(cnt2, rowptr2, bsum, N);
    scan3_kernel<<<nb, 256, 0, stream>>>(rowptr2, bsum, bbaseR, nb, N, E);
    bin_kernel<1><<<ebins, 256, 0, stream>>>(nullptr, staged1, rank, bbaseR, gcurR, staged2, E);
    csr_kernel<<<256 * KB_CSR, 256, 0, stream>>>(staged2, bbaseR, rowptr2, cursor, col);

    {
        dim3 g((N * 2 + 255) / 256, IN_CH / 8);
        slice_x_kernel<<<g, 256, 0, stream>>>(x, perm, dinvR, XS, N);
    }

    // encoder (rank space)
    agg_kernel<IN_CH, false, false><<<chunks * 4, 256, 0, stream>>>(
        XS, A, rowptr2, cnt2, col, dinvR, perm, nullptr, N);
    gemm_kernel<IN_CH, HID, true, true, true, false><<<2048, 256, 0, stream>>>(
        A, W_enc0, b_enc0, dinvR, perm, B, N);
    agg_kernel<HID, false, false><<<chunks * 8, 256, 0, stream>>>(
        B, A, rowptr2, cnt2, col, dinvR, perm, nullptr, N);
    gemm_kernel<HID, HID, true, true, true, false><<<2048, 256, 0, stream>>>(
        A, W_enc1, b_enc1, dinvR, perm, B, N);
    agg_kernel<HID, false, false><<<chunks * 8, 256, 0, stream>>>(
        B, A, rowptr2, cnt2, col, dinvR, perm, nullptr, N);
    gemm_kernel<HID, HID, true, true, false, true><<<2048, 256, 0, stream>>>(
        A, W_enc2, b_enc2, dinvR, perm, B, N);   // scatter to ORIGINAL order for pool

    // pool + latent
    pool_kernel<<<(N + 511) / 512, 256, 0, stream>>>(B, batch, sums, cntb, N);
    latent_kernel<<<1, 1024, 0, stream>>>(sums, cntb, W_proj, b_proj, W_dec_proj, b_dec_proj, z_out, dg);

    // decoder (rank space): group-agg replaces bcast + generic agg
    gagg_kernel<<<chunks, 256, 0, stream>>>(dg, pgR, rowptr2, cnt2, col, A, N);
    gemm_kernel<HID, HID, true, true, false, false><<<2048, 256, 0, stream>>>(
        A, W_dec0, b_dec0, dinvR, perm, B, N);
    gemm_kernel<HID, IN_CH, false, false, true, false><<<2048, 256, 0, stream>>>(
        B, W_dec1, nullptr, dinvR, perm, A, N);
    agg_kernel<IN_CH, true, true><<<chunks * 4, 256, 0, stream>>>(
        A, x_recon, rowptr2, cnt2, col, dinvR, perm, b_dec1, N);
}

// Round 8
// 686.164 us; speedup vs baseline: 1.7019x; 1.0187x over previous
//
#include <hip/hip_runtime.h>
#include <hip/hip_bf16.h>

typedef unsigned long long u64;

static constexpr int IN_CH  = 32;
static constexpr int HID    = 64;
static constexpr int LAT    = 16;
static constexpr int NGRAPH = 64;
static constexpr int KB_CSR  = 24;     // blocks per bucket in csr_kernel

// RANK-SPACE pipeline with BUCKET-LOCAL degree sort: rank r of node n stays in
// the same 512-node window (r = (n>>9)*512 + local_rank_by_degree). Feature
// tensors, dinvR, pgR, CSR (col = rank[src]) all in rank space. Sliced
// [C/8][N][8] layout keeps each gather slice L2-resident per XCD
// (blockIdx%NSL pins slice->XCD). All agg inputs pre-scaled by dinv.
// CSR build: bhist -> bin (LDS counting sort by dst>>9) -> degb (per-bucket
// degree + local sort + rowptr, all in LDS) -> csr (bucket-local fill).

__device__ inline void add4(float4& a, const float4& b) {
    a.x += b.x; a.y += b.y; a.z += b.z; a.w += b.w;
}

// ---------------- bucket histogram of dst ----------------

__global__ __launch_bounds__(256) void bhist_kernel(const int* __restrict__ ei,
                                                    int* __restrict__ bh, int E) {
    __shared__ int lh[256];
    lh[threadIdx.x] = 0;
    __syncthreads();
    int base = blockIdx.x * 2048;
    #pragma unroll
    for (int j = 0; j < 8; j++) {
        int idx = base + j * 256 + threadIdx.x;
        if (idx < E) atomicAdd(&lh[ei[E + idx] >> 9], 1);
    }
    __syncthreads();
    if (lh[threadIdx.x]) atomicAdd(&bh[threadIdx.x], lh[threadIdx.x]);
}

// ---------------- LDS counting-sort binning by dst>>9 ----------------

__global__ __launch_bounds__(256) void bin_kernel(
        const int* __restrict__ ei, const int* __restrict__ bh,
        int* __restrict__ gcur, u64* __restrict__ sout, int E) {
    __shared__ int lhist[256], lscan[256], lcur[256], gbase[256], bbaseL[256];
    __shared__ u64 sbuf[2048];
    int tid = threadIdx.x;
    lhist[tid] = 0;
    {   // exclusive scan of bh -> bucket bases
        int v = bh[tid];
        lscan[tid] = v;
        for (int off = 1; off < 256; off <<= 1) {
            __syncthreads();
            int x = (tid >= off) ? lscan[tid - off] : 0;
            __syncthreads();
            lscan[tid] += x;
        }
        __syncthreads();
        bbaseL[tid] = lscan[tid] - v;
    }
    __syncthreads();
    int base = blockIdx.x * 2048;
    int cnt = min(2048, E - base);
    int myb[8]; u64 myp[8];
    #pragma unroll
    for (int j = 0; j < 8; j++) {
        int idx = base + j * 256 + tid;
        myb[j] = -1;
        if (idx < E) {
            int key = ei[E + idx], val = ei[idx];
            int b = key >> 9;
            myb[j] = b;
            myp[j] = ((u64)(unsigned)key << 32) | (unsigned)val;
            atomicAdd(&lhist[b], 1);
        }
    }
    __syncthreads();
    int v = lhist[tid];
    lscan[tid] = v;
    for (int off = 1; off < 256; off <<= 1) {
        __syncthreads();
        int x = (tid >= off) ? lscan[tid - off] : 0;
        __syncthreads();
        lscan[tid] += x;
    }
    __syncthreads();
    int excl = lscan[tid] - v;
    __syncthreads();
    lscan[tid] = excl;
    lcur[tid] = excl;
    __syncthreads();
    #pragma unroll
    for (int j = 0; j < 8; j++) {
        if (myb[j] >= 0) {
            int pos = atomicAdd(&lcur[myb[j]], 1);
            sbuf[pos] = myp[j];
        }
    }
    gbase[tid] = v ? atomicAdd(&gcur[tid], v) : 0;
    __syncthreads();
    for (int i = tid; i < cnt; i += 256) {
        u64 p = sbuf[i];
        int b = (int)(p >> 41);   // key>>9
        sout[bbaseL[b] + gbase[b] + (i - lscan[b])] = p;
    }
}

// ---------------- per-bucket: degree, local degree-sort, rowptr, metadata ----------------
// One block per dst-bucket b (512 nodes). rank r = (b<<9) + local_rank where
// local ranks sort the bucket's nodes by (clamped) degree. rowptr2[r] =
// bucket edge base + prefix of sorted degrees. Everything in LDS, no extra passes.

__global__ __launch_bounds__(256) void degb_kernel(
        const u64* __restrict__ staged, const int* __restrict__ bh,
        const int* __restrict__ batch,
        int* __restrict__ rank, int* __restrict__ perm, int* __restrict__ cnt2,
        int* __restrict__ rowptr2, float* __restrict__ dinvR,
        float2* __restrict__ pgR, int* __restrict__ bbase, int N, int E) {
    __shared__ int sc[256];
    __shared__ int ldeg[512], lrank[512], degS[512], psum[512];
    __shared__ int kcur[256];
    __shared__ int s0s, s1s;
    int b = blockIdx.x, tid = threadIdx.x;
    {   // scan bh -> this bucket's edge range [s0, s1)
        int bv = bh[tid];
        sc[tid] = bv;
        for (int off = 1; off < 256; off <<= 1) {
            __syncthreads();
            int x = (tid >= off) ? sc[tid - off] : 0;
            __syncthreads();
            sc[tid] += x;
        }
        __syncthreads();
        if (tid == b) { s0s = sc[tid] - bv; s1s = sc[tid]; }
    }
    ldeg[tid] = 0; ldeg[tid + 256] = 0;
    degS[tid] = 0; degS[tid + 256] = 0;
    kcur[tid] = 0;   // used first as khist
    __syncthreads();
    int s0 = s0s, s1 = s1s;
    int base = b << 9;
    for (int i = s0 + tid; i < s1; i += 256)
        atomicAdd(&ldeg[(int)(__builtin_nontemporal_load(&staged[i]) >> 32) - base], 1);
    __syncthreads();
    int k = N - base; k = k < 0 ? 0 : (k > 512 ? 512 : k);
    #pragma unroll
    for (int j = 0; j < 2; j++) {
        int t = tid + j * 256;
        if (t < k) atomicAdd(&kcur[min(ldeg[t], 255)], 1);
    }
    __syncthreads();
    {   // exclusive scan of key-histogram -> kcur = bucket offsets
        int hv = kcur[tid];
        sc[tid] = hv;
        for (int off = 1; off < 256; off <<= 1) {
            __syncthreads();
            int x = (tid >= off) ? sc[tid - off] : 0;
            __syncthreads();
            sc[tid] += x;
        }
        __syncthreads();
        kcur[tid] = sc[tid] - hv;
    }
    __syncthreads();
    #pragma unroll
    for (int j = 0; j < 2; j++) {
        int t = tid + j * 256;
        if (t < k) lrank[t] = atomicAdd(&kcur[min(ldeg[t], 255)], 1);
    }
    __syncthreads();
    #pragma unroll
    for (int j = 0; j < 2; j++) {
        int t = tid + j * 256;
        if (t < k) degS[lrank[t]] = ldeg[t];
    }
    __syncthreads();
    {   // exclusive scan of degS[512] -> psum (edge prefix in local-rank order)
        int v0 = degS[2 * tid], v1 = degS[2 * tid + 1];
        int T = v0 + v1;
        sc[tid] = T;
        for (int off = 1; off < 256; off <<= 1) {
            __syncthreads();
            int x = (tid >= off) ? sc[tid - off] : 0;
            __syncthreads();
            sc[tid] += x;
        }
        __syncthreads();
        int ex = sc[tid] - T;
        psum[2 * tid] = ex;
        psum[2 * tid + 1] = ex + v0;
    }
    __syncthreads();
    #pragma unroll
    for (int j = 0; j < 2; j++) {
        int t = tid + j * 256;
        if (t < k) {
            int n = base + t;
            int d = ldeg[t], lr = lrank[t];
            int r = base + lr;
            rank[n] = r;
            perm[r] = n;
            cnt2[r] = d;
            rowptr2[r] = s0 + psum[lr];
            float dv = rsqrtf((float)d + 1.0f);
            dinvR[r] = dv;
            pgR[r] = make_float2(dv, __int_as_float(batch[n]));
        }
    }
    if (tid == 0) {
        bbase[b] = s0;
        if (b == 255) bbase[256] = E;
    }
}

// ---------------- bucket-local CSR fill (col = rank[src]) ----------------

__global__ __launch_bounds__(256) void csr_kernel(
        const u64* __restrict__ staged, const int* __restrict__ bbase,
        const int* __restrict__ rank, const int* __restrict__ rowptr2,
        int* __restrict__ cur, int* __restrict__ col) {
    int bucket = blockIdx.x & 255;
    int k = blockIdx.x >> 8;
    int s0 = bbase[bucket], s1 = bbase[bucket + 1];
    for (int i = s0 + k * 256 + threadIdx.x; i < s1; i += 256 * KB_CSR) {
        u64 p = __builtin_nontemporal_load(&staged[i]);
        int dst = (int)(p >> 32);
        int src = (int)(p & 0xffffffffu);
        int rd = rank[dst];            // dst-local window: hot
        int pos = rowptr2[rd] + atomicAdd(&cur[rd], 1);
        col[pos] = rank[src];          // random over 400KB rank table: L2-resident
    }
}

// ---------------- x -> rank-space sliced layout, pre-scaled ----------------

__global__ void slice_x_kernel(const float* __restrict__ x, const int* __restrict__ perm,
                               const float* __restrict__ dinvR,
                               float* __restrict__ xs, int N) {
    int idx = blockIdx.x * 256 + threadIdx.x;   // over N*2
    if (idx >= N * 2) return;
    int r = idx >> 1, h = idx & 1;
    int sl = blockIdx.y;
    int n = perm[r];                            // local window gather
    float4 v = ((const float4*)x)[(size_t)n * 8 + sl * 2 + h];
    float dn = dinvR[r];
    v.x *= dn; v.y *= dn; v.z *= dn; v.w *= dn;
    ((float4*)(xs + (size_t)sl * N * 8))[idx] = v;
}

// ---------------- aggregation (rank space; R5-proven body) ----------------
// out[r] = dinvR[r] * (in[r] + sum_{sr in row r} in[sr])   [+bias]
// Lane pair shares a row: lane h owns half h (16B); the pair's two 16B gathers
// of the SAME edge coalesce into one 32B L2 request.

template <int C, bool ADD_BIAS, bool OUT_ROWMAJOR>
__global__ __launch_bounds__(256) void agg_kernel(
        const float* __restrict__ in, float* __restrict__ out,
        const int* __restrict__ rowptr2, const int* __restrict__ cnt2,
        const int* __restrict__ col, const float* __restrict__ dinvR,
        const int* __restrict__ perm, const float* __restrict__ bias, int N) {
    constexpr int NSL = C / 8;
    int sl = blockIdx.x % NSL;
    int chunk = blockIdx.x / NSL;
    int slot = threadIdx.x >> 1, h = threadIdx.x & 1;
    int r = chunk * 128 + slot;
    if (r >= N) return;
    const float4* inS = (const float4*)(in + (size_t)sl * N * 8);
    int start = rowptr2[r], m = cnt2[r];
    const int* cp = col + start;
    float4 acc = inS[(size_t)r * 2 + h];   // self (own half)
    int i = 0;
    for (; i + 8 <= m; i += 8) {
        int s0 = cp[i], s1 = cp[i+1], s2 = cp[i+2], s3 = cp[i+3];
        int s4 = cp[i+4], s5 = cp[i+5], s6 = cp[i+6], s7 = cp[i+7];
        float4 v0 = inS[(size_t)s0*2+h], v1 = inS[(size_t)s1*2+h];
        float4 v2 = inS[(size_t)s2*2+h], v3 = inS[(size_t)s3*2+h];
        float4 v4 = inS[(size_t)s4*2+h], v5 = inS[(size_t)s5*2+h];
        float4 v6 = inS[(size_t)s6*2+h], v7 = inS[(size_t)s7*2+h];
        add4(v0, v1); add4(v2, v3); add4(v4, v5); add4(v6, v7);
        add4(v0, v2); add4(v4, v6);
        add4(acc, v0); add4(acc, v4);
    }
    if (i + 4 <= m) {
        int s0 = cp[i], s1 = cp[i+1], s2 = cp[i+2], s3 = cp[i+3];
        float4 v0 = inS[(size_t)s0*2+h], v1 = inS[(size_t)s1*2+h];
        float4 v2 = inS[(size_t)s2*2+h], v3 = inS[(size_t)s3*2+h];
        add4(v0, v1); add4(v2, v3); add4(v0, v2);
        add4(acc, v0);
        i += 4;
    }
    for (; i < m; ++i) {
        int c = cp[i];
        add4(acc, inS[(size_t)c * 2 + h]);
    }
    float dn = dinvR[r];
    acc.x *= dn; acc.y *= dn; acc.z *= dn; acc.w *= dn;
    if (ADD_BIAS) {
        float4 b4 = ((const float4*)bias)[sl * 2 + h];
        add4(acc, b4);
    }
    if (OUT_ROWMAJOR) ((float4*)out)[(size_t)perm[r] * (C / 4) + sl * 2 + h] = acc;
    else ((float4*)(out + (size_t)sl * N * 8))[(size_t)r * 2 + h] = acc;
}

// ---------------- group-agg for decoder conv0 ----------------
// Input d[r] = dinv[r]*dg[group[r]] has only 64 distinct 64ch rows -> LDS.

__global__ __launch_bounds__(256) void gagg_kernel(
        const float* __restrict__ dg, const float2* __restrict__ pgR,
        const int* __restrict__ rowptr2, const int* __restrict__ cnt2,
        const int* __restrict__ col, float* __restrict__ out, int N) {
    __shared__ float dgL[NGRAPH * 68];   // padded stride 68 floats (17 float4)
    for (int i = threadIdx.x; i < NGRAPH * 64; i += 256)
        dgL[(i >> 6) * 68 + (i & 63)] = dg[i];
    __syncthreads();
    int slot = threadIdx.x >> 1, e = threadIdx.x & 1;   // e: channel half (32ch)
    int r = blockIdx.x * 128 + slot;
    if (r >= N) return;
    const float4* dgL4 = (const float4*)dgL;            // row stride 17
    int start = rowptr2[r], m = cnt2[r];
    const int* cp = col + start;
    float2 ps = pgR[r];
    float dn = ps.x;
    int gs = __float_as_int(ps.y);
    float4 acc[8];
    {
        const float4* rp = dgL4 + gs * 17 + e * 8;
        #pragma unroll
        for (int j = 0; j < 8; ++j) {
            float4 v = rp[j];
            acc[j] = make_float4(dn * v.x, dn * v.y, dn * v.z, dn * v.w);
        }
    }
    int i = 0;
    for (; i + 2 <= m; i += 2) {
        int c0 = cp[i], c1 = cp[i + 1];
        float2 p0 = pgR[c0], p1 = pgR[c1];
        const float4* r0 = dgL4 + __float_as_int(p0.y) * 17 + e * 8;
        const float4* r1 = dgL4 + __float_as_int(p1.y) * 17 + e * 8;
        float w0 = p0.x, w1 = p1.x;
        #pragma unroll
        for (int j = 0; j < 8; ++j) {
            float4 v0 = r0[j], v1 = r1[j];
            acc[j].x += w0 * v0.x + w1 * v1.x;
            acc[j].y += w0 * v0.y + w1 * v1.y;
            acc[j].z += w0 * v0.z + w1 * v1.z;
            acc[j].w += w0 * v0.w + w1 * v1.w;
        }
    }
    if (i < m) {
        int c0 = cp[i];
        float2 p0 = pgR[c0];
        const float4* r0 = dgL4 + __float_as_int(p0.y) * 17 + e * 8;
        float w0 = p0.x;
        #pragma unroll
        for (int j = 0; j < 8; ++j) {
            float4 v0 = r0[j];
            acc[j].x += w0 * v0.x; acc[j].y += w0 * v0.y;
            acc[j].z += w0 * v0.z; acc[j].w += w0 * v0.w;
        }
    }
    #pragma unroll
    for (int k = 0; k < 4; ++k) {
        #pragma unroll
        for (int jj = 0; jj < 2; ++jj) {
            float4 v = acc[k * 2 + jj];
            v.x *= dn; v.y *= dn; v.z *= dn; v.w *= dn;
            ((float4*)(out + (size_t)(4 * e + k) * N * 8))[(size_t)r * 2 + jj] = v;
        }
    }
}

// ---------------- dense transform: W column in registers, x broadcast from LDS ----------------

template <int CIN, int COUT, bool RELU, bool BIAS, bool SCALE, bool OUT_ROWMAJOR>
__global__ __launch_bounds__(256) void gemm_kernel(
        const float* __restrict__ in, const float* __restrict__ W,
        const float* __restrict__ b, const float* __restrict__ dinvR,
        const int* __restrict__ perm, float* __restrict__ out, int N) {
    constexpr int NPB = 256 / COUT;
    constexpr int K4 = CIN / 4;
    __shared__ float4 xsh[NPB * K4];
    int r  = threadIdx.x / COUT;
    int co = threadIdx.x % COUT;
    float w[CIN];
    #pragma unroll
    for (int k = 0; k < CIN; ++k) w[k] = W[k * COUT + co];
    float bsv = BIAS ? b[co] : 0.f;
    int ngroups = (N + NPB - 1) / NPB;
    for (int grp = blockIdx.x; grp < ngroups; grp += gridDim.x) {
        int base = grp * NPB;
        __syncthreads();
        for (int i = threadIdx.x; i < NPB * K4; i += 256) {
            int rr = i / K4, k4 = i % K4;
            int n = base + rr;
            float4 v = make_float4(0.f, 0.f, 0.f, 0.f);
            if (n < N) v = ((const float4*)(in + (size_t)(k4 >> 1) * N * 8))[(size_t)n * 2 + (k4 & 1)];
            xsh[i] = v;
        }
        __syncthreads();
        int n = base + r;
        if (n < N) {
            float acc = bsv;
            #pragma unroll
            for (int k4 = 0; k4 < K4; ++k4) {
                float4 xv = xsh[r * K4 + k4];   // wave-uniform -> LDS broadcast
                acc += xv.x * w[4 * k4] + xv.y * w[4 * k4 + 1]
                     + xv.z * w[4 * k4 + 2] + xv.w * w[4 * k4 + 3];
            }
            if (RELU) acc = fmaxf(acc, 0.f);
            if (SCALE) acc *= dinvR[n];
            if (OUT_ROWMAJOR) out[(size_t)perm[n] * COUT + co] = acc;
            else out[(size_t)(co >> 3) * N * 8 + (size_t)n * 8 + (co & 7)] = acc;
        }
    }
}

// ---------------- pooling over sorted batch ids (row-major, original order) ----------------

__global__ __launch_bounds__(256) void pool_kernel(
        const float* __restrict__ h, const int* __restrict__ batch,
        float* __restrict__ sums, int* __restrict__ cntb, int N) {
    const int CHUNK = 512;
    int chunkStart = blockIdx.x * CHUNK;
    int c = threadIdx.x & 63;
    int r = threadIdx.x >> 6;
    int curg = -1;
    float acc = 0.f;
    int cnt = 0;
    int end = chunkStart + CHUNK;
    if (end > N) end = N;
    for (int n = chunkStart + r; n < end; n += 4) {
        int g = batch[n];
        if (g != curg) {
            if (curg >= 0) {
                atomicAdd(&sums[curg * 64 + c], acc);
                if (c == 0) atomicAdd(&cntb[curg], cnt);
            }
            curg = g; acc = 0.f; cnt = 0;
        }
        acc += h[(size_t)n * 64 + c];
        cnt++;
    }
    if (curg >= 0) {
        atomicAdd(&sums[curg * 64 + c], acc);
        if (c == 0) atomicAdd(&cntb[curg], cnt);
    }
}

// ---------------- latent ----------------

__global__ __launch_bounds__(1024) void latent_kernel(
        const float* __restrict__ sums, const int* __restrict__ cntb,
        const float* __restrict__ Wp, const float* __restrict__ bp,
        const float* __restrict__ Wd, const float* __restrict__ bd,
        float* __restrict__ z_out, float* __restrict__ dg) {
    __shared__ float zl[NGRAPH * LAT];
    int t = threadIdx.x;
    {
        int g = t / LAT, l = t % LAT;
        float cf = (float)cntb[g];
        float inv = 1.0f / fmaxf(cf, 1.0f);
        float acc = bp[l];
        #pragma unroll
        for (int k = 0; k < HID; k++) acc += sums[g * HID + k] * inv * Wp[k * LAT + l];
        zl[t] = acc;
        z_out[t] = acc;
    }
    __syncthreads();
    #pragma unroll
    for (int i = 0; i < 4; i++) {
        int idx = t + i * 1024;
        int g = idx >> 6, c = idx & 63;
        float acc = bd[c];
        #pragma unroll
        for (int l = 0; l < LAT; l++) acc += zl[g * LAT + l] * Wd[l * HID + c];
        dg[idx] = fmaxf(acc, 0.f);
    }
}

// ---------------- launch ----------------

extern "C" void kernel_launch(void* const* d_in, const int* in_sizes, int n_in,
                              void* d_out, int out_size, void* d_ws, size_t ws_size,
                              hipStream_t stream) {
    const float* x          = (const float*)d_in[0];
    const int*   ei         = (const int*)d_in[1];
    const int*   batch      = (const int*)d_in[2];
    const float* W_enc0     = (const float*)d_in[3];
    const float* b_enc0     = (const float*)d_in[4];
    const float* W_enc1     = (const float*)d_in[5];
    const float* b_enc1     = (const float*)d_in[6];
    const float* W_enc2     = (const float*)d_in[7];
    const float* b_enc2     = (const float*)d_in[8];
    const float* W_proj     = (const float*)d_in[9];
    const float* b_proj     = (const float*)d_in[10];
    const float* W_dec_proj = (const float*)d_in[11];
    const float* b_dec_proj = (const float*)d_in[12];
    const float* W_dec0     = (const float*)d_in[13];
    const float* b_dec0     = (const float*)d_in[14];
    const float* W_dec1     = (const float*)d_in[15];
    const float* b_dec1     = (const float*)d_in[16];

    const int N = in_sizes[0] / IN_CH;
    const int E = in_sizes[1] / 2;

    char* ws = (char*)d_ws;
    size_t off = 0;
    auto alloc = [&](size_t bytes) {
        void* p = ws + off;
        off += (bytes + 255) & ~(size_t)255;
        return p;
    };
    float* A       = (float*)alloc((size_t)N * HID * 4);
    float* B       = (float*)alloc((size_t)N * HID * 4);
    float* XS      = (float*)alloc((size_t)N * IN_CH * 4); // aliases staged1
    int*   col     = (int*)  alloc((size_t)E * 4);
    int*   cnt2    = (int*)  alloc((size_t)N * 4);
    int*   rowptr2 = (int*)  alloc((size_t)(N + 1) * 4);
    int*   perm    = (int*)  alloc((size_t)N * 4);
    int*   rank    = (int*)  alloc((size_t)N * 4);
    float* dinvR   = (float*)alloc((size_t)N * 4);
    float2* pgR    = (float2*)alloc((size_t)N * 8);
    int*   bbase   = (int*)  alloc(257 * 4);
    // ---- zero-initialized region (single memset) ----
    char* zbase = ws + off;
    int*   cursor  = (int*)  alloc((size_t)N * 4);
    int*   bh      = (int*)  alloc(256 * 4);
    int*   gcurD   = (int*)  alloc(256 * 4);
    float* sums    = (float*)alloc((size_t)NGRAPH * HID * 4);
    int*   cntb    = (int*)  alloc((size_t)NGRAPH * 4);
    size_t zbytes = (size_t)((ws + off) - zbase);
    float* dg      = (float*)alloc((size_t)NGRAPH * HID * 4);

    u64* staged1 = (u64*)XS;   // dead before slice_x writes XS

    float* x_recon = (float*)d_out;
    float* z_out   = (float*)d_out + (size_t)N * IN_CH;

    hipMemsetAsync(zbase, 0, zbytes, stream);

    int ebins = (E + 2047) / 2048;
    int chunks = (N + 127) / 128;

    // CSR build with bucket-local degree sort
    bhist_kernel<<<ebins, 256, 0, stream>>>(ei, bh, E);
    bin_kernel<<<ebins, 256, 0, stream>>>(ei, bh, gcurD, staged1, E);
    degb_kernel<<<256, 256, 0, stream>>>(staged1, bh, batch, rank, perm, cnt2,
                                         rowptr2, dinvR, pgR, bbase, N, E);
    csr_kernel<<<256 * KB_CSR, 256, 0, stream>>>(staged1, bbase, rank, rowptr2, cursor, col);

    {
        dim3 g((N * 2 + 255) / 256, IN_CH / 8);
        slice_x_kernel<<<g, 256, 0, stream>>>(x, perm, dinvR, XS, N);
    }

    // encoder (rank space)
    agg_kernel<IN_CH, false, false><<<chunks * 4, 256, 0, stream>>>(
        XS, A, rowptr2, cnt2, col, dinvR, perm, nullptr, N);
    gemm_kernel<IN_CH, HID, true, true, true, false><<<2048, 256, 0, stream>>>(
        A, W_enc0, b_enc0, dinvR, perm, B, N);
    agg_kernel<HID, false, false><<<chunks * 8, 256, 0, stream>>>(
        B, A, rowptr2, cnt2, col, dinvR, perm, nullptr, N);
    gemm_kernel<HID, HID, true, true, true, false><<<2048, 256, 0, stream>>>(
        A, W_enc1, b_enc1, dinvR, perm, B, N);
    agg_kernel<HID, false, false><<<chunks * 8, 256, 0, stream>>>(
        B, A, rowptr2, cnt2, col, dinvR, perm, nullptr, N);
    gemm_kernel<HID, HID, true, true, false, true><<<2048, 256, 0, stream>>>(
        A, W_enc2, b_enc2, dinvR, perm, B, N);   // scatter to ORIGINAL order for pool

    // pool + latent
    pool_kernel<<<(N + 511) / 512, 256, 0, stream>>>(B, batch, sums, cntb, N);
    latent_kernel<<<1, 1024, 0, stream>>>(sums, cntb, W_proj, b_proj, W_dec_proj, b_dec_proj, z_out, dg);

    // decoder (rank space): group-agg replaces bcast + generic agg
    gagg_kernel<<<chunks, 256, 0, stream>>>(dg, pgR, rowptr2, cnt2, col, A, N);
    gemm_kernel<HID, HID, true, true, false, false><<<2048, 256, 0, stream>>>(
        A, W_dec0, b_dec0, dinvR, perm, B, N);
    gemm_kernel<HID, IN_CH, false, false, true, false><<<2048, 256, 0, stream>>>(
        B, W_dec1, nullptr, dinvR, perm, A, N);
    agg_kernel<IN_CH, true, true><<<chunks * 4, 256, 0, stream>>>(
        A, x_recon, rowptr2, cnt2, col, dinvR, perm, b_dec1, N);
}

// Round 9
// 638.657 us; speedup vs baseline: 1.8285x; 1.0744x over previous
//
#include <hip/hip_runtime.h>
#include <hip/hip_bf16.h>

typedef unsigned long long u64;

static constexpr int IN_CH  = 32;
static constexpr int HID    = 64;
static constexpr int LAT    = 16;
static constexpr int NGRAPH = 64;
static constexpr int KB_CSR  = 24;     // blocks per bucket in csr_kernel
static constexpr int CPB     = 4;      // chunks (128 rows) per 512-node bucket

// RANK-SPACE pipeline with BUCKET-LOCAL degree sort (rank r of node n stays in
// n's 512-window, ordered by degree within it). Feature tensors, dinvR, pgR,
// CSR (col = rank[src]) all in rank space. Sliced [C/8][N][8] layout keeps each
// gather slice L2-resident per XCD (blockIdx%NSL pins slice->XCD). All agg
// inputs pre-scaled by dinv.
// Agg schedule: QUARTER-INTERLEAVE — chunk = (o%NBK)*CPB + o/NBK so each
// dispatch round covers the same degree-quarter of many buckets -> uniform
// rounds (restores R5's global-sort concurrency without the global sort).

__device__ inline void add4(float4& a, const float4& b) {
    a.x += b.x; a.y += b.y; a.z += b.z; a.w += b.w;
}

// ---------------- bucket histogram of dst ----------------

__global__ __launch_bounds__(256) void bhist_kernel(const int* __restrict__ ei,
                                                    int* __restrict__ bh, int E) {
    __shared__ int lh[256];
    lh[threadIdx.x] = 0;
    __syncthreads();
    int base = blockIdx.x * 2048;
    #pragma unroll
    for (int j = 0; j < 8; j++) {
        int idx = base + j * 256 + threadIdx.x;
        if (idx < E) atomicAdd(&lh[ei[E + idx] >> 9], 1);
    }
    __syncthreads();
    if (lh[threadIdx.x]) atomicAdd(&bh[threadIdx.x], lh[threadIdx.x]);
}

// ---------------- LDS counting-sort binning by dst>>9 ----------------

__global__ __launch_bounds__(256) void bin_kernel(
        const int* __restrict__ ei, const int* __restrict__ bh,
        int* __restrict__ gcur, u64* __restrict__ sout, int E) {
    __shared__ int lhist[256], lscan[256], lcur[256], gbase[256], bbaseL[256];
    __shared__ u64 sbuf[2048];
    int tid = threadIdx.x;
    lhist[tid] = 0;
    {   // exclusive scan of bh -> bucket bases
        int v = bh[tid];
        lscan[tid] = v;
        for (int off = 1; off < 256; off <<= 1) {
            __syncthreads();
            int x = (tid >= off) ? lscan[tid - off] : 0;
            __syncthreads();
            lscan[tid] += x;
        }
        __syncthreads();
        bbaseL[tid] = lscan[tid] - v;
    }
    __syncthreads();
    int base = blockIdx.x * 2048;
    int cnt = min(2048, E - base);
    int myb[8]; u64 myp[8];
    #pragma unroll
    for (int j = 0; j < 8; j++) {
        int idx = base + j * 256 + tid;
        myb[j] = -1;
        if (idx < E) {
            int key = ei[E + idx], val = ei[idx];
            int b = key >> 9;
            myb[j] = b;
            myp[j] = ((u64)(unsigned)key << 32) | (unsigned)val;
            atomicAdd(&lhist[b], 1);
        }
    }
    __syncthreads();
    int v = lhist[tid];
    lscan[tid] = v;
    for (int off = 1; off < 256; off <<= 1) {
        __syncthreads();
        int x = (tid >= off) ? lscan[tid - off] : 0;
        __syncthreads();
        lscan[tid] += x;
    }
    __syncthreads();
    int excl = lscan[tid] - v;
    __syncthreads();
    lscan[tid] = excl;
    lcur[tid] = excl;
    __syncthreads();
    #pragma unroll
    for (int j = 0; j < 8; j++) {
        if (myb[j] >= 0) {
            int pos = atomicAdd(&lcur[myb[j]], 1);
            sbuf[pos] = myp[j];
        }
    }
    gbase[tid] = v ? atomicAdd(&gcur[tid], v) : 0;
    __syncthreads();
    for (int i = tid; i < cnt; i += 256) {
        u64 p = sbuf[i];
        int b = (int)(p >> 41);   // key>>9
        sout[bbaseL[b] + gbase[b] + (i - lscan[b])] = p;
    }
}

// ---------------- per-bucket: degree, local degree-sort, rowptr, metadata ----------------

__global__ __launch_bounds__(256) void degb_kernel(
        const u64* __restrict__ staged, const int* __restrict__ bh,
        const int* __restrict__ batch,
        int* __restrict__ rank, int* __restrict__ perm, int* __restrict__ cnt2,
        int* __restrict__ rowptr2, float* __restrict__ dinvR,
        float2* __restrict__ pgR, int* __restrict__ bbase, int N, int E) {
    __shared__ int sc[256];
    __shared__ int ldeg[512], lrank[512], degS[512], psum[512];
    __shared__ int kcur[256];
    __shared__ int s0s, s1s;
    int b = blockIdx.x, tid = threadIdx.x;
    {   // scan bh -> this bucket's edge range [s0, s1)
        int bv = bh[tid];
        sc[tid] = bv;
        for (int off = 1; off < 256; off <<= 1) {
            __syncthreads();
            int x = (tid >= off) ? sc[tid - off] : 0;
            __syncthreads();
            sc[tid] += x;
        }
        __syncthreads();
        if (tid == b) { s0s = sc[tid] - bv; s1s = sc[tid]; }
    }
    ldeg[tid] = 0; ldeg[tid + 256] = 0;
    degS[tid] = 0; degS[tid + 256] = 0;
    kcur[tid] = 0;   // used first as khist
    __syncthreads();
    int s0 = s0s, s1 = s1s;
    int base = b << 9;
    for (int i = s0 + tid; i < s1; i += 256)
        atomicAdd(&ldeg[(int)(__builtin_nontemporal_load(&staged[i]) >> 32) - base], 1);
    __syncthreads();
    int k = N - base; k = k < 0 ? 0 : (k > 512 ? 512 : k);
    #pragma unroll
    for (int j = 0; j < 2; j++) {
        int t = tid + j * 256;
        if (t < k) atomicAdd(&kcur[min(ldeg[t], 255)], 1);
    }
    __syncthreads();
    {   // exclusive scan of key-histogram -> kcur = bucket offsets
        int hv = kcur[tid];
        sc[tid] = hv;
        for (int off = 1; off < 256; off <<= 1) {
            __syncthreads();
            int x = (tid >= off) ? sc[tid - off] : 0;
            __syncthreads();
            sc[tid] += x;
        }
        __syncthreads();
        kcur[tid] = sc[tid] - hv;
    }
    __syncthreads();
    #pragma unroll
    for (int j = 0; j < 2; j++) {
        int t = tid + j * 256;
        if (t < k) lrank[t] = atomicAdd(&kcur[min(ldeg[t], 255)], 1);
    }
    __syncthreads();
    #pragma unroll
    for (int j = 0; j < 2; j++) {
        int t = tid + j * 256;
        if (t < k) degS[lrank[t]] = ldeg[t];
    }
    __syncthreads();
    {   // exclusive scan of degS[512] -> psum (edge prefix in local-rank order)
        int v0 = degS[2 * tid], v1 = degS[2 * tid + 1];
        int T = v0 + v1;
        sc[tid] = T;
        for (int off = 1; off < 256; off <<= 1) {
            __syncthreads();
            int x = (tid >= off) ? sc[tid - off] : 0;
            __syncthreads();
            sc[tid] += x;
        }
        __syncthreads();
        int ex = sc[tid] - T;
        psum[2 * tid] = ex;
        psum[2 * tid + 1] = ex + v0;
    }
    __syncthreads();
    #pragma unroll
    for (int j = 0; j < 2; j++) {
        int t = tid + j * 256;
        if (t < k) {
            int n = base + t;
            int d = ldeg[t], lr = lrank[t];
            int r = base + lr;
            rank[n] = r;
            perm[r] = n;
            cnt2[r] = d;
            rowptr2[r] = s0 + psum[lr];
            float dv = rsqrtf((float)d + 1.0f);
            dinvR[r] = dv;
            pgR[r] = make_float2(dv, __int_as_float(batch[n]));
        }
    }
    if (tid == 0) {
        bbase[b] = s0;
        if (b == 255) bbase[256] = E;
    }
}

// ---------------- bucket-local CSR fill (col = rank[src]) ----------------

__global__ __launch_bounds__(256) void csr_kernel(
        const u64* __restrict__ staged, const int* __restrict__ bbase,
        const int* __restrict__ rank, const int* __restrict__ rowptr2,
        int* __restrict__ cur, int* __restrict__ col) {
    int bucket = blockIdx.x & 255;
    int k = blockIdx.x >> 8;
    int s0 = bbase[bucket], s1 = bbase[bucket + 1];
    for (int i = s0 + k * 256 + threadIdx.x; i < s1; i += 256 * KB_CSR) {
        u64 p = __builtin_nontemporal_load(&staged[i]);
        int dst = (int)(p >> 32);
        int src = (int)(p & 0xffffffffu);
        int rd = rank[dst];            // dst-local window: hot
        int pos = rowptr2[rd] + atomicAdd(&cur[rd], 1);
        col[pos] = rank[src];          // random over 400KB rank table: L2-resident
    }
}

// ---------------- x -> rank-space sliced layout, pre-scaled ----------------

__global__ void slice_x_kernel(const float* __restrict__ x, const int* __restrict__ perm,
                               const float* __restrict__ dinvR,
                               float* __restrict__ xs, int N) {
    int idx = blockIdx.x * 256 + threadIdx.x;   // over N*2
    if (idx >= N * 2) return;
    int r = idx >> 1, h = idx & 1;
    int sl = blockIdx.y;
    int n = perm[r];                            // local window gather
    float4 v = ((const float4*)x)[(size_t)n * 8 + sl * 2 + h];
    float dn = dinvR[r];
    v.x *= dn; v.y *= dn; v.z *= dn; v.w *= dn;
    ((float4*)(xs + (size_t)sl * N * 8))[idx] = v;
}

// ---------------- aggregation (rank space; quarter-interleaved schedule) ----------------
// out[r] = dinvR[r] * (in[r] + sum_{sr in row r} in[sr])   [+bias]
// Lane pair shares a row: lane h owns half h (16B); the pair's two 16B gathers
// of the SAME edge coalesce into one 32B L2 request.

template <int C, bool ADD_BIAS, bool OUT_ROWMAJOR>
__global__ __launch_bounds__(256) void agg_kernel(
        const float* __restrict__ in, float* __restrict__ out,
        const int* __restrict__ rowptr2, const int* __restrict__ cnt2,
        const int* __restrict__ col, const float* __restrict__ dinvR,
        const int* __restrict__ perm, const float* __restrict__ bias,
        int nbk, int N) {
    constexpr int NSL = C / 8;
    int sl = blockIdx.x % NSL;
    int o  = blockIdx.x / NSL;
    int chunk = (o % nbk) * CPB + (o / nbk);   // quarter-interleave
    int slot = threadIdx.x >> 1, h = threadIdx.x & 1;
    int r = chunk * 128 + slot;
    if (r >= N) return;
    const float4* inS = (const float4*)(in + (size_t)sl * N * 8);
    int start = rowptr2[r], m = cnt2[r];
    const int* cp = col + start;
    float4 acc = inS[(size_t)r * 2 + h];   // self (own half)
    int i = 0;
    for (; i + 8 <= m; i += 8) {
        int s0 = cp[i], s1 = cp[i+1], s2 = cp[i+2], s3 = cp[i+3];
        int s4 = cp[i+4], s5 = cp[i+5], s6 = cp[i+6], s7 = cp[i+7];
        float4 v0 = inS[(size_t)s0*2+h], v1 = inS[(size_t)s1*2+h];
        float4 v2 = inS[(size_t)s2*2+h], v3 = inS[(size_t)s3*2+h];
        float4 v4 = inS[(size_t)s4*2+h], v5 = inS[(size_t)s5*2+h];
        float4 v6 = inS[(size_t)s6*2+h], v7 = inS[(size_t)s7*2+h];
        add4(v0, v1); add4(v2, v3); add4(v4, v5); add4(v6, v7);
        add4(v0, v2); add4(v4, v6);
        add4(acc, v0); add4(acc, v4);
    }
    if (i + 4 <= m) {
        int s0 = cp[i], s1 = cp[i+1], s2 = cp[i+2], s3 = cp[i+3];
        float4 v0 = inS[(size_t)s0*2+h], v1 = inS[(size_t)s1*2+h];
        float4 v2 = inS[(size_t)s2*2+h], v3 = inS[(size_t)s3*2+h];
        add4(v0, v1); add4(v2, v3); add4(v0, v2);
        add4(acc, v0);
        i += 4;
    }
    for (; i < m; ++i) {
        int c = cp[i];
        add4(acc, inS[(size_t)c * 2 + h]);
    }
    float dn = dinvR[r];
    acc.x *= dn; acc.y *= dn; acc.z *= dn; acc.w *= dn;
    if (ADD_BIAS) {
        float4 b4 = ((const float4*)bias)[sl * 2 + h];
        add4(acc, b4);
    }
    if (OUT_ROWMAJOR) ((float4*)out)[(size_t)perm[r] * (C / 4) + sl * 2 + h] = acc;
    else ((float4*)(out + (size_t)sl * N * 8))[(size_t)r * 2 + h] = acc;
}

// ---------------- group-agg for decoder conv0 ----------------
// Input d[r] = dinv[r]*dg[group[r]] has only 64 distinct 64ch rows -> LDS.

__global__ __launch_bounds__(256) void gagg_kernel(
        const float* __restrict__ dg, const float2* __restrict__ pgR,
        const int* __restrict__ rowptr2, const int* __restrict__ cnt2,
        const int* __restrict__ col, float* __restrict__ out, int nbk, int N) {
    __shared__ float dgL[NGRAPH * 68];   // padded stride 68 floats (17 float4)
    for (int i = threadIdx.x; i < NGRAPH * 64; i += 256)
        dgL[(i >> 6) * 68 + (i & 63)] = dg[i];
    __syncthreads();
    int slot = threadIdx.x >> 1, e = threadIdx.x & 1;   // e: channel half (32ch)
    int o = blockIdx.x;
    int chunk = (o % nbk) * CPB + (o / nbk);            // quarter-interleave
    int r = chunk * 128 + slot;
    if (r >= N) return;
    const float4* dgL4 = (const float4*)dgL;            // row stride 17
    int start = rowptr2[r], m = cnt2[r];
    const int* cp = col + start;
    float2 ps = pgR[r];
    float dn = ps.x;
    int gs = __float_as_int(ps.y);
    float4 acc[8];
    {
        const float4* rp = dgL4 + gs * 17 + e * 8;
        #pragma unroll
        for (int j = 0; j < 8; ++j) {
            float4 v = rp[j];
            acc[j] = make_float4(dn * v.x, dn * v.y, dn * v.z, dn * v.w);
        }
    }
    int i = 0;
    for (; i + 2 <= m; i += 2) {
        int c0 = cp[i], c1 = cp[i + 1];
        float2 p0 = pgR[c0], p1 = pgR[c1];
        const float4* r0 = dgL4 + __float_as_int(p0.y) * 17 + e * 8;
        const float4* r1 = dgL4 + __float_as_int(p1.y) * 17 + e * 8;
        float w0 = p0.x, w1 = p1.x;
        #pragma unroll
        for (int j = 0; j < 8; ++j) {
            float4 v0 = r0[j], v1 = r1[j];
            acc[j].x += w0 * v0.x + w1 * v1.x;
            acc[j].y += w0 * v0.y + w1 * v1.y;
            acc[j].z += w0 * v0.z + w1 * v1.z;
            acc[j].w += w0 * v0.w + w1 * v1.w;
        }
    }
    if (i < m) {
        int c0 = cp[i];
        float2 p0 = pgR[c0];
        const float4* r0 = dgL4 + __float_as_int(p0.y) * 17 + e * 8;
        float w0 = p0.x;
        #pragma unroll
        for (int j = 0; j < 8; ++j) {
            float4 v0 = r0[j];
            acc[j].x += w0 * v0.x; acc[j].y += w0 * v0.y;
            acc[j].z += w0 * v0.z; acc[j].w += w0 * v0.w;
        }
    }
    #pragma unroll
    for (int k = 0; k < 4; ++k) {
        #pragma unroll
        for (int jj = 0; jj < 2; ++jj) {
            float4 v = acc[k * 2 + jj];
            v.x *= dn; v.y *= dn; v.z *= dn; v.w *= dn;
            ((float4*)(out + (size_t)(4 * e + k) * N * 8))[(size_t)r * 2 + jj] = v;
        }
    }
}

// ---------------- dense transform: W column in registers, x broadcast from LDS ----------------

template <int CIN, int COUT, bool RELU, bool BIAS, bool SCALE, bool OUT_ROWMAJOR>
__global__ __launch_bounds__(256) void gemm_kernel(
        const float* __restrict__ in, const float* __restrict__ W,
        const float* __restrict__ b, const float* __restrict__ dinvR,
        const int* __restrict__ perm, float* __restrict__ out, int N) {
    constexpr int NPB = 256 / COUT;
    constexpr int K4 = CIN / 4;
    __shared__ float4 xsh[NPB * K4];
    int r  = threadIdx.x / COUT;
    int co = threadIdx.x % COUT;
    float w[CIN];
    #pragma unroll
    for (int k = 0; k < CIN; ++k) w[k] = W[k * COUT + co];
    float bsv = BIAS ? b[co] : 0.f;
    int ngroups = (N + NPB - 1) / NPB;
    for (int grp = blockIdx.x; grp < ngroups; grp += gridDim.x) {
        int base = grp * NPB;
        __syncthreads();
        for (int i = threadIdx.x; i < NPB * K4; i += 256) {
            int rr = i / K4, k4 = i % K4;
            int n = base + rr;
            float4 v = make_float4(0.f, 0.f, 0.f, 0.f);
            if (n < N) v = ((const float4*)(in + (size_t)(k4 >> 1) * N * 8))[(size_t)n * 2 + (k4 & 1)];
            xsh[i] = v;
        }
        __syncthreads();
        int n = base + r;
        if (n < N) {
            float acc = bsv;
            #pragma unroll
            for (int k4 = 0; k4 < K4; ++k4) {
                float4 xv = xsh[r * K4 + k4];   // wave-uniform -> LDS broadcast
                acc += xv.x * w[4 * k4] + xv.y * w[4 * k4 + 1]
                     + xv.z * w[4 * k4 + 2] + xv.w * w[4 * k4 + 3];
            }
            if (RELU) acc = fmaxf(acc, 0.f);
            if (SCALE) acc *= dinvR[n];
            if (OUT_ROWMAJOR) out[(size_t)perm[n] * COUT + co] = acc;
            else out[(size_t)(co >> 3) * N * 8 + (size_t)n * 8 + (co & 7)] = acc;
        }
    }
}

// ---------------- fused decoder gemm: t = relu(in@W0+b0); out = dinv*(t@W1) ----------------
// in sliced 64ch; out sliced 32ch. Intermediate t lives only in LDS.

__global__ __launch_bounds__(256) void gemm2_kernel(
        const float* __restrict__ in, const float* __restrict__ W0,
        const float* __restrict__ b0, const float* __restrict__ W1,
        const float* __restrict__ dinvR, float* __restrict__ out, int N) {
    constexpr int NPB = 4;           // rows per group
    __shared__ float4 xsh[NPB * 16];
    __shared__ float t1sh[NPB * 65];
    __shared__ float w1sh[HID * IN_CH];   // 8KB
    int tid = threadIdx.x;
    int r  = tid >> 6;               // 0..3
    int co = tid & 63;
    float w0[HID];
    #pragma unroll
    for (int k = 0; k < HID; ++k) w0[k] = W0[k * HID + co];
    float b0v = b0[co];
    for (int i = tid; i < HID * IN_CH; i += 256) w1sh[i] = W1[i];
    int r2  = tid >> 5;              // 0..7 (only 0..3 used in phase B)
    int co2 = tid & 31;
    int ngroups = (N + NPB - 1) / NPB;
    for (int grp = blockIdx.x; grp < ngroups; grp += gridDim.x) {
        int base = grp * NPB;
        __syncthreads();             // prior phase B done (t1sh/xsh reusable)
        if (tid < NPB * 16) {
            int rr = tid >> 4, k4 = tid & 15;
            int n = base + rr;
            float4 v = make_float4(0.f, 0.f, 0.f, 0.f);
            if (n < N) v = ((const float4*)(in + (size_t)(k4 >> 1) * N * 8))[(size_t)n * 2 + (k4 & 1)];
            xsh[tid] = v;
        }
        __syncthreads();
        {   // phase A: t1 = relu(x @ W0 + b0)
            float acc = b0v;
            #pragma unroll
            for (int k4 = 0; k4 < 16; ++k4) {
                float4 xv = xsh[r * 16 + k4];
                acc += xv.x * w0[4 * k4] + xv.y * w0[4 * k4 + 1]
                     + xv.z * w0[4 * k4 + 2] + xv.w * w0[4 * k4 + 3];
            }
            t1sh[r * 65 + co] = fmaxf(acc, 0.f);
        }
        __syncthreads();
        if (r2 < NPB) {              // phase B: out = dinv * (t1 @ W1)
            int n = base + r2;
            if (n < N) {
                float acc = 0.f;
                #pragma unroll
                for (int k = 0; k < HID; ++k)
                    acc += t1sh[r2 * 65 + k] * w1sh[k * IN_CH + co2];
                acc *= dinvR[n];
                out[(size_t)(co2 >> 3) * N * 8 + (size_t)n * 8 + (co2 & 7)] = acc;
            }
        }
    }
}

// ---------------- pooling over sorted batch ids (row-major, original order) ----------------

__global__ __launch_bounds__(256) void pool_kernel(
        const float* __restrict__ h, const int* __restrict__ batch,
        float* __restrict__ sums, int* __restrict__ cntb, int N) {
    const int CHUNK = 512;
    int chunkStart = blockIdx.x * CHUNK;
    int c = threadIdx.x & 63;
    int r = threadIdx.x >> 6;
    int curg = -1;
    float acc = 0.f;
    int cnt = 0;
    int end = chunkStart + CHUNK;
    if (end > N) end = N;
    for (int n = chunkStart + r; n < end; n += 4) {
        int g = batch[n];
        if (g != curg) {
            if (curg >= 0) {
                atomicAdd(&sums[curg * 64 + c], acc);
                if (c == 0) atomicAdd(&cntb[curg], cnt);
            }
            curg = g; acc = 0.f; cnt = 0;
        }
        acc += h[(size_t)n * 64 + c];
        cnt++;
    }
    if (curg >= 0) {
        atomicAdd(&sums[curg * 64 + c], acc);
        if (c == 0) atomicAdd(&cntb[curg], cnt);
    }
}

// ---------------- latent ----------------

__global__ __launch_bounds__(1024) void latent_kernel(
        const float* __restrict__ sums, const int* __restrict__ cntb,
        const float* __restrict__ Wp, const float* __restrict__ bp,
        const float* __restrict__ Wd, const float* __restrict__ bd,
        float* __restrict__ z_out, float* __restrict__ dg) {
    __shared__ float zl[NGRAPH * LAT];
    int t = threadIdx.x;
    {
        int g = t / LAT, l = t % LAT;
        float cf = (float)cntb[g];
        float inv = 1.0f / fmaxf(cf, 1.0f);
        float acc = bp[l];
        #pragma unroll
        for (int k = 0; k < HID; k++) acc += sums[g * HID + k] * inv * Wp[k * LAT + l];
        zl[t] = acc;
        z_out[t] = acc;
    }
    __syncthreads();
    #pragma unroll
    for (int i = 0; i < 4; i++) {
        int idx = t + i * 1024;
        int g = idx >> 6, c = idx & 63;
        float acc = bd[c];
        #pragma unroll
        for (int l = 0; l < LAT; l++) acc += zl[g * LAT + l] * Wd[l * HID + c];
        dg[idx] = fmaxf(acc, 0.f);
    }
}

// ---------------- launch ----------------

extern "C" void kernel_launch(void* const* d_in, const int* in_sizes, int n_in,
                              void* d_out, int out_size, void* d_ws, size_t ws_size,
                              hipStream_t stream) {
    const float* x          = (const float*)d_in[0];
    const int*   ei         = (const int*)d_in[1];
    const int*   batch      = (const int*)d_in[2];
    const float* W_enc0     = (const float*)d_in[3];
    const float* b_enc0     = (const float*)d_in[4];
    const float* W_enc1     = (const float*)d_in[5];
    const float* b_enc1     = (const float*)d_in[6];
    const float* W_enc2     = (const float*)d_in[7];
    const float* b_enc2     = (const float*)d_in[8];
    const float* W_proj     = (const float*)d_in[9];
    const float* b_proj     = (const float*)d_in[10];
    const float* W_dec_proj = (const float*)d_in[11];
    const float* b_dec_proj = (const float*)d_in[12];
    const float* W_dec0     = (const float*)d_in[13];
    const float* b_dec0     = (const float*)d_in[14];
    const float* W_dec1     = (const float*)d_in[15];
    const float* b_dec1     = (const float*)d_in[16];

    const int N = in_sizes[0] / IN_CH;
    const int E = in_sizes[1] / 2;

    char* ws = (char*)d_ws;
    size_t off = 0;
    auto alloc = [&](size_t bytes) {
        void* p = ws + off;
        off += (bytes + 255) & ~(size_t)255;
        return p;
    };
    float* A       = (float*)alloc((size_t)N * HID * 4);
    float* B       = (float*)alloc((size_t)N * HID * 4);
    float* XS      = (float*)alloc((size_t)N * IN_CH * 4); // aliases staged1
    int*   col     = (int*)  alloc((size_t)E * 4);
    int*   cnt2    = (int*)  alloc((size_t)N * 4);
    int*   rowptr2 = (int*)  alloc((size_t)(N + 1) * 4);
    int*   perm    = (int*)  alloc((size_t)N * 4);
    int*   rank    = (int*)  alloc((size_t)N * 4);
    float* dinvR   = (float*)alloc((size_t)N * 4);
    float2* pgR    = (float2*)alloc((size_t)N * 8);
    int*   bbase   = (int*)  alloc(257 * 4);
    // ---- zero-initialized region (single memset) ----
    char* zbase = ws + off;
    int*   cursor  = (int*)  alloc((size_t)N * 4);
    int*   bh      = (int*)  alloc(256 * 4);
    int*   gcurD   = (int*)  alloc(256 * 4);
    float* sums    = (float*)alloc((size_t)NGRAPH * HID * 4);
    int*   cntb    = (int*)  alloc((size_t)NGRAPH * 4);
    size_t zbytes = (size_t)((ws + off) - zbase);
    float* dg      = (float*)alloc((size_t)NGRAPH * HID * 4);

    u64* staged1 = (u64*)XS;   // dead before slice_x writes XS

    float* x_recon = (float*)d_out;
    float* z_out   = (float*)d_out + (size_t)N * IN_CH;

    hipMemsetAsync(zbase, 0, zbytes, stream);

    int ebins = (E + 2047) / 2048;
    int nbk = (N + 511) >> 9;            // buckets
    int chunksI = nbk * CPB;             // quarter-interleaved chunk count

    // CSR build with bucket-local degree sort
    bhist_kernel<<<ebins, 256, 0, stream>>>(ei, bh, E);
    bin_kernel<<<ebins, 256, 0, stream>>>(ei, bh, gcurD, staged1, E);
    degb_kernel<<<256, 256, 0, stream>>>(staged1, bh, batch, rank, perm, cnt2,
                                         rowptr2, dinvR, pgR, bbase, N, E);
    csr_kernel<<<256 * KB_CSR, 256, 0, stream>>>(staged1, bbase, rank, rowptr2, cursor, col);

    {
        dim3 g((N * 2 + 255) / 256, IN_CH / 8);
        slice_x_kernel<<<g, 256, 0, stream>>>(x, perm, dinvR, XS, N);
    }

    // encoder (rank space)
    agg_kernel<IN_CH, false, false><<<chunksI * 4, 256, 0, stream>>>(
        XS, A, rowptr2, cnt2, col, dinvR, perm, nullptr, nbk, N);
    gemm_kernel<IN_CH, HID, true, true, true, false><<<2048, 256, 0, stream>>>(
        A, W_enc0, b_enc0, dinvR, perm, B, N);
    agg_kernel<HID, false, false><<<chunksI * 8, 256, 0, stream>>>(
        B, A, rowptr2, cnt2, col, dinvR, perm, nullptr, nbk, N);
    gemm_kernel<HID, HID, true, true, true, false><<<2048, 256, 0, stream>>>(
        A, W_enc1, b_enc1, dinvR, perm, B, N);
    agg_kernel<HID, false, false><<<chunksI * 8, 256, 0, stream>>>(
        B, A, rowptr2, cnt2, col, dinvR, perm, nullptr, nbk, N);
    gemm_kernel<HID, HID, true, true, false, true><<<2048, 256, 0, stream>>>(
        A, W_enc2, b_enc2, dinvR, perm, B, N);   // scatter to ORIGINAL order for pool

    // pool + latent
    pool_kernel<<<(N + 511) / 512, 256, 0, stream>>>(B, batch, sums, cntb, N);
    latent_kernel<<<1, 1024, 0, stream>>>(sums, cntb, W_proj, b_proj, W_dec_proj, b_dec_proj, z_out, dg);

    // decoder (rank space): group-agg, fused double-gemm, final agg
    gagg_kernel<<<chunksI, 256, 0, stream>>>(dg, pgR, rowptr2, cnt2, col, A, nbk, N);
    gemm2_kernel<<<2048, 256, 0, stream>>>(A, W_dec0, b_dec0, W_dec1, dinvR, B, N);
    agg_kernel<IN_CH, true, true><<<chunksI * 4, 256, 0, stream>>>(
        B, x_recon, rowptr2, cnt2, col, dinvR, perm, b_dec1, nbk, N);
}

// Round 10
// 635.761 us; speedup vs baseline: 1.8368x; 1.0046x over previous
//
#include <hip/hip_runtime.h>
#include <hip/hip_bf16.h>

typedef unsigned long long u64;

static constexpr int IN_CH  = 32;
static constexpr int HID    = 64;
static constexpr int LAT    = 16;
static constexpr int NGRAPH = 64;
static constexpr int CPB     = 4;      // chunks (128 rows) per 512-node bucket

// RANK-SPACE pipeline, bucket-local degree sort, sliced [C/8][N][8] features
// (slice L2-resident per XCD; blockIdx%NSL pins slice->XCD), quarter-interleaved
// agg schedule. All agg inputs pre-scaled by dinv.
// R10: 16-deep gather unroll in agg (Little's law: latency-bound at 8-deep),
// csr fill with LDS cursors (one block per bucket, no global atomics).

__device__ inline void add4(float4& a, const float4& b) {
    a.x += b.x; a.y += b.y; a.z += b.z; a.w += b.w;
}

// ---------------- bucket histogram of dst ----------------

__global__ __launch_bounds__(256) void bhist_kernel(const int* __restrict__ ei,
                                                    int* __restrict__ bh, int E) {
    __shared__ int lh[256];
    lh[threadIdx.x] = 0;
    __syncthreads();
    int base = blockIdx.x * 2048;
    #pragma unroll
    for (int j = 0; j < 8; j++) {
        int idx = base + j * 256 + threadIdx.x;
        if (idx < E) atomicAdd(&lh[ei[E + idx] >> 9], 1);
    }
    __syncthreads();
    if (lh[threadIdx.x]) atomicAdd(&bh[threadIdx.x], lh[threadIdx.x]);
}

// ---------------- LDS counting-sort binning by dst>>9 ----------------

__global__ __launch_bounds__(256) void bin_kernel(
        const int* __restrict__ ei, const int* __restrict__ bh,
        int* __restrict__ gcur, u64* __restrict__ sout, int E) {
    __shared__ int lhist[256], lscan[256], lcur[256], gbase[256], bbaseL[256];
    __shared__ u64 sbuf[2048];
    int tid = threadIdx.x;
    lhist[tid] = 0;
    {   // exclusive scan of bh -> bucket bases
        int v = bh[tid];
        lscan[tid] = v;
        for (int off = 1; off < 256; off <<= 1) {
            __syncthreads();
            int x = (tid >= off) ? lscan[tid - off] : 0;
            __syncthreads();
            lscan[tid] += x;
        }
        __syncthreads();
        bbaseL[tid] = lscan[tid] - v;
    }
    __syncthreads();
    int base = blockIdx.x * 2048;
    int cnt = min(2048, E - base);
    int myb[8]; u64 myp[8];
    #pragma unroll
    for (int j = 0; j < 8; j++) {
        int idx = base + j * 256 + tid;
        myb[j] = -1;
        if (idx < E) {
            int key = ei[E + idx], val = ei[idx];
            int b = key >> 9;
            myb[j] = b;
            myp[j] = ((u64)(unsigned)key << 32) | (unsigned)val;
            atomicAdd(&lhist[b], 1);
        }
    }
    __syncthreads();
    int v = lhist[tid];
    lscan[tid] = v;
    for (int off = 1; off < 256; off <<= 1) {
        __syncthreads();
        int x = (tid >= off) ? lscan[tid - off] : 0;
        __syncthreads();
        lscan[tid] += x;
    }
    __syncthreads();
    int excl = lscan[tid] - v;
    __syncthreads();
    lscan[tid] = excl;
    lcur[tid] = excl;
    __syncthreads();
    #pragma unroll
    for (int j = 0; j < 8; j++) {
        if (myb[j] >= 0) {
            int pos = atomicAdd(&lcur[myb[j]], 1);
            sbuf[pos] = myp[j];
        }
    }
    gbase[tid] = v ? atomicAdd(&gcur[tid], v) : 0;
    __syncthreads();
    for (int i = tid; i < cnt; i += 256) {
        u64 p = sbuf[i];
        int b = (int)(p >> 41);   // key>>9
        sout[bbaseL[b] + gbase[b] + (i - lscan[b])] = p;
    }
}

// ---------------- per-bucket: degree, local degree-sort, rowptr, metadata ----------------

__global__ __launch_bounds__(256) void degb_kernel(
        const u64* __restrict__ staged, const int* __restrict__ bh,
        const int* __restrict__ batch,
        int* __restrict__ rank, int* __restrict__ perm, int* __restrict__ cnt2,
        int* __restrict__ rowptr2, float* __restrict__ dinvR,
        float2* __restrict__ pgR, int* __restrict__ bbase, int N, int E) {
    __shared__ int sc[256];
    __shared__ int ldeg[512], lrank[512], degS[512], psum[512];
    __shared__ int kcur[256];
    __shared__ int s0s, s1s;
    int b = blockIdx.x, tid = threadIdx.x;
    {   // scan bh -> this bucket's edge range [s0, s1)
        int bv = bh[tid];
        sc[tid] = bv;
        for (int off = 1; off < 256; off <<= 1) {
            __syncthreads();
            int x = (tid >= off) ? sc[tid - off] : 0;
            __syncthreads();
            sc[tid] += x;
        }
        __syncthreads();
        if (tid == b) { s0s = sc[tid] - bv; s1s = sc[tid]; }
    }
    ldeg[tid] = 0; ldeg[tid + 256] = 0;
    degS[tid] = 0; degS[tid + 256] = 0;
    kcur[tid] = 0;   // used first as khist
    __syncthreads();
    int s0 = s0s, s1 = s1s;
    int base = b << 9;
    for (int i = s0 + tid; i < s1; i += 256)
        atomicAdd(&ldeg[(int)(__builtin_nontemporal_load(&staged[i]) >> 32) - base], 1);
    __syncthreads();
    int k = N - base; k = k < 0 ? 0 : (k > 512 ? 512 : k);
    #pragma unroll
    for (int j = 0; j < 2; j++) {
        int t = tid + j * 256;
        if (t < k) atomicAdd(&kcur[min(ldeg[t], 255)], 1);
    }
    __syncthreads();
    {   // exclusive scan of key-histogram -> kcur = bucket offsets
        int hv = kcur[tid];
        sc[tid] = hv;
        for (int off = 1; off < 256; off <<= 1) {
            __syncthreads();
            int x = (tid >= off) ? sc[tid - off] : 0;
            __syncthreads();
            sc[tid] += x;
        }
        __syncthreads();
        kcur[tid] = sc[tid] - hv;
    }
    __syncthreads();
    #pragma unroll
    for (int j = 0; j < 2; j++) {
        int t = tid + j * 256;
        if (t < k) lrank[t] = atomicAdd(&kcur[min(ldeg[t], 255)], 1);
    }
    __syncthreads();
    #pragma unroll
    for (int j = 0; j < 2; j++) {
        int t = tid + j * 256;
        if (t < k) degS[lrank[t]] = ldeg[t];
    }
    __syncthreads();
    {   // exclusive scan of degS[512] -> psum (edge prefix in local-rank order)
        int v0 = degS[2 * tid], v1 = degS[2 * tid + 1];
        int T = v0 + v1;
        sc[tid] = T;
        for (int off = 1; off < 256; off <<= 1) {
            __syncthreads();
            int x = (tid >= off) ? sc[tid - off] : 0;
            __syncthreads();
            sc[tid] += x;
        }
        __syncthreads();
        int ex = sc[tid] - T;
        psum[2 * tid] = ex;
        psum[2 * tid + 1] = ex + v0;
    }
    __syncthreads();
    #pragma unroll
    for (int j = 0; j < 2; j++) {
        int t = tid + j * 256;
        if (t < k) {
            int n = base + t;
            int d = ldeg[t], lr = lrank[t];
            int r = base + lr;
            rank[n] = r;
            perm[r] = n;
            cnt2[r] = d;
            rowptr2[r] = s0 + psum[lr];
            float dv = rsqrtf((float)d + 1.0f);
            dinvR[r] = dv;
            pgR[r] = make_float2(dv, __int_as_float(batch[n]));
        }
    }
    if (tid == 0) {
        bbase[b] = s0;
        if (b == 255) bbase[256] = E;
    }
}

// ---------------- bucket-local CSR fill, LDS cursors (col = rank[src]) ----------------
// One block per bucket: all edges with dst in this 512-window are in [s0,s1),
// so per-row cursors live entirely in LDS (no global atomics).

__global__ __launch_bounds__(256) void csr_kernel(
        const u64* __restrict__ staged, const int* __restrict__ bbase,
        const int* __restrict__ rank, const int* __restrict__ rowptr2,
        int* __restrict__ col) {
    __shared__ int lcur[512];
    int b = blockIdx.x, tid = threadIdx.x;
    lcur[tid] = 0; lcur[tid + 256] = 0;
    __syncthreads();
    int s0 = bbase[b], s1 = bbase[b + 1];
    int base = b << 9;
    for (int i = s0 + tid; i < s1; i += 256) {
        u64 p = __builtin_nontemporal_load(&staged[i]);
        int dst = (int)(p >> 32);
        int src = (int)(p & 0xffffffffu);
        int rd = rank[dst];                       // hot 2KB window
        int pos = rowptr2[rd] + atomicAdd(&lcur[rd - base], 1);
        col[pos] = rank[src];                     // L2-resident 400KB table
    }
}

// ---------------- x -> rank-space sliced layout, pre-scaled ----------------

__global__ void slice_x_kernel(const float* __restrict__ x, const int* __restrict__ perm,
                               const float* __restrict__ dinvR,
                               float* __restrict__ xs, int N) {
    int idx = blockIdx.x * 256 + threadIdx.x;   // over N*2
    if (idx >= N * 2) return;
    int r = idx >> 1, h = idx & 1;
    int sl = blockIdx.y;
    int n = perm[r];                            // local window gather
    float4 v = ((const float4*)x)[(size_t)n * 8 + sl * 2 + h];
    float dn = dinvR[r];
    v.x *= dn; v.y *= dn; v.z *= dn; v.w *= dn;
    ((float4*)(xs + (size_t)sl * N * 8))[idx] = v;
}

// ---------------- aggregation (rank space; quarter-interleave; 16-deep gathers) ----------------
// out[r] = dinvR[r] * (in[r] + sum_{sr in row r} in[sr])   [+bias]
// Lane pair shares a row: lane h owns half h (16B); pair's gathers of the SAME
// edge coalesce into one 32B request. 16 gathers in flight per lane.

template <int C, bool ADD_BIAS, bool OUT_ROWMAJOR>
__global__ __launch_bounds__(256) void agg_kernel(
        const float* __restrict__ in, float* __restrict__ out,
        const int* __restrict__ rowptr2, const int* __restrict__ cnt2,
        const int* __restrict__ col, const float* __restrict__ dinvR,
        const int* __restrict__ perm, const float* __restrict__ bias,
        int nbk, int N) {
    constexpr int NSL = C / 8;
    int sl = blockIdx.x % NSL;
    int o  = blockIdx.x / NSL;
    int chunk = (o % nbk) * CPB + (o / nbk);   // quarter-interleave
    int slot = threadIdx.x >> 1, h = threadIdx.x & 1;
    int r = chunk * 128 + slot;
    if (r >= N) return;
    const float4* inS = (const float4*)(in + (size_t)sl * N * 8);
    int start = rowptr2[r], m = cnt2[r];
    const int* cp = col + start;
    float4 acc0 = inS[(size_t)r * 2 + h];   // self (own half)
    float4 acc1 = make_float4(0.f, 0.f, 0.f, 0.f);
    int i = 0;
    for (; i + 16 <= m; i += 16) {
        int4 ca = *(const int4*)(cp + i);
        int4 cb = *(const int4*)(cp + i + 4);
        int4 cc = *(const int4*)(cp + i + 8);
        int4 cd = *(const int4*)(cp + i + 12);
        float4 v0 = inS[(size_t)ca.x*2+h], v1 = inS[(size_t)ca.y*2+h];
        float4 v2 = inS[(size_t)ca.z*2+h], v3 = inS[(size_t)ca.w*2+h];
        float4 v4 = inS[(size_t)cb.x*2+h], v5 = inS[(size_t)cb.y*2+h];
        float4 v6 = inS[(size_t)cb.z*2+h], v7 = inS[(size_t)cb.w*2+h];
        float4 v8 = inS[(size_t)cc.x*2+h], v9 = inS[(size_t)cc.y*2+h];
        float4 va = inS[(size_t)cc.z*2+h], vb = inS[(size_t)cc.w*2+h];
        float4 vc = inS[(size_t)cd.x*2+h], vd = inS[(size_t)cd.y*2+h];
        float4 ve = inS[(size_t)cd.z*2+h], vf = inS[(size_t)cd.w*2+h];
        add4(v0, v1); add4(v2, v3); add4(v4, v5); add4(v6, v7);
        add4(v8, v9); add4(va, vb); add4(vc, vd); add4(ve, vf);
        add4(v0, v2); add4(v4, v6); add4(v8, va); add4(vc, ve);
        add4(v0, v4); add4(v8, vc);
        add4(acc0, v0); add4(acc1, v8);
    }
    if (i + 8 <= m) {
        int4 ca = *(const int4*)(cp + i);
        int4 cb = *(const int4*)(cp + i + 4);
        float4 v0 = inS[(size_t)ca.x*2+h], v1 = inS[(size_t)ca.y*2+h];
        float4 v2 = inS[(size_t)ca.z*2+h], v3 = inS[(size_t)ca.w*2+h];
        float4 v4 = inS[(size_t)cb.x*2+h], v5 = inS[(size_t)cb.y*2+h];
        float4 v6 = inS[(size_t)cb.z*2+h], v7 = inS[(size_t)cb.w*2+h];
        add4(v0, v1); add4(v2, v3); add4(v4, v5); add4(v6, v7);
        add4(v0, v2); add4(v4, v6);
        add4(acc0, v0); add4(acc1, v4);
        i += 8;
    }
    if (i + 4 <= m) {
        int4 ca = *(const int4*)(cp + i);
        float4 v0 = inS[(size_t)ca.x*2+h], v1 = inS[(size_t)ca.y*2+h];
        float4 v2 = inS[(size_t)ca.z*2+h], v3 = inS[(size_t)ca.w*2+h];
        add4(v0, v1); add4(v2, v3); add4(v0, v2);
        add4(acc0, v0);
        i += 4;
    }
    for (; i < m; ++i) {
        int c = cp[i];
        add4(acc1, inS[(size_t)c * 2 + h]);
    }
    add4(acc0, acc1);
    float dn = dinvR[r];
    acc0.x *= dn; acc0.y *= dn; acc0.z *= dn; acc0.w *= dn;
    if (ADD_BIAS) {
        float4 b4 = ((const float4*)bias)[sl * 2 + h];
        add4(acc0, b4);
    }
    if (OUT_ROWMAJOR) ((float4*)out)[(size_t)perm[r] * (C / 4) + sl * 2 + h] = acc0;
    else ((float4*)(out + (size_t)sl * N * 8))[(size_t)r * 2 + h] = acc0;
}

// ---------------- group-agg for decoder conv0 ----------------
// Input d[r] = dinv[r]*dg[group[r]] has only 64 distinct 64ch rows -> LDS.

__global__ __launch_bounds__(256) void gagg_kernel(
        const float* __restrict__ dg, const float2* __restrict__ pgR,
        const int* __restrict__ rowptr2, const int* __restrict__ cnt2,
        const int* __restrict__ col, float* __restrict__ out, int nbk, int N) {
    __shared__ float dgL[NGRAPH * 68];   // padded stride 68 floats (17 float4)
    for (int i = threadIdx.x; i < NGRAPH * 64; i += 256)
        dgL[(i >> 6) * 68 + (i & 63)] = dg[i];
    __syncthreads();
    int slot = threadIdx.x >> 1, e = threadIdx.x & 1;   // e: channel half (32ch)
    int o = blockIdx.x;
    int chunk = (o % nbk) * CPB + (o / nbk);            // quarter-interleave
    int r = chunk * 128 + slot;
    if (r >= N) return;
    const float4* dgL4 = (const float4*)dgL;            // row stride 17
    int start = rowptr2[r], m = cnt2[r];
    const int* cp = col + start;
    float2 ps = pgR[r];
    float dn = ps.x;
    int gs = __float_as_int(ps.y);
    float4 acc[8];
    {
        const float4* rp = dgL4 + gs * 17 + e * 8;
        #pragma unroll
        for (int j = 0; j < 8; ++j) {
            float4 v = rp[j];
            acc[j] = make_float4(dn * v.x, dn * v.y, dn * v.z, dn * v.w);
        }
    }
    int i = 0;
    for (; i + 4 <= m; i += 4) {
        int4 ca = *(const int4*)(cp + i);
        float2 p0 = pgR[ca.x], p1 = pgR[ca.y], p2 = pgR[ca.z], p3 = pgR[ca.w];
        const float4* r0 = dgL4 + __float_as_int(p0.y) * 17 + e * 8;
        const float4* r1 = dgL4 + __float_as_int(p1.y) * 17 + e * 8;
        const float4* r2 = dgL4 + __float_as_int(p2.y) * 17 + e * 8;
        const float4* r3 = dgL4 + __float_as_int(p3.y) * 17 + e * 8;
        float w0 = p0.x, w1 = p1.x, w2 = p2.x, w3 = p3.x;
        #pragma unroll
        for (int j = 0; j < 8; ++j) {
            float4 v0 = r0[j], v1 = r1[j], v2 = r2[j], v3 = r3[j];
            acc[j].x += (w0 * v0.x + w1 * v1.x) + (w2 * v2.x + w3 * v3.x);
            acc[j].y += (w0 * v0.y + w1 * v1.y) + (w2 * v2.y + w3 * v3.y);
            acc[j].z += (w0 * v0.z + w1 * v1.z) + (w2 * v2.z + w3 * v3.z);
            acc[j].w += (w0 * v0.w + w1 * v1.w) + (w2 * v2.w + w3 * v3.w);
        }
    }
    for (; i < m; ++i) {
        int c0 = cp[i];
        float2 p0 = pgR[c0];
        const float4* r0 = dgL4 + __float_as_int(p0.y) * 17 + e * 8;
        float w0 = p0.x;
        #pragma unroll
        for (int j = 0; j < 8; ++j) {
            float4 v0 = r0[j];
            acc[j].x += w0 * v0.x; acc[j].y += w0 * v0.y;
            acc[j].z += w0 * v0.z; acc[j].w += w0 * v0.w;
        }
    }
    #pragma unroll
    for (int k = 0; k < 4; ++k) {
        #pragma unroll
        for (int jj = 0; jj < 2; ++jj) {
            float4 v = acc[k * 2 + jj];
            v.x *= dn; v.y *= dn; v.z *= dn; v.w *= dn;
            ((float4*)(out + (size_t)(4 * e + k) * N * 8))[(size_t)r * 2 + jj] = v;
        }
    }
}

// ---------------- dense transform: W column in registers, x broadcast from LDS ----------------

template <int CIN, int COUT, bool RELU, bool BIAS, bool SCALE, bool OUT_ROWMAJOR>
__global__ __launch_bounds__(256) void gemm_kernel(
        const float* __restrict__ in, const float* __restrict__ W,
        const float* __restrict__ b, const float* __restrict__ dinvR,
        const int* __restrict__ perm, float* __restrict__ out, int N) {
    constexpr int NPB = 256 / COUT;
    constexpr int K4 = CIN / 4;
    __shared__ float4 xsh[NPB * K4];
    int r  = threadIdx.x / COUT;
    int co = threadIdx.x % COUT;
    float w[CIN];
    #pragma unroll
    for (int k = 0; k < CIN; ++k) w[k] = W[k * COUT + co];
    float bsv = BIAS ? b[co] : 0.f;
    int ngroups = (N + NPB - 1) / NPB;
    for (int grp = blockIdx.x; grp < ngroups; grp += gridDim.x) {
        int base = grp * NPB;
        __syncthreads();
        for (int i = threadIdx.x; i < NPB * K4; i += 256) {
            int rr = i / K4, k4 = i % K4;
            int n = base + rr;
            float4 v = make_float4(0.f, 0.f, 0.f, 0.f);
            if (n < N) v = ((const float4*)(in + (size_t)(k4 >> 1) * N * 8))[(size_t)n * 2 + (k4 & 1)];
            xsh[i] = v;
        }
        __syncthreads();
        int n = base + r;
        if (n < N) {
            float acc = bsv;
            #pragma unroll
            for (int k4 = 0; k4 < K4; ++k4) {
                float4 xv = xsh[r * K4 + k4];   // wave-uniform -> LDS broadcast
                acc += xv.x * w[4 * k4] + xv.y * w[4 * k4 + 1]
                     + xv.z * w[4 * k4 + 2] + xv.w * w[4 * k4 + 3];
            }
            if (RELU) acc = fmaxf(acc, 0.f);
            if (SCALE) acc *= dinvR[n];
            if (OUT_ROWMAJOR) out[(size_t)perm[n] * COUT + co] = acc;
            else out[(size_t)(co >> 3) * N * 8 + (size_t)n * 8 + (co & 7)] = acc;
        }
    }
}

// ---------------- fused decoder gemm: t = relu(in@W0+b0); out = dinv*(t@W1) ----------------

__global__ __launch_bounds__(256) void gemm2_kernel(
        const float* __restrict__ in, const float* __restrict__ W0,
        const float* __restrict__ b0, const float* __restrict__ W1,
        const float* __restrict__ dinvR, float* __restrict__ out, int N) {
    constexpr int NPB = 4;           // rows per group
    __shared__ float4 xsh[NPB * 16];
    __shared__ float t1sh[NPB * 65];
    __shared__ float w1sh[HID * IN_CH];   // 8KB
    int tid = threadIdx.x;
    int r  = tid >> 6;               // 0..3
    int co = tid & 63;
    float w0[HID];
    #pragma unroll
    for (int k = 0; k < HID; ++k) w0[k] = W0[k * HID + co];
    float b0v = b0[co];
    for (int i = tid; i < HID * IN_CH; i += 256) w1sh[i] = W1[i];
    int r2  = tid >> 5;              // 0..7 (only 0..3 used in phase B)
    int co2 = tid & 31;
    int ngroups = (N + NPB - 1) / NPB;
    for (int grp = blockIdx.x; grp < ngroups; grp += gridDim.x) {
        int base = grp * NPB;
        __syncthreads();             // prior phase B done (t1sh/xsh reusable)
        if (tid < NPB * 16) {
            int rr = tid >> 4, k4 = tid & 15;
            int n = base + rr;
            float4 v = make_float4(0.f, 0.f, 0.f, 0.f);
            if (n < N) v = ((const float4*)(in + (size_t)(k4 >> 1) * N * 8))[(size_t)n * 2 + (k4 & 1)];
            xsh[tid] = v;
        }
        __syncthreads();
        {   // phase A: t1 = relu(x @ W0 + b0)
            float acc = b0v;
            #pragma unroll
            for (int k4 = 0; k4 < 16; ++k4) {
                float4 xv = xsh[r * 16 + k4];
                acc += xv.x * w0[4 * k4] + xv.y * w0[4 * k4 + 1]
                     + xv.z * w0[4 * k4 + 2] + xv.w * w0[4 * k4 + 3];
            }
            t1sh[r * 65 + co] = fmaxf(acc, 0.f);
        }
        __syncthreads();
        if (r2 < NPB) {              // phase B: out = dinv * (t1 @ W1)
            int n = base + r2;
            if (n < N) {
                float acc = 0.f;
                #pragma unroll
                for (int k = 0; k < HID; ++k)
                    acc += t1sh[r2 * 65 + k] * w1sh[k * IN_CH + co2];
                acc *= dinvR[n];
                out[(size_t)(co2 >> 3) * N * 8 + (size_t)n * 8 + (co2 & 7)] = acc;
            }
        }
    }
}

// ---------------- pooling over sorted batch ids (row-major, original order) ----------------

__global__ __launch_bounds__(256) void pool_kernel(
        const float* __restrict__ h, const int* __restrict__ batch,
        float* __restrict__ sums, int* __restrict__ cntb, int N) {
    const int CHUNK = 512;
    int chunkStart = blockIdx.x * CHUNK;
    int c = threadIdx.x & 63;
    int r = threadIdx.x >> 6;
    int curg = -1;
    float acc = 0.f;
    int cnt = 0;
    int end = chunkStart + CHUNK;
    if (end > N) end = N;
    for (int n = chunkStart + r; n < end; n += 4) {
        int g = batch[n];
        if (g != curg) {
            if (curg >= 0) {
                atomicAdd(&sums[curg * 64 + c], acc);
                if (c == 0) atomicAdd(&cntb[curg], cnt);
            }
            curg = g; acc = 0.f; cnt = 0;
        }
        acc += h[(size_t)n * 64 + c];
        cnt++;
    }
    if (curg >= 0) {
        atomicAdd(&sums[curg * 64 + c], acc);
        if (c == 0) atomicAdd(&cntb[curg], cnt);
    }
}

// ---------------- latent ----------------

__global__ __launch_bounds__(1024) void latent_kernel(
        const float* __restrict__ sums, const int* __restrict__ cntb,
        const float* __restrict__ Wp, const float* __restrict__ bp,
        const float* __restrict__ Wd, const float* __restrict__ bd,
        float* __restrict__ z_out, float* __restrict__ dg) {
    __shared__ float zl[NGRAPH * LAT];
    int t = threadIdx.x;
    {
        int g = t / LAT, l = t % LAT;
        float cf = (float)cntb[g];
        float inv = 1.0f / fmaxf(cf, 1.0f);
        float acc = bp[l];
        #pragma unroll
        for (int k = 0; k < HID; k++) acc += sums[g * HID + k] * inv * Wp[k * LAT + l];
        zl[t] = acc;
        z_out[t] = acc;
    }
    __syncthreads();
    #pragma unroll
    for (int i = 0; i < 4; i++) {
        int idx = t + i * 1024;
        int g = idx >> 6, c = idx & 63;
        float acc = bd[c];
        #pragma unroll
        for (int l = 0; l < LAT; l++) acc += zl[g * LAT + l] * Wd[l * HID + c];
        dg[idx] = fmaxf(acc, 0.f);
    }
}

// ---------------- launch ----------------

extern "C" void kernel_launch(void* const* d_in, const int* in_sizes, int n_in,
                              void* d_out, int out_size, void* d_ws, size_t ws_size,
                              hipStream_t stream) {
    const float* x          = (const float*)d_in[0];
    const int*   ei         = (const int*)d_in[1];
    const int*   batch      = (const int*)d_in[2];
    const float* W_enc0     = (const float*)d_in[3];
    const float* b_enc0     = (const float*)d_in[4];
    const float* W_enc1     = (const float*)d_in[5];
    const float* b_enc1     = (const float*)d_in[6];
    const float* W_enc2     = (const float*)d_in[7];
    const float* b_enc2     = (const float*)d_in[8];
    const float* W_proj     = (const float*)d_in[9];
    const float* b_proj     = (const float*)d_in[10];
    const float* W_dec_proj = (const float*)d_in[11];
    const float* b_dec_proj = (const float*)d_in[12];
    const float* W_dec0     = (const float*)d_in[13];
    const float* b_dec0     = (const float*)d_in[14];
    const float* W_dec1     = (const float*)d_in[15];
    const float* b_dec1     = (const float*)d_in[16];

    const int N = in_sizes[0] / IN_CH;
    const int E = in_sizes[1] / 2;

    char* ws = (char*)d_ws;
    size_t off = 0;
    auto alloc = [&](size_t bytes) {
        void* p = ws + off;
        off += (bytes + 255) & ~(size_t)255;
        return p;
    };
    float* A       = (float*)alloc((size_t)N * HID * 4);
    float* B       = (float*)alloc((size_t)N * HID * 4);
    float* XS      = (float*)alloc((size_t)N * IN_CH * 4); // aliases staged1
    int*   col     = (int*)  alloc((size_t)E * 4);
    int*   cnt2    = (int*)  alloc((size_t)N * 4);
    int*   rowptr2 = (int*)  alloc((size_t)(N + 1) * 4);
    int*   perm    = (int*)  alloc((size_t)N * 4);
    int*   rank    = (int*)  alloc((size_t)N * 4);
    float* dinvR   = (float*)alloc((size_t)N * 4);
    float2* pgR    = (float2*)alloc((size_t)N * 8);
    int*   bbase   = (int*)  alloc(257 * 4);
    // ---- zero-initialized region (single memset) ----
    char* zbase = ws + off;
    int*   bh      = (int*)  alloc(256 * 4);
    int*   gcurD   = (int*)  alloc(256 * 4);
    float* sums    = (float*)alloc((size_t)NGRAPH * HID * 4);
    int*   cntb    = (int*)  alloc((size_t)NGRAPH * 4);
    size_t zbytes = (size_t)((ws + off) - zbase);
    float* dg      = (float*)alloc((size_t)NGRAPH * HID * 4);

    u64* staged1 = (u64*)XS;   // dead before slice_x writes XS

    float* x_recon = (float*)d_out;
    float* z_out   = (float*)d_out + (size_t)N * IN_CH;

    hipMemsetAsync(zbase, 0, zbytes, stream);

    int ebins = (E + 2047) / 2048;
    int nbk = (N + 511) >> 9;            // buckets
    int chunksI = nbk * CPB;             // quarter-interleaved chunk count

    // CSR build with bucket-local degree sort
    bhist_kernel<<<ebins, 256, 0, stream>>>(ei, bh, E);
    bin_kernel<<<ebins, 256, 0, stream>>>(ei, bh, gcurD, staged1, E);
    degb_kernel<<<256, 256, 0, stream>>>(staged1, bh, batch, rank, perm, cnt2,
                                         rowptr2, dinvR, pgR, bbase, N, E);
    csr_kernel<<<256, 256, 0, stream>>>(staged1, bbase, rank, rowptr2, col);

    {
        dim3 g((N * 2 + 255) / 256, IN_CH / 8);
        slice_x_kernel<<<g, 256, 0, stream>>>(x, perm, dinvR, XS, N);
    }

    // encoder (rank space)
    agg_kernel<IN_CH, false, false><<<chunksI * 4, 256, 0, stream>>>(
        XS, A, rowptr2, cnt2, col, dinvR, perm, nullptr, nbk, N);
    gemm_kernel<IN_CH, HID, true, true, true, false><<<2048, 256, 0, stream>>>(
        A, W_enc0, b_enc0, dinvR, perm, B, N);
    agg_kernel<HID, false, false><<<chunksI * 8, 256, 0, stream>>>(
        B, A, rowptr2, cnt2, col, dinvR, perm, nullptr, nbk, N);
    gemm_kernel<HID, HID, true, true, true, false><<<2048, 256, 0, stream>>>(
        A, W_enc1, b_enc1, dinvR, perm, B, N);
    agg_kernel<HID, false, false><<<chunksI * 8, 256, 0, stream>>>(
        B, A, rowptr2, cnt2, col, dinvR, perm, nullptr, nbk, N);
    gemm_kernel<HID, HID, true, true, false, true><<<2048, 256, 0, stream>>>(
        A, W_enc2, b_enc2, dinvR, perm, B, N);   // scatter to ORIGINAL order for pool

    // pool + latent
    pool_kernel<<<(N + 511) / 512, 256, 0, stream>>>(B, batch, sums, cntb, N);
    latent_kernel<<<1, 1024, 0, stream>>>(sums, cntb, W_proj, b_proj, W_dec_proj, b_dec_proj, z_out, dg);

    // decoder (rank space): group-agg, fused double-gemm, final agg
    gagg_kernel<<<chunksI, 256, 0, stream>>>(dg, pgR, rowptr2, cnt2, col, A, nbk, N);
    gemm2_kernel<<<2048, 256, 0, stream>>>(A, W_dec0, b_dec0, W_dec1, dinvR, B, N);
    agg_kernel<IN_CH, true, true><<<chunksI * 4, 256, 0, stream>>>(
        B, x_recon, rowptr2, cnt2, col, dinvR, perm, b_dec1, nbk, N);
}

// Round 11
// 603.293 us; speedup vs baseline: 1.9356x; 1.0538x over previous
//
#include <hip/hip_runtime.h>
#include <hip/hip_bf16.h>

typedef unsigned long long u64;

static constexpr int IN_CH  = 32;
static constexpr int HID    = 64;
static constexpr int LAT    = 16;
static constexpr int NGRAPH = 64;
static constexpr int CPB8   = 8;   // 64-row chunks per 512-node bucket (agg)
static constexpr int CPB4   = 4;   // 128-row chunks per bucket (gagg)

// RANK-SPACE pipeline, bucket-local degree sort. R11: 16-CHANNEL slices
// ([C/16][N][16] floats, 64B/node/slice). A 4-lane QUAD owns a row; the quad's
// 4x16B gathers of one edge cover exactly ONE 64B line -> half the random
// requests of the 8ch/pair scheme (R6/R10 evidence: request-count-bound).
// Slice = 6.4MB (partial L2 residency per XCD, L3 backs the rest).
// All agg inputs pre-scaled by dinv. Eighth-interleaved chunk schedule keeps
// dispatch rounds degree-uniform.

__device__ inline void add4(float4& a, const float4& b) {
    a.x += b.x; a.y += b.y; a.z += b.z; a.w += b.w;
}

// ---------------- bucket histogram of dst ----------------

__global__ __launch_bounds__(256) void bhist_kernel(const int* __restrict__ ei,
                                                    int* __restrict__ bh, int E) {
    __shared__ int lh[256];
    lh[threadIdx.x] = 0;
    __syncthreads();
    int base = blockIdx.x * 2048;
    #pragma unroll
    for (int j = 0; j < 8; j++) {
        int idx = base + j * 256 + threadIdx.x;
        if (idx < E) atomicAdd(&lh[ei[E + idx] >> 9], 1);
    }
    __syncthreads();
    if (lh[threadIdx.x]) atomicAdd(&bh[threadIdx.x], lh[threadIdx.x]);
}

// ---------------- LDS counting-sort binning by dst>>9 ----------------

__global__ __launch_bounds__(256) void bin_kernel(
        const int* __restrict__ ei, const int* __restrict__ bh,
        int* __restrict__ gcur, u64* __restrict__ sout, int E) {
    __shared__ int lhist[256], lscan[256], lcur[256], gbase[256], bbaseL[256];
    __shared__ u64 sbuf[2048];
    int tid = threadIdx.x;
    lhist[tid] = 0;
    {   // exclusive scan of bh -> bucket bases
        int v = bh[tid];
        lscan[tid] = v;
        for (int off = 1; off < 256; off <<= 1) {
            __syncthreads();
            int x = (tid >= off) ? lscan[tid - off] : 0;
            __syncthreads();
            lscan[tid] += x;
        }
        __syncthreads();
        bbaseL[tid] = lscan[tid] - v;
    }
    __syncthreads();
    int base = blockIdx.x * 2048;
    int cnt = min(2048, E - base);
    int myb[8]; u64 myp[8];
    #pragma unroll
    for (int j = 0; j < 8; j++) {
        int idx = base + j * 256 + tid;
        myb[j] = -1;
        if (idx < E) {
            int key = ei[E + idx], val = ei[idx];
            int b = key >> 9;
            myb[j] = b;
            myp[j] = ((u64)(unsigned)key << 32) | (unsigned)val;
            atomicAdd(&lhist[b], 1);
        }
    }
    __syncthreads();
    int v = lhist[tid];
    lscan[tid] = v;
    for (int off = 1; off < 256; off <<= 1) {
        __syncthreads();
        int x = (tid >= off) ? lscan[tid - off] : 0;
        __syncthreads();
        lscan[tid] += x;
    }
    __syncthreads();
    int excl = lscan[tid] - v;
    __syncthreads();
    lscan[tid] = excl;
    lcur[tid] = excl;
    __syncthreads();
    #pragma unroll
    for (int j = 0; j < 8; j++) {
        if (myb[j] >= 0) {
            int pos = atomicAdd(&lcur[myb[j]], 1);
            sbuf[pos] = myp[j];
        }
    }
    gbase[tid] = v ? atomicAdd(&gcur[tid], v) : 0;
    __syncthreads();
    for (int i = tid; i < cnt; i += 256) {
        u64 p = sbuf[i];
        int b = (int)(p >> 41);   // key>>9
        sout[bbaseL[b] + gbase[b] + (i - lscan[b])] = p;
    }
}

// ---------------- per-bucket: degree, local degree-sort, rowptr, metadata ----------------

__global__ __launch_bounds__(256) void degb_kernel(
        const u64* __restrict__ staged, const int* __restrict__ bh,
        const int* __restrict__ batch,
        int* __restrict__ rank, int* __restrict__ perm, int* __restrict__ cnt2,
        int* __restrict__ rowptr2, float* __restrict__ dinvR,
        float2* __restrict__ pgR, int* __restrict__ bbase, int N, int E) {
    __shared__ int sc[256];
    __shared__ int ldeg[512], lrank[512], degS[512], psum[512];
    __shared__ int kcur[256];
    __shared__ int s0s, s1s;
    int b = blockIdx.x, tid = threadIdx.x;
    {   // scan bh -> this bucket's edge range [s0, s1)
        int bv = bh[tid];
        sc[tid] = bv;
        for (int off = 1; off < 256; off <<= 1) {
            __syncthreads();
            int x = (tid >= off) ? sc[tid - off] : 0;
            __syncthreads();
            sc[tid] += x;
        }
        __syncthreads();
        if (tid == b) { s0s = sc[tid] - bv; s1s = sc[tid]; }
    }
    ldeg[tid] = 0; ldeg[tid + 256] = 0;
    degS[tid] = 0; degS[tid + 256] = 0;
    kcur[tid] = 0;   // used first as khist
    __syncthreads();
    int s0 = s0s, s1 = s1s;
    int base = b << 9;
    for (int i = s0 + tid; i < s1; i += 256)
        atomicAdd(&ldeg[(int)(__builtin_nontemporal_load(&staged[i]) >> 32) - base], 1);
    __syncthreads();
    int k = N - base; k = k < 0 ? 0 : (k > 512 ? 512 : k);
    #pragma unroll
    for (int j = 0; j < 2; j++) {
        int t = tid + j * 256;
        if (t < k) atomicAdd(&kcur[min(ldeg[t], 255)], 1);
    }
    __syncthreads();
    {   // exclusive scan of key-histogram -> kcur = bucket offsets
        int hv = kcur[tid];
        sc[tid] = hv;
        for (int off = 1; off < 256; off <<= 1) {
            __syncthreads();
            int x = (tid >= off) ? sc[tid - off] : 0;
            __syncthreads();
            sc[tid] += x;
        }
        __syncthreads();
        kcur[tid] = sc[tid] - hv;
    }
    __syncthreads();
    #pragma unroll
    for (int j = 0; j < 2; j++) {
        int t = tid + j * 256;
        if (t < k) lrank[t] = atomicAdd(&kcur[min(ldeg[t], 255)], 1);
    }
    __syncthreads();
    #pragma unroll
    for (int j = 0; j < 2; j++) {
        int t = tid + j * 256;
        if (t < k) degS[lrank[t]] = ldeg[t];
    }
    __syncthreads();
    {   // exclusive scan of degS[512] -> psum (edge prefix in local-rank order)
        int v0 = degS[2 * tid], v1 = degS[2 * tid + 1];
        int T = v0 + v1;
        sc[tid] = T;
        for (int off = 1; off < 256; off <<= 1) {
            __syncthreads();
            int x = (tid >= off) ? sc[tid - off] : 0;
            __syncthreads();
            sc[tid] += x;
        }
        __syncthreads();
        int ex = sc[tid] - T;
        psum[2 * tid] = ex;
        psum[2 * tid + 1] = ex + v0;
    }
    __syncthreads();
    #pragma unroll
    for (int j = 0; j < 2; j++) {
        int t = tid + j * 256;
        if (t < k) {
            int n = base + t;
            int d = ldeg[t], lr = lrank[t];
            int r = base + lr;
            rank[n] = r;
            perm[r] = n;
            cnt2[r] = d;
            rowptr2[r] = s0 + psum[lr];
            float dv = rsqrtf((float)d + 1.0f);
            dinvR[r] = dv;
            pgR[r] = make_float2(dv, __int_as_float(batch[n]));
        }
    }
    if (tid == 0) {
        bbase[b] = s0;
        if (b == 255) bbase[256] = E;
    }
}

// ---------------- bucket-local CSR fill, LDS cursors (col = rank[src]) ----------------

__global__ __launch_bounds__(256) void csr_kernel(
        const u64* __restrict__ staged, const int* __restrict__ bbase,
        const int* __restrict__ rank, const int* __restrict__ rowptr2,
        int* __restrict__ col) {
    __shared__ int lcur[512];
    int b = blockIdx.x, tid = threadIdx.x;
    lcur[tid] = 0; lcur[tid + 256] = 0;
    __syncthreads();
    int s0 = bbase[b], s1 = bbase[b + 1];
    int base = b << 9;
    for (int i = s0 + tid; i < s1; i += 256) {
        u64 p = __builtin_nontemporal_load(&staged[i]);
        int dst = (int)(p >> 32);
        int src = (int)(p & 0xffffffffu);
        int rd = rank[dst];                       // hot 2KB window
        int pos = rowptr2[rd] + atomicAdd(&lcur[rd - base], 1);
        col[pos] = rank[src];                     // L2-resident 400KB table
    }
}

// ---------------- x -> rank-space 16ch-sliced layout, pre-scaled ----------------

__global__ void slice_x_kernel(const float* __restrict__ x, const int* __restrict__ perm,
                               const float* __restrict__ dinvR,
                               float* __restrict__ xs, int N) {
    int idx = blockIdx.x * 256 + threadIdx.x;   // over N*4
    if (idx >= N * 4) return;
    int r = idx >> 2, h = idx & 3;
    int sl = blockIdx.y;                        // 0..IN_CH/16-1
    int n = perm[r];                            // local window gather
    float4 v = ((const float4*)x)[(size_t)n * 8 + sl * 4 + h];
    float dn = dinvR[r];
    v.x *= dn; v.y *= dn; v.z *= dn; v.w *= dn;
    ((float4*)(xs + (size_t)sl * N * 16))[idx] = v;
}

// ---------------- aggregation (16ch slices, 4-lane quad, one 64B line/edge) ----------------
// out[r] = dinvR[r] * (in[r] + sum_{sr in row r} in[sr])   [+bias]

template <int C, bool ADD_BIAS, bool OUT_ROWMAJOR>
__global__ __launch_bounds__(256) void agg_kernel(
        const float* __restrict__ in, float* __restrict__ out,
        const int* __restrict__ rowptr2, const int* __restrict__ cnt2,
        const int* __restrict__ col, const float* __restrict__ dinvR,
        const int* __restrict__ perm, const float* __restrict__ bias,
        int nbk, int N) {
    constexpr int NSL = C / 16;
    int sl = blockIdx.x % NSL;
    int o  = blockIdx.x / NSL;
    int chunk = (o % nbk) * CPB8 + (o / nbk);   // eighth-interleave
    int quad = threadIdx.x >> 2, q = threadIdx.x & 3;
    int r = chunk * 64 + quad;
    if (r >= N) return;
    const float4* inS = (const float4*)(in + (size_t)sl * N * 16);
    int start = rowptr2[r], m = cnt2[r];
    const int* cp = col + start;
    float4 acc0 = inS[(size_t)r * 4 + q];   // self (own quarter-line)
    float4 acc1 = make_float4(0.f, 0.f, 0.f, 0.f);
    int i = 0;
    for (; i + 8 <= m; i += 8) {
        int4 ca = *(const int4*)(cp + i);       // quad-uniform: broadcast
        int4 cb = *(const int4*)(cp + i + 4);
        float4 v0 = inS[(size_t)ca.x*4+q], v1 = inS[(size_t)ca.y*4+q];
        float4 v2 = inS[(size_t)ca.z*4+q], v3 = inS[(size_t)ca.w*4+q];
        float4 v4 = inS[(size_t)cb.x*4+q], v5 = inS[(size_t)cb.y*4+q];
        float4 v6 = inS[(size_t)cb.z*4+q], v7 = inS[(size_t)cb.w*4+q];
        add4(v0, v1); add4(v2, v3); add4(v4, v5); add4(v6, v7);
        add4(v0, v2); add4(v4, v6);
        add4(acc0, v0); add4(acc1, v4);
    }
    if (i + 4 <= m) {
        int4 ca = *(const int4*)(cp + i);
        float4 v0 = inS[(size_t)ca.x*4+q], v1 = inS[(size_t)ca.y*4+q];
        float4 v2 = inS[(size_t)ca.z*4+q], v3 = inS[(size_t)ca.w*4+q];
        add4(v0, v1); add4(v2, v3); add4(v0, v2);
        add4(acc0, v0);
        i += 4;
    }
    for (; i < m; ++i) {
        int c = cp[i];
        add4(acc1, inS[(size_t)c * 4 + q]);
    }
    add4(acc0, acc1);
    float dn = dinvR[r];
    acc0.x *= dn; acc0.y *= dn; acc0.z *= dn; acc0.w *= dn;
    if (ADD_BIAS) {
        float4 b4 = ((const float4*)bias)[sl * 4 + q];
        add4(acc0, b4);
    }
    if (OUT_ROWMAJOR) ((float4*)out)[(size_t)perm[r] * (C / 4) + sl * 4 + q] = acc0;
    else ((float4*)(out + (size_t)sl * N * 16))[(size_t)r * 4 + q] = acc0;
}

// ---------------- group-agg for decoder conv0 (output 16ch-sliced) ----------------

__global__ __launch_bounds__(256) void gagg_kernel(
        const float* __restrict__ dg, const float2* __restrict__ pgR,
        const int* __restrict__ rowptr2, const int* __restrict__ cnt2,
        const int* __restrict__ col, float* __restrict__ out, int nbk, int N) {
    __shared__ float dgL[NGRAPH * 68];   // padded stride 68 floats (17 float4)
    for (int i = threadIdx.x; i < NGRAPH * 64; i += 256)
        dgL[(i >> 6) * 68 + (i & 63)] = dg[i];
    __syncthreads();
    int slot = threadIdx.x >> 1, e = threadIdx.x & 1;   // e: channel half (32ch)
    int o = blockIdx.x;
    int chunk = (o % nbk) * CPB4 + (o / nbk);           // quarter-interleave
    int r = chunk * 128 + slot;
    if (r >= N) return;
    const float4* dgL4 = (const float4*)dgL;            // row stride 17
    int start = rowptr2[r], m = cnt2[r];
    const int* cp = col + start;
    float2 ps = pgR[r];
    float dn = ps.x;
    int gs = __float_as_int(ps.y);
    float4 acc[8];
    {
        const float4* rp = dgL4 + gs * 17 + e * 8;
        #pragma unroll
        for (int j = 0; j < 8; ++j) {
            float4 v = rp[j];
            acc[j] = make_float4(dn * v.x, dn * v.y, dn * v.z, dn * v.w);
        }
    }
    int i = 0;
    for (; i + 4 <= m; i += 4) {
        int4 ca = *(const int4*)(cp + i);
        float2 p0 = pgR[ca.x], p1 = pgR[ca.y], p2 = pgR[ca.z], p3 = pgR[ca.w];
        const float4* r0 = dgL4 + __float_as_int(p0.y) * 17 + e * 8;
        const float4* r1 = dgL4 + __float_as_int(p1.y) * 17 + e * 8;
        const float4* r2 = dgL4 + __float_as_int(p2.y) * 17 + e * 8;
        const float4* r3 = dgL4 + __float_as_int(p3.y) * 17 + e * 8;
        float w0 = p0.x, w1 = p1.x, w2 = p2.x, w3 = p3.x;
        #pragma unroll
        for (int j = 0; j < 8; ++j) {
            float4 v0 = r0[j], v1 = r1[j], v2 = r2[j], v3 = r3[j];
            acc[j].x += (w0 * v0.x + w1 * v1.x) + (w2 * v2.x + w3 * v3.x);
            acc[j].y += (w0 * v0.y + w1 * v1.y) + (w2 * v2.y + w3 * v3.y);
            acc[j].z += (w0 * v0.z + w1 * v1.z) + (w2 * v2.z + w3 * v3.z);
            acc[j].w += (w0 * v0.w + w1 * v1.w) + (w2 * v2.w + w3 * v3.w);
        }
    }
    for (; i < m; ++i) {
        int c0 = cp[i];
        float2 p0 = pgR[c0];
        const float4* r0 = dgL4 + __float_as_int(p0.y) * 17 + e * 8;
        float w0 = p0.x;
        #pragma unroll
        for (int j = 0; j < 8; ++j) {
            float4 v0 = r0[j];
            acc[j].x += w0 * v0.x; acc[j].y += w0 * v0.y;
            acc[j].z += w0 * v0.z; acc[j].w += w0 * v0.w;
        }
    }
    #pragma unroll
    for (int k = 0; k < 4; ++k) {
        #pragma unroll
        for (int jj = 0; jj < 2; ++jj) {
            float4 v = acc[k * 2 + jj];
            v.x *= dn; v.y *= dn; v.z *= dn; v.w *= dn;
            int ch = e * 32 + k * 8 + jj * 4;
            ((float4*)(out + (size_t)(ch >> 4) * N * 16))[(size_t)r * 4 + ((ch & 15) >> 2)] = v;
        }
    }
}

// ---------------- dense transform: W column in registers, x broadcast from LDS ----------------

template <int CIN, int COUT, bool RELU, bool BIAS, bool SCALE, bool OUT_ROWMAJOR>
__global__ __launch_bounds__(256) void gemm_kernel(
        const float* __restrict__ in, const float* __restrict__ W,
        const float* __restrict__ b, const float* __restrict__ dinvR,
        const int* __restrict__ perm, float* __restrict__ out, int N) {
    constexpr int NPB = 256 / COUT;
    constexpr int K4 = CIN / 4;
    __shared__ float4 xsh[NPB * K4];
    int r  = threadIdx.x / COUT;
    int co = threadIdx.x % COUT;
    float w[CIN];
    #pragma unroll
    for (int k = 0; k < CIN; ++k) w[k] = W[k * COUT + co];
    float bsv = BIAS ? b[co] : 0.f;
    int ngroups = (N + NPB - 1) / NPB;
    for (int grp = blockIdx.x; grp < ngroups; grp += gridDim.x) {
        int base = grp * NPB;
        __syncthreads();
        for (int i = threadIdx.x; i < NPB * K4; i += 256) {
            int rr = i / K4, k4 = i % K4;
            int n = base + rr;
            float4 v = make_float4(0.f, 0.f, 0.f, 0.f);
            if (n < N) v = ((const float4*)(in + (size_t)(k4 >> 2) * N * 16))[(size_t)n * 4 + (k4 & 3)];
            xsh[i] = v;
        }
        __syncthreads();
        int n = base + r;
        if (n < N) {
            float acc = bsv;
            #pragma unroll
            for (int k4 = 0; k4 < K4; ++k4) {
                float4 xv = xsh[r * K4 + k4];   // wave-uniform -> LDS broadcast
                acc += xv.x * w[4 * k4] + xv.y * w[4 * k4 + 1]
                     + xv.z * w[4 * k4 + 2] + xv.w * w[4 * k4 + 3];
            }
            if (RELU) acc = fmaxf(acc, 0.f);
            if (SCALE) acc *= dinvR[n];
            if (OUT_ROWMAJOR) out[(size_t)perm[n] * COUT + co] = acc;
            else out[(size_t)(co >> 4) * N * 16 + (size_t)n * 16 + (co & 15)] = acc;
        }
    }
}

// ---------------- fused decoder gemm: t = relu(in@W0+b0); out = dinv*(t@W1) ----------------

__global__ __launch_bounds__(256) void gemm2_kernel(
        const float* __restrict__ in, const float* __restrict__ W0,
        const float* __restrict__ b0, const float* __restrict__ W1,
        const float* __restrict__ dinvR, float* __restrict__ out, int N) {
    constexpr int NPB = 4;           // rows per group
    __shared__ float4 xsh[NPB * 16];
    __shared__ float t1sh[NPB * 65];
    __shared__ float w1sh[HID * IN_CH];   // 8KB
    int tid = threadIdx.x;
    int r  = tid >> 6;               // 0..3
    int co = tid & 63;
    float w0[HID];
    #pragma unroll
    for (int k = 0; k < HID; ++k) w0[k] = W0[k * HID + co];
    float b0v = b0[co];
    for (int i = tid; i < HID * IN_CH; i += 256) w1sh[i] = W1[i];
    int r2  = tid >> 5;              // 0..7 (only 0..3 used in phase B)
    int co2 = tid & 31;
    int ngroups = (N + NPB - 1) / NPB;
    for (int grp = blockIdx.x; grp < ngroups; grp += gridDim.x) {
        int base = grp * NPB;
        __syncthreads();             // prior phase B done (t1sh/xsh reusable)
        if (tid < NPB * 16) {
            int rr = tid >> 4, k4 = tid & 15;
            int n = base + rr;
            float4 v = make_float4(0.f, 0.f, 0.f, 0.f);
            if (n < N) v = ((const float4*)(in + (size_t)(k4 >> 2) * N * 16))[(size_t)n * 4 + (k4 & 3)];
            xsh[tid] = v;
        }
        __syncthreads();
        {   // phase A: t1 = relu(x @ W0 + b0)
            float acc = b0v;
            #pragma unroll
            for (int k4 = 0; k4 < 16; ++k4) {
                float4 xv = xsh[r * 16 + k4];
                acc += xv.x * w0[4 * k4] + xv.y * w0[4 * k4 + 1]
                     + xv.z * w0[4 * k4 + 2] + xv.w * w0[4 * k4 + 3];
            }
            t1sh[r * 65 + co] = fmaxf(acc, 0.f);
        }
        __syncthreads();
        if (r2 < NPB) {              // phase B: out = dinv * (t1 @ W1)
            int n = base + r2;
            if (n < N) {
                float acc = 0.f;
                #pragma unroll
                for (int k = 0; k < HID; ++k)
                    acc += t1sh[r2 * 65 + k] * w1sh[k * IN_CH + co2];
                acc *= dinvR[n];
                out[(size_t)(co2 >> 4) * N * 16 + (size_t)n * 16 + (co2 & 15)] = acc;
            }
        }
    }
}

// ---------------- pooling over sorted batch ids (row-major, original order) ----------------

__global__ __launch_bounds__(256) void pool_kernel(
        const float* __restrict__ h, const int* __restrict__ batch,
        float* __restrict__ sums, int* __restrict__ cntb, int N) {
    const int CHUNK = 512;
    int chunkStart = blockIdx.x * CHUNK;
    int c = threadIdx.x & 63;
    int r = threadIdx.x >> 6;
    int curg = -1;
    float acc = 0.f;
    int cnt = 0;
    int end = chunkStart + CHUNK;
    if (end > N) end = N;
    for (int n = chunkStart + r; n < end; n += 4) {
        int g = batch[n];
        if (g != curg) {
            if (curg >= 0) {
                atomicAdd(&sums[curg * 64 + c], acc);
                if (c == 0) atomicAdd(&cntb[curg], cnt);
            }
            curg = g; acc = 0.f; cnt = 0;
        }
        acc += h[(size_t)n * 64 + c];
        cnt++;
    }
    if (curg >= 0) {
        atomicAdd(&sums[curg * 64 + c], acc);
        if (c == 0) atomicAdd(&cntb[curg], cnt);
    }
}

// ---------------- latent ----------------

__global__ __launch_bounds__(1024) void latent_kernel(
        const float* __restrict__ sums, const int* __restrict__ cntb,
        const float* __restrict__ Wp, const float* __restrict__ bp,
        const float* __restrict__ Wd, const float* __restrict__ bd,
        float* __restrict__ z_out, float* __restrict__ dg) {
    __shared__ float zl[NGRAPH * LAT];
    int t = threadIdx.x;
    {
        int g = t / LAT, l = t % LAT;
        float cf = (float)cntb[g];
        float inv = 1.0f / fmaxf(cf, 1.0f);
        float acc = bp[l];
        #pragma unroll
        for (int k = 0; k < HID; k++) acc += sums[g * HID + k] * inv * Wp[k * LAT + l];
        zl[t] = acc;
        z_out[t] = acc;
    }
    __syncthreads();
    #pragma unroll
    for (int i = 0; i < 4; i++) {
        int idx = t + i * 1024;
        int g = idx >> 6, c = idx & 63;
        float acc = bd[c];
        #pragma unroll
        for (int l = 0; l < LAT; l++) acc += zl[g * LAT + l] * Wd[l * HID + c];
        dg[idx] = fmaxf(acc, 0.f);
    }
}

// ---------------- launch ----------------

extern "C" void kernel_launch(void* const* d_in, const int* in_sizes, int n_in,
                              void* d_out, int out_size, void* d_ws, size_t ws_size,
                              hipStream_t stream) {
    const float* x          = (const float*)d_in[0];
    const int*   ei         = (const int*)d_in[1];
    const int*   batch      = (const int*)d_in[2];
    const float* W_enc0     = (const float*)d_in[3];
    const float* b_enc0     = (const float*)d_in[4];
    const float* W_enc1     = (const float*)d_in[5];
    const float* b_enc1     = (const float*)d_in[6];
    const float* W_enc2     = (const float*)d_in[7];
    const float* b_enc2     = (const float*)d_in[8];
    const float* W_proj     = (const float*)d_in[9];
    const float* b_proj     = (const float*)d_in[10];
    const float* W_dec_proj = (const float*)d_in[11];
    const float* b_dec_proj = (const float*)d_in[12];
    const float* W_dec0     = (const float*)d_in[13];
    const float* b_dec0     = (const float*)d_in[14];
    const float* W_dec1     = (const float*)d_in[15];
    const float* b_dec1     = (const float*)d_in[16];

    const int N = in_sizes[0] / IN_CH;
    const int E = in_sizes[1] / 2;

    char* ws = (char*)d_ws;
    size_t off = 0;
    auto alloc = [&](size_t bytes) {
        void* p = ws + off;
        off += (bytes + 255) & ~(size_t)255;
        return p;
    };
    float* A       = (float*)alloc((size_t)N * HID * 4);
    float* B       = (float*)alloc((size_t)N * HID * 4);
    float* XS      = (float*)alloc((size_t)N * IN_CH * 4); // aliases staged1
    int*   col     = (int*)  alloc((size_t)E * 4);
    int*   cnt2    = (int*)  alloc((size_t)N * 4);
    int*   rowptr2 = (int*)  alloc((size_t)(N + 1) * 4);
    int*   perm    = (int*)  alloc((size_t)N * 4);
    int*   rank    = (int*)  alloc((size_t)N * 4);
    float* dinvR   = (float*)alloc((size_t)N * 4);
    float2* pgR    = (float2*)alloc((size_t)N * 8);
    int*   bbase   = (int*)  alloc(257 * 4);
    // ---- zero-initialized region (single memset) ----
    char* zbase = ws + off;
    int*   bh      = (int*)  alloc(256 * 4);
    int*   gcurD   = (int*)  alloc(256 * 4);
    float* sums    = (float*)alloc((size_t)NGRAPH * HID * 4);
    int*   cntb    = (int*)  alloc((size_t)NGRAPH * 4);
    size_t zbytes = (size_t)((ws + off) - zbase);
    float* dg      = (float*)alloc((size_t)NGRAPH * HID * 4);

    u64* staged1 = (u64*)XS;   // dead before slice_x writes XS

    float* x_recon = (float*)d_out;
    float* z_out   = (float*)d_out + (size_t)N * IN_CH;

    hipMemsetAsync(zbase, 0, zbytes, stream);

    int ebins = (E + 2047) / 2048;
    int nbk = (N + 511) >> 9;            // buckets
    int chunks8 = nbk * CPB8;            // 64-row interleaved chunks (agg)
    int chunks4 = nbk * CPB4;            // 128-row interleaved chunks (gagg)

    // CSR build with bucket-local degree sort
    bhist_kernel<<<ebins, 256, 0, stream>>>(ei, bh, E);
    bin_kernel<<<ebins, 256, 0, stream>>>(ei, bh, gcurD, staged1, E);
    degb_kernel<<<256, 256, 0, stream>>>(staged1, bh, batch, rank, perm, cnt2,
                                         rowptr2, dinvR, pgR, bbase, N, E);
    csr_kernel<<<256, 256, 0, stream>>>(staged1, bbase, rank, rowptr2, col);

    {
        dim3 g((N * 4 + 255) / 256, IN_CH / 16);
        slice_x_kernel<<<g, 256, 0, stream>>>(x, perm, dinvR, XS, N);
    }

    // encoder (rank space)
    agg_kernel<IN_CH, false, false><<<chunks8 * 2, 256, 0, stream>>>(
        XS, A, rowptr2, cnt2, col, dinvR, perm, nullptr, nbk, N);
    gemm_kernel<IN_CH, HID, true, true, true, false><<<2048, 256, 0, stream>>>(
        A, W_enc0, b_enc0, dinvR, perm, B, N);
    agg_kernel<HID, false, false><<<chunks8 * 4, 256, 0, stream>>>(
        B, A, rowptr2, cnt2, col, dinvR, perm, nullptr, nbk, N);
    gemm_kernel<HID, HID, true, true, true, false><<<2048, 256, 0, stream>>>(
        A, W_enc1, b_enc1, dinvR, perm, B, N);
    agg_kernel<HID, false, false><<<chunks8 * 4, 256, 0, stream>>>(
        B, A, rowptr2, cnt2, col, dinvR, perm, nullptr, nbk, N);
    gemm_kernel<HID, HID, true, true, false, true><<<2048, 256, 0, stream>>>(
        A, W_enc2, b_enc2, dinvR, perm, B, N);   // scatter to ORIGINAL order for pool

    // pool + latent
    pool_kernel<<<(N + 511) / 512, 256, 0, stream>>>(B, batch, sums, cntb, N);
    latent_kernel<<<1, 1024, 0, stream>>>(sums, cntb, W_proj, b_proj, W_dec_proj, b_dec_proj, z_out, dg);

    // decoder (rank space): group-agg, fused double-gemm, final agg
    gagg_kernel<<<chunks4, 256, 0, stream>>>(dg, pgR, rowptr2, cnt2, col, A, nbk, N);
    gemm2_kernel<<<2048, 256, 0, stream>>>(A, W_dec0, b_dec0, W_dec1, dinvR, B, N);
    agg_kernel<IN_CH, true, true><<<chunks8 * 2, 256, 0, stream>>>(
        B, x_recon, rowptr2, cnt2, col, dinvR, perm, b_dec1, nbk, N);
}

// Round 12
// 600.827 us; speedup vs baseline: 1.9436x; 1.0041x over previous
//
#include <hip/hip_runtime.h>
#include <hip/hip_bf16.h>

typedef unsigned long long u64;
typedef unsigned int u32;

static constexpr int IN_CH  = 32;
static constexpr int HID    = 64;
static constexpr int LAT    = 16;
static constexpr int NGRAPH = 64;
static constexpr int CPB8   = 8;   // 64-row chunks per 512-node bucket (agg)
static constexpr int CPB4   = 4;   // 128-row chunks per bucket (gagg)

// RANK-SPACE pipeline, bucket-local degree sort, 16-channel slices
// ([C/16][N][16] floats): a 4-lane quad gathers one full 64B line per edge
// (request-count-bound regime, R11-confirmed). Eighth-interleaved chunk
// schedule keeps dispatch rounds degree-uniform. All agg inputs pre-scaled
// by dinv. R12: enc2-gemm fused with pool (h3 never materialized), staged
// edges packed to u32 (dst-low9<<17 | src; N < 2^17), cntb by binary search.

__device__ inline void add4(float4& a, const float4& b) {
    a.x += b.x; a.y += b.y; a.z += b.z; a.w += b.w;
}

// ---------------- bucket histogram of dst ----------------

__global__ __launch_bounds__(256) void bhist_kernel(const int* __restrict__ ei,
                                                    int* __restrict__ bh, int E) {
    __shared__ int lh[256];
    lh[threadIdx.x] = 0;
    __syncthreads();
    int base = blockIdx.x * 2048;
    #pragma unroll
    for (int j = 0; j < 8; j++) {
        int idx = base + j * 256 + threadIdx.x;
        if (idx < E) atomicAdd(&lh[ei[E + idx] >> 9], 1);
    }
    __syncthreads();
    if (lh[threadIdx.x]) atomicAdd(&bh[threadIdx.x], lh[threadIdx.x]);
}

// ---------------- LDS counting-sort binning by dst>>9 (u32 staged out) ----------------

__global__ __launch_bounds__(256) void bin_kernel(
        const int* __restrict__ ei, const int* __restrict__ bh,
        int* __restrict__ gcur, u32* __restrict__ sout, int E) {
    __shared__ int lhist[256], lscan[256], lcur[256], gbase[256], bbaseL[256];
    __shared__ u64 sbuf[2048];
    int tid = threadIdx.x;
    lhist[tid] = 0;
    {   // exclusive scan of bh -> bucket bases
        int v = bh[tid];
        lscan[tid] = v;
        for (int off = 1; off < 256; off <<= 1) {
            __syncthreads();
            int x = (tid >= off) ? lscan[tid - off] : 0;
            __syncthreads();
            lscan[tid] += x;
        }
        __syncthreads();
        bbaseL[tid] = lscan[tid] - v;
    }
    __syncthreads();
    int base = blockIdx.x * 2048;
    int cnt = min(2048, E - base);
    int myb[8]; u64 myp[8];
    #pragma unroll
    for (int j = 0; j < 8; j++) {
        int idx = base + j * 256 + tid;
        myb[j] = -1;
        if (idx < E) {
            int key = ei[E + idx], val = ei[idx];
            int b = key >> 9;
            myb[j] = b;
            u32 packed = ((u32)(key & 511) << 17) | (u32)val;
            myp[j] = ((u64)(unsigned)b << 32) | packed;
            atomicAdd(&lhist[b], 1);
        }
    }
    __syncthreads();
    int v = lhist[tid];
    lscan[tid] = v;
    for (int off = 1; off < 256; off <<= 1) {
        __syncthreads();
        int x = (tid >= off) ? lscan[tid - off] : 0;
        __syncthreads();
        lscan[tid] += x;
    }
    __syncthreads();
    int excl = lscan[tid] - v;
    __syncthreads();
    lscan[tid] = excl;
    lcur[tid] = excl;
    __syncthreads();
    #pragma unroll
    for (int j = 0; j < 8; j++) {
        if (myb[j] >= 0) {
            int pos = atomicAdd(&lcur[myb[j]], 1);
            sbuf[pos] = myp[j];
        }
    }
    gbase[tid] = v ? atomicAdd(&gcur[tid], v) : 0;
    __syncthreads();
    for (int i = tid; i < cnt; i += 256) {
        u64 p = sbuf[i];
        int b = (int)(p >> 32);
        sout[bbaseL[b] + gbase[b] + (i - lscan[b])] = (u32)(p & 0xffffffffu);
    }
}

// ---------------- per-bucket: degree, local degree-sort, rowptr, metadata ----------------

__global__ __launch_bounds__(256) void degb_kernel(
        const u32* __restrict__ staged, const int* __restrict__ bh,
        const int* __restrict__ batch,
        int* __restrict__ rank, int* __restrict__ perm, int* __restrict__ cnt2,
        int* __restrict__ rowptr2, float* __restrict__ dinvR,
        float2* __restrict__ pgR, int* __restrict__ bbase, int N, int E) {
    __shared__ int sc[256];
    __shared__ int ldeg[512], lrank[512], degS[512], psum[512];
    __shared__ int kcur[256];
    __shared__ int s0s, s1s;
    int b = blockIdx.x, tid = threadIdx.x;
    {   // scan bh -> this bucket's edge range [s0, s1)
        int bv = bh[tid];
        sc[tid] = bv;
        for (int off = 1; off < 256; off <<= 1) {
            __syncthreads();
            int x = (tid >= off) ? sc[tid - off] : 0;
            __syncthreads();
            sc[tid] += x;
        }
        __syncthreads();
        if (tid == b) { s0s = sc[tid] - bv; s1s = sc[tid]; }
    }
    ldeg[tid] = 0; ldeg[tid + 256] = 0;
    degS[tid] = 0; degS[tid + 256] = 0;
    kcur[tid] = 0;   // used first as khist
    __syncthreads();
    int s0 = s0s, s1 = s1s;
    int base = b << 9;
    for (int i = s0 + tid; i < s1; i += 256)
        atomicAdd(&ldeg[(int)(__builtin_nontemporal_load(&staged[i]) >> 17)], 1);
    __syncthreads();
    int k = N - base; k = k < 0 ? 0 : (k > 512 ? 512 : k);
    #pragma unroll
    for (int j = 0; j < 2; j++) {
        int t = tid + j * 256;
        if (t < k) atomicAdd(&kcur[min(ldeg[t], 255)], 1);
    }
    __syncthreads();
    {   // exclusive scan of key-histogram -> kcur = bucket offsets
        int hv = kcur[tid];
        sc[tid] = hv;
        for (int off = 1; off < 256; off <<= 1) {
            __syncthreads();
            int x = (tid >= off) ? sc[tid - off] : 0;
            __syncthreads();
            sc[tid] += x;
        }
        __syncthreads();
        kcur[tid] = sc[tid] - hv;
    }
    __syncthreads();
    #pragma unroll
    for (int j = 0; j < 2; j++) {
        int t = tid + j * 256;
        if (t < k) lrank[t] = atomicAdd(&kcur[min(ldeg[t], 255)], 1);
    }
    __syncthreads();
    #pragma unroll
    for (int j = 0; j < 2; j++) {
        int t = tid + j * 256;
        if (t < k) degS[lrank[t]] = ldeg[t];
    }
    __syncthreads();
    {   // exclusive scan of degS[512] -> psum (edge prefix in local-rank order)
        int v0 = degS[2 * tid], v1 = degS[2 * tid + 1];
        int T = v0 + v1;
        sc[tid] = T;
        for (int off = 1; off < 256; off <<= 1) {
            __syncthreads();
            int x = (tid >= off) ? sc[tid - off] : 0;
            __syncthreads();
            sc[tid] += x;
        }
        __syncthreads();
        int ex = sc[tid] - T;
        psum[2 * tid] = ex;
        psum[2 * tid + 1] = ex + v0;
    }
    __syncthreads();
    #pragma unroll
    for (int j = 0; j < 2; j++) {
        int t = tid + j * 256;
        if (t < k) {
            int n = base + t;
            int d = ldeg[t], lr = lrank[t];
            int r = base + lr;
            rank[n] = r;
            perm[r] = n;
            cnt2[r] = d;
            rowptr2[r] = s0 + psum[lr];
            float dv = rsqrtf((float)d + 1.0f);
            dinvR[r] = dv;
            pgR[r] = make_float2(dv, __int_as_float(batch[n]));
        }
    }
    if (tid == 0) {
        bbase[b] = s0;
        if (b == 255) bbase[256] = E;
    }
}

// ---------------- bucket-local CSR fill, LDS cursors (col = rank[src]) ----------------

__global__ __launch_bounds__(256) void csr_kernel(
        const u32* __restrict__ staged, const int* __restrict__ bbase,
        const int* __restrict__ rank, const int* __restrict__ rowptr2,
        int* __restrict__ col) {
    __shared__ int lcur[512];
    int b = blockIdx.x, tid = threadIdx.x;
    lcur[tid] = 0; lcur[tid + 256] = 0;
    __syncthreads();
    int s0 = bbase[b], s1 = bbase[b + 1];
    int base = b << 9;
    for (int i = s0 + tid; i < s1; i += 256) {
        u32 p = __builtin_nontemporal_load(&staged[i]);
        int low9 = (int)(p >> 17);
        int src  = (int)(p & 0x1FFFFu);
        int rd = rank[base + low9];               // hot 2KB window
        int pos = rowptr2[rd] + atomicAdd(&lcur[rd - base], 1);
        col[pos] = rank[src];                     // L2-resident 400KB table
    }
}

// ---------------- cntb: nodes per graph via binary search on sorted batch ----------------

__global__ void cntb_kernel(const int* __restrict__ batch, int* __restrict__ cntb, int N) {
    int g = threadIdx.x;   // 0..63
    if (g >= NGRAPH) return;
    auto lb = [&](int key) {
        int lo = 0, hi = N;
        while (lo < hi) { int mid = (lo + hi) >> 1; if (batch[mid] < key) lo = mid + 1; else hi = mid; }
        return lo;
    };
    cntb[g] = lb(g + 1) - lb(g);
}

// ---------------- x -> rank-space 16ch-sliced layout, pre-scaled ----------------

__global__ void slice_x_kernel(const float* __restrict__ x, const int* __restrict__ perm,
                               const float* __restrict__ dinvR,
                               float* __restrict__ xs, int N) {
    int idx = blockIdx.x * 256 + threadIdx.x;   // over N*4
    if (idx >= N * 4) return;
    int r = idx >> 2, h = idx & 3;
    int sl = blockIdx.y;                        // 0..IN_CH/16-1
    int n = perm[r];                            // local window gather
    float4 v = ((const float4*)x)[(size_t)n * 8 + sl * 4 + h];
    float dn = dinvR[r];
    v.x *= dn; v.y *= dn; v.z *= dn; v.w *= dn;
    ((float4*)(xs + (size_t)sl * N * 16))[idx] = v;
}

// ---------------- aggregation (16ch slices, 4-lane quad, one 64B line/edge) ----------------
// out[r] = dinvR[r] * (in[r] + sum_{sr in row r} in[sr])   [+bias]

template <int C, bool ADD_BIAS, bool OUT_ROWMAJOR>
__global__ __launch_bounds__(256) void agg_kernel(
        const float* __restrict__ in, float* __restrict__ out,
        const int* __restrict__ rowptr2, const int* __restrict__ cnt2,
        const int* __restrict__ col, const float* __restrict__ dinvR,
        const int* __restrict__ perm, const float* __restrict__ bias,
        int nbk, int N) {
    constexpr int NSL = C / 16;
    int sl = blockIdx.x % NSL;
    int o  = blockIdx.x / NSL;
    int chunk = (o % nbk) * CPB8 + (o / nbk);   // eighth-interleave
    int quad = threadIdx.x >> 2, q = threadIdx.x & 3;
    int r = chunk * 64 + quad;
    if (r >= N) return;
    const float4* inS = (const float4*)(in + (size_t)sl * N * 16);
    int start = rowptr2[r], m = cnt2[r];
    const int* cp = col + start;
    float4 acc0 = inS[(size_t)r * 4 + q];   // self (own quarter-line)
    float4 acc1 = make_float4(0.f, 0.f, 0.f, 0.f);
    int i = 0;
    for (; i + 8 <= m; i += 8) {
        int4 ca = *(const int4*)(cp + i);       // quad-uniform: broadcast
        int4 cb = *(const int4*)(cp + i + 4);
        float4 v0 = inS[(size_t)ca.x*4+q], v1 = inS[(size_t)ca.y*4+q];
        float4 v2 = inS[(size_t)ca.z*4+q], v3 = inS[(size_t)ca.w*4+q];
        float4 v4 = inS[(size_t)cb.x*4+q], v5 = inS[(size_t)cb.y*4+q];
        float4 v6 = inS[(size_t)cb.z*4+q], v7 = inS[(size_t)cb.w*4+q];
        add4(v0, v1); add4(v2, v3); add4(v4, v5); add4(v6, v7);
        add4(v0, v2); add4(v4, v6);
        add4(acc0, v0); add4(acc1, v4);
    }
    if (i + 4 <= m) {
        int4 ca = *(const int4*)(cp + i);
        float4 v0 = inS[(size_t)ca.x*4+q], v1 = inS[(size_t)ca.y*4+q];
        float4 v2 = inS[(size_t)ca.z*4+q], v3 = inS[(size_t)ca.w*4+q];
        add4(v0, v1); add4(v2, v3); add4(v0, v2);
        add4(acc0, v0);
        i += 4;
    }
    for (; i < m; ++i) {
        int c = cp[i];
        add4(acc1, inS[(size_t)c * 4 + q]);
    }
    add4(acc0, acc1);
    float dn = dinvR[r];
    acc0.x *= dn; acc0.y *= dn; acc0.z *= dn; acc0.w *= dn;
    if (ADD_BIAS) {
        float4 b4 = ((const float4*)bias)[sl * 4 + q];
        add4(acc0, b4);
    }
    if (OUT_ROWMAJOR) ((float4*)out)[(size_t)perm[r] * (C / 4) + sl * 4 + q] = acc0;
    else ((float4*)(out + (size_t)sl * N * 16))[(size_t)r * 4 + q] = acc0;
}

// ---------------- group-agg for decoder conv0 (output 16ch-sliced) ----------------

__global__ __launch_bounds__(256) void gagg_kernel(
        const float* __restrict__ dg, const float2* __restrict__ pgR,
        const int* __restrict__ rowptr2, const int* __restrict__ cnt2,
        const int* __restrict__ col, float* __restrict__ out, int nbk, int N) {
    __shared__ float dgL[NGRAPH * 68];   // padded stride 68 floats (17 float4)
    for (int i = threadIdx.x; i < NGRAPH * 64; i += 256)
        dgL[(i >> 6) * 68 + (i & 63)] = dg[i];
    __syncthreads();
    int slot = threadIdx.x >> 1, e = threadIdx.x & 1;   // e: channel half (32ch)
    int o = blockIdx.x;
    int chunk = (o % nbk) * CPB4 + (o / nbk);           // quarter-interleave
    int r = chunk * 128 + slot;
    if (r >= N) return;
    const float4* dgL4 = (const float4*)dgL;            // row stride 17
    int start = rowptr2[r], m = cnt2[r];
    const int* cp = col + start;
    float2 ps = pgR[r];
    float dn = ps.x;
    int gs = __float_as_int(ps.y);
    float4 acc[8];
    {
        const float4* rp = dgL4 + gs * 17 + e * 8;
        #pragma unroll
        for (int j = 0; j < 8; ++j) {
            float4 v = rp[j];
            acc[j] = make_float4(dn * v.x, dn * v.y, dn * v.z, dn * v.w);
        }
    }
    int i = 0;
    for (; i + 4 <= m; i += 4) {
        int4 ca = *(const int4*)(cp + i);
        float2 p0 = pgR[ca.x], p1 = pgR[ca.y], p2 = pgR[ca.z], p3 = pgR[ca.w];
        const float4* r0 = dgL4 + __float_as_int(p0.y) * 17 + e * 8;
        const float4* r1 = dgL4 + __float_as_int(p1.y) * 17 + e * 8;
        const float4* r2 = dgL4 + __float_as_int(p2.y) * 17 + e * 8;
        const float4* r3 = dgL4 + __float_as_int(p3.y) * 17 + e * 8;
        float w0 = p0.x, w1 = p1.x, w2 = p2.x, w3 = p3.x;
        #pragma unroll
        for (int j = 0; j < 8; ++j) {
            float4 v0 = r0[j], v1 = r1[j], v2 = r2[j], v3 = r3[j];
            acc[j].x += (w0 * v0.x + w1 * v1.x) + (w2 * v2.x + w3 * v3.x);
            acc[j].y += (w0 * v0.y + w1 * v1.y) + (w2 * v2.y + w3 * v3.y);
            acc[j].z += (w0 * v0.z + w1 * v1.z) + (w2 * v2.z + w3 * v3.z);
            acc[j].w += (w0 * v0.w + w1 * v1.w) + (w2 * v2.w + w3 * v3.w);
        }
    }
    for (; i < m; ++i) {
        int c0 = cp[i];
        float2 p0 = pgR[c0];
        const float4* r0 = dgL4 + __float_as_int(p0.y) * 17 + e * 8;
        float w0 = p0.x;
        #pragma unroll
        for (int j = 0; j < 8; ++j) {
            float4 v0 = r0[j];
            acc[j].x += w0 * v0.x; acc[j].y += w0 * v0.y;
            acc[j].z += w0 * v0.z; acc[j].w += w0 * v0.w;
        }
    }
    #pragma unroll
    for (int k = 0; k < 4; ++k) {
        #pragma unroll
        for (int jj = 0; jj < 2; ++jj) {
            float4 v = acc[k * 2 + jj];
            v.x *= dn; v.y *= dn; v.z *= dn; v.w *= dn;
            int ch = e * 32 + k * 8 + jj * 4;
            ((float4*)(out + (size_t)(ch >> 4) * N * 16))[(size_t)r * 4 + ((ch & 15) >> 2)] = v;
        }
    }
}

// ---------------- dense transform: W column in registers, x broadcast from LDS ----------------

template <int CIN, int COUT, bool RELU, bool BIAS, bool SCALE, bool OUT_ROWMAJOR>
__global__ __launch_bounds__(256) void gemm_kernel(
        const float* __restrict__ in, const float* __restrict__ W,
        const float* __restrict__ b, const float* __restrict__ dinvR,
        const int* __restrict__ perm, float* __restrict__ out, int N) {
    constexpr int NPB = 256 / COUT;
    constexpr int K4 = CIN / 4;
    __shared__ float4 xsh[NPB * K4];
    int r  = threadIdx.x / COUT;
    int co = threadIdx.x % COUT;
    float w[CIN];
    #pragma unroll
    for (int k = 0; k < CIN; ++k) w[k] = W[k * COUT + co];
    float bsv = BIAS ? b[co] : 0.f;
    int ngroups = (N + NPB - 1) / NPB;
    for (int grp = blockIdx.x; grp < ngroups; grp += gridDim.x) {
        int base = grp * NPB;
        __syncthreads();
        for (int i = threadIdx.x; i < NPB * K4; i += 256) {
            int rr = i / K4, k4 = i % K4;
            int n = base + rr;
            float4 v = make_float4(0.f, 0.f, 0.f, 0.f);
            if (n < N) v = ((const float4*)(in + (size_t)(k4 >> 2) * N * 16))[(size_t)n * 4 + (k4 & 3)];
            xsh[i] = v;
        }
        __syncthreads();
        int n = base + r;
        if (n < N) {
            float acc = bsv;
            #pragma unroll
            for (int k4 = 0; k4 < K4; ++k4) {
                float4 xv = xsh[r * K4 + k4];   // wave-uniform -> LDS broadcast
                acc += xv.x * w[4 * k4] + xv.y * w[4 * k4 + 1]
                     + xv.z * w[4 * k4 + 2] + xv.w * w[4 * k4 + 3];
            }
            if (RELU) acc = fmaxf(acc, 0.f);
            if (SCALE) acc *= dinvR[n];
            if (OUT_ROWMAJOR) out[(size_t)perm[n] * COUT + co] = acc;
            else out[(size_t)(co >> 4) * N * 16 + (size_t)n * 16 + (co & 15)] = acc;
        }
    }
}

// ---------------- fused enc2-gemm + global mean pool (sum part) ----------------
// h3 = relu(A @ W + b) is consumed ONLY by pooling -> never materialized.
// Per-block LDS accumulation of per-graph sums, one atomic flush per block.

__global__ __launch_bounds__(256) void gemm_pool_kernel(
        const float* __restrict__ in, const float* __restrict__ W,
        const float* __restrict__ b, const float2* __restrict__ pgR,
        float* __restrict__ sums, int N) {
    constexpr int NPB = 4;
    constexpr int K4 = HID / 4;   // 16
    __shared__ float4 xsh[NPB * K4];
    __shared__ float lsum[NGRAPH * HID];   // 16KB
    int tid = threadIdx.x;
    int r  = tid >> 6;     // 0..3
    int co = tid & 63;
    float w[HID];
    #pragma unroll
    for (int k = 0; k < HID; ++k) w[k] = W[k * HID + co];
    float bv = b[co];
    for (int i = tid; i < NGRAPH * HID; i += 256) lsum[i] = 0.f;
    int ngroups = (N + NPB - 1) / NPB;
    for (int grp = blockIdx.x; grp < ngroups; grp += gridDim.x) {
        int base = grp * NPB;
        __syncthreads();
        if (tid < NPB * K4) {
            int rr = tid >> 4, k4 = tid & 15;
            int n = base + rr;
            float4 v = make_float4(0.f, 0.f, 0.f, 0.f);
            if (n < N) v = ((const float4*)(in + (size_t)(k4 >> 2) * N * 16))[(size_t)n * 4 + (k4 & 3)];
            xsh[tid] = v;
        }
        __syncthreads();
        int n = base + r;
        if (n < N) {
            float acc = bv;
            #pragma unroll
            for (int k4 = 0; k4 < K4; ++k4) {
                float4 xv = xsh[r * K4 + k4];
                acc += xv.x * w[4 * k4] + xv.y * w[4 * k4 + 1]
                     + xv.z * w[4 * k4 + 2] + xv.w * w[4 * k4 + 3];
            }
            acc = fmaxf(acc, 0.f);
            int g = __float_as_int(pgR[n].y);
            atomicAdd(&lsum[g * HID + co], acc);
        }
    }
    __syncthreads();
    for (int i = tid; i < NGRAPH * HID; i += 256) {
        float v = lsum[i];
        if (v != 0.f) atomicAdd(&sums[i], v);
    }
}

// ---------------- latent ----------------

__global__ __launch_bounds__(1024) void latent_kernel(
        const float* __restrict__ sums, const int* __restrict__ cntb,
        const float* __restrict__ Wp, const float* __restrict__ bp,
        const float* __restrict__ Wd, const float* __restrict__ bd,
        float* __restrict__ z_out, float* __restrict__ dg) {
    __shared__ float zl[NGRAPH * LAT];
    int t = threadIdx.x;
    {
        int g = t / LAT, l = t % LAT;
        float cf = (float)cntb[g];
        float inv = 1.0f / fmaxf(cf, 1.0f);
        float acc = bp[l];
        #pragma unroll
        for (int k = 0; k < HID; k++) acc += sums[g * HID + k] * inv * Wp[k * LAT + l];
        zl[t] = acc;
        z_out[t] = acc;
    }
    __syncthreads();
    #pragma unroll
    for (int i = 0; i < 4; i++) {
        int idx = t + i * 1024;
        int g = idx >> 6, c = idx & 63;
        float acc = bd[c];
        #pragma unroll
        for (int l = 0; l < LAT; l++) acc += zl[g * LAT + l] * Wd[l * HID + c];
        dg[idx] = fmaxf(acc, 0.f);
    }
}

// ---------------- fused decoder gemm: t = relu(in@W0+b0); out = dinv*(t@W1) ----------------

__global__ __launch_bounds__(256) void gemm2_kernel(
        const float* __restrict__ in, const float* __restrict__ W0,
        const float* __restrict__ b0, const float* __restrict__ W1,
        const float* __restrict__ dinvR, float* __restrict__ out, int N) {
    constexpr int NPB = 4;           // rows per group
    __shared__ float4 xsh[NPB * 16];
    __shared__ float t1sh[NPB * 65];
    __shared__ float w1sh[HID * IN_CH];   // 8KB
    int tid = threadIdx.x;
    int r  = tid >> 6;               // 0..3
    int co = tid & 63;
    float w0[HID];
    #pragma unroll
    for (int k = 0; k < HID; ++k) w0[k] = W0[k * HID + co];
    float b0v = b0[co];
    for (int i = tid; i < HID * IN_CH; i += 256) w1sh[i] = W1[i];
    int r2  = tid >> 5;              // 0..7 (only 0..3 used in phase B)
    int co2 = tid & 31;
    int ngroups = (N + NPB - 1) / NPB;
    for (int grp = blockIdx.x; grp < ngroups; grp += gridDim.x) {
        int base = grp * NPB;
        __syncthreads();             // prior phase B done (t1sh/xsh reusable)
        if (tid < NPB * 16) {
            int rr = tid >> 4, k4 = tid & 15;
            int n = base + rr;
            float4 v = make_float4(0.f, 0.f, 0.f, 0.f);
            if (n < N) v = ((const float4*)(in + (size_t)(k4 >> 2) * N * 16))[(size_t)n * 4 + (k4 & 3)];
            xsh[tid] = v;
        }
        __syncthreads();
        {   // phase A: t1 = relu(x @ W0 + b0)
            float acc = b0v;
            #pragma unroll
            for (int k4 = 0; k4 < 16; ++k4) {
                float4 xv = xsh[r * 16 + k4];
                acc += xv.x * w0[4 * k4] + xv.y * w0[4 * k4 + 1]
                     + xv.z * w0[4 * k4 + 2] + xv.w * w0[4 * k4 + 3];
            }
            t1sh[r * 65 + co] = fmaxf(acc, 0.f);
        }
        __syncthreads();
        if (r2 < NPB) {              // phase B: out = dinv * (t1 @ W1)
            int n = base + r2;
            if (n < N) {
                float acc = 0.f;
                #pragma unroll
                for (int k = 0; k < HID; ++k)
                    acc += t1sh[r2 * 65 + k] * w1sh[k * IN_CH + co2];
                acc *= dinvR[n];
                out[(size_t)(co2 >> 4) * N * 16 + (size_t)n * 16 + (co2 & 15)] = acc;
            }
        }
    }
}

// ---------------- launch ----------------

extern "C" void kernel_launch(void* const* d_in, const int* in_sizes, int n_in,
                              void* d_out, int out_size, void* d_ws, size_t ws_size,
                              hipStream_t stream) {
    const float* x          = (const float*)d_in[0];
    const int*   ei         = (const int*)d_in[1];
    const int*   batch      = (const int*)d_in[2];
    const float* W_enc0     = (const float*)d_in[3];
    const float* b_enc0     = (const float*)d_in[4];
    const float* W_enc1     = (const float*)d_in[5];
    const float* b_enc1     = (const float*)d_in[6];
    const float* W_enc2     = (const float*)d_in[7];
    const float* b_enc2     = (const float*)d_in[8];
    const float* W_proj     = (const float*)d_in[9];
    const float* b_proj     = (const float*)d_in[10];
    const float* W_dec_proj = (const float*)d_in[11];
    const float* b_dec_proj = (const float*)d_in[12];
    const float* W_dec0     = (const float*)d_in[13];
    const float* b_dec0     = (const float*)d_in[14];
    const float* W_dec1     = (const float*)d_in[15];
    const float* b_dec1     = (const float*)d_in[16];

    const int N = in_sizes[0] / IN_CH;
    const int E = in_sizes[1] / 2;

    char* ws = (char*)d_ws;
    size_t off = 0;
    auto alloc = [&](size_t bytes) {
        void* p = ws + off;
        off += (bytes + 255) & ~(size_t)255;
        return p;
    };
    float* A       = (float*)alloc((size_t)N * HID * 4);
    float* B       = (float*)alloc((size_t)N * HID * 4);
    float* XS      = (float*)alloc((size_t)N * IN_CH * 4); // aliases staged1
    int*   col     = (int*)  alloc((size_t)E * 4);
    int*   cnt2    = (int*)  alloc((size_t)N * 4);
    int*   rowptr2 = (int*)  alloc((size_t)(N + 1) * 4);
    int*   perm    = (int*)  alloc((size_t)N * 4);
    int*   rank    = (int*)  alloc((size_t)N * 4);
    float* dinvR   = (float*)alloc((size_t)N * 4);
    float2* pgR    = (float2*)alloc((size_t)N * 8);
    int*   bbase   = (int*)  alloc(257 * 4);
    // ---- zero-initialized region (single memset) ----
    char* zbase = ws + off;
    int*   bh      = (int*)  alloc(256 * 4);
    int*   gcurD   = (int*)  alloc(256 * 4);
    float* sums    = (float*)alloc((size_t)NGRAPH * HID * 4);
    int*   cntb    = (int*)  alloc((size_t)NGRAPH * 4);
    size_t zbytes = (size_t)((ws + off) - zbase);
    float* dg      = (float*)alloc((size_t)NGRAPH * HID * 4);

    u32* staged1 = (u32*)XS;   // 6.4MB, dead before slice_x writes XS

    float* x_recon = (float*)d_out;
    float* z_out   = (float*)d_out + (size_t)N * IN_CH;

    hipMemsetAsync(zbase, 0, zbytes, stream);

    int ebins = (E + 2047) / 2048;
    int nbk = (N + 511) >> 9;            // buckets
    int chunks8 = nbk * CPB8;            // 64-row interleaved chunks (agg)
    int chunks4 = nbk * CPB4;            // 128-row interleaved chunks (gagg)

    // CSR build with bucket-local degree sort (u32 staged)
    bhist_kernel<<<ebins, 256, 0, stream>>>(ei, bh, E);
    bin_kernel<<<ebins, 256, 0, stream>>>(ei, bh, gcurD, staged1, E);
    degb_kernel<<<256, 256, 0, stream>>>(staged1, bh, batch, rank, perm, cnt2,
                                         rowptr2, dinvR, pgR, bbase, N, E);
    csr_kernel<<<256, 256, 0, stream>>>(staged1, bbase, rank, rowptr2, col);
    cntb_kernel<<<1, 64, 0, stream>>>(batch, cntb, N);

    {
        dim3 g((N * 4 + 255) / 256, IN_CH / 16);
        slice_x_kernel<<<g, 256, 0, stream>>>(x, perm, dinvR, XS, N);
    }

    // encoder (rank space)
    agg_kernel<IN_CH, false, false><<<chunks8 * 2, 256, 0, stream>>>(
        XS, A, rowptr2, cnt2, col, dinvR, perm, nullptr, nbk, N);
    gemm_kernel<IN_CH, HID, true, true, true, false><<<2048, 256, 0, stream>>>(
        A, W_enc0, b_enc0, dinvR, perm, B, N);
    agg_kernel<HID, false, false><<<chunks8 * 4, 256, 0, stream>>>(
        B, A, rowptr2, cnt2, col, dinvR, perm, nullptr, nbk, N);
    gemm_kernel<HID, HID, true, true, true, false><<<2048, 256, 0, stream>>>(
        A, W_enc1, b_enc1, dinvR, perm, B, N);
    agg_kernel<HID, false, false><<<chunks8 * 4, 256, 0, stream>>>(
        B, A, rowptr2, cnt2, col, dinvR, perm, nullptr, nbk, N);
    // enc2 gemm fused with pool: h3 never materialized
    gemm_pool_kernel<<<512, 256, 0, stream>>>(A, W_enc2, b_enc2, pgR, sums, N);

    latent_kernel<<<1, 1024, 0, stream>>>(sums, cntb, W_proj, b_proj, W_dec_proj, b_dec_proj, z_out, dg);

    // decoder (rank space): group-agg, fused double-gemm, final agg
    gagg_kernel<<<chunks4, 256, 0, stream>>>(dg, pgR, rowptr2, cnt2, col, A, nbk, N);
    gemm2_kernel<<<2048, 256, 0, stream>>>(A, W_dec0, b_dec0, W_dec1, dinvR, B, N);
    agg_kernel<IN_CH, true, true><<<chunks8 * 2, 256, 0, stream>>>(
        B, x_recon, rowptr2, cnt2, col, dinvR, perm, b_dec1, nbk, N);
}